// Round 1
// baseline (4940.465 us; speedup 1.0000x reference)
//
#include <hip/hip_runtime.h>
#include <hip/hip_bf16.h>

// SearchPredictModel: cos-topK -> gather/sum emb -> time-decay GRU (8192x15)
//                     -> time-decay GRU (128x128, keep last 4) -> attention -> MLP -> sigmoid
// Round 1: correctness-first fp32 scalar implementation.
// Workspace use: ~55.3 MB (e tensors stored bf16).

#define PAD_TOK 200000
#define DD 128
#define HH 256
#define KK 15
#define MM 4
#define BB 512
#define SS 16
#define II 64

// ---------------- workspace layout (byte offsets) ----------------
// computed in kernel_launch with a running cursor.

__global__ __launch_bounds__(128) void k_eself(const int* __restrict__ x,
                                               const int* __restrict__ self_loc,
                                               const float* __restrict__ emb,
                                               float* __restrict__ es,
                                               float* __restrict__ ns) {
  int b = blockIdx.x, d = threadIdx.x;
  int tok = x[((size_t)(b * SS + 0) * II + self_loc[b]) * 8 + 5];
  float v = emb[(size_t)tok * DD + d];
  es[b * DD + d] = v;
  __shared__ float red[128];
  red[d] = v * v;
  __syncthreads();
  for (int o = 64; o > 0; o >>= 1) {
    if (d < o) red[d] += red[d + o];
    __syncthreads();
  }
  if (d == 0) ns[b] = fmaxf(sqrtf(red[0]), 1e-8f);
}

__global__ void k_init(unsigned* minu) { *minu = 0xFFFFFFFFu; }

__global__ __launch_bounds__(256) void k_cos(const int* __restrict__ x,
                                             const float* __restrict__ emb,
                                             const float* __restrict__ es,
                                             const float* __restrict__ ns,
                                             float* __restrict__ simw,
                                             unsigned* __restrict__ minu) {
  int row = blockIdx.x;  // b*16+s
  int b = row >> 4;
  int tid = threadIdx.x, wave = tid >> 6, lane = tid & 63;
  const float2 ev = reinterpret_cast<const float2*>(es + b * DD)[lane];
  float nsb = ns[b];
  unsigned localmin = 0xFFFFFFFFu;
  for (int it = 0; it < 16; ++it) {
    int i = wave * 16 + it;
    const int* xr = x + ((size_t)row * II + i) * 8;
    int tok = xr[5];
    float2 a = *reinterpret_cast<const float2*>(emb + (size_t)tok * DD + lane * 2);
    float dot = a.x * ev.x + a.y * ev.y;
    float ss = a.x * a.x + a.y * a.y;
    for (int o = 32; o; o >>= 1) {
      dot += __shfl_xor(dot, o);
      ss += __shfl_xor(ss, o);
    }
    if (lane == 0) {
      float cosv = dot / (fmaxf(sqrtf(ss), 1e-8f) * nsb);
      simw[(size_t)row * II + i] = cosv;
      if (xr[0] != PAD_TOK) {
        unsigned u = __float_as_uint(cosv);
        unsigned key = (cosv < 0.f) ? ~u : (u | 0x80000000u);
        localmin = min(localmin, key);
      }
    }
  }
  if (lane == 0 && localmin != 0xFFFFFFFFu) atomicMin(minu, localmin);
}

__global__ __launch_bounds__(64) void k_topk(const int* __restrict__ x,
                                             const float* __restrict__ simw,
                                             const unsigned* __restrict__ minu,
                                             int* __restrict__ topidx) {
  int row = blockIdx.x, i = threadIdx.x;
  unsigned mk = *minu;
  float neg = ((mk & 0x80000000u) ? __uint_as_float(mk ^ 0x80000000u) : __uint_as_float(~mk)) - 1.0f;
  float c = simw[(size_t)row * II + i];
  bool real = x[((size_t)row * II + i) * 8] != PAD_TOK;
  float s = real ? c : neg;
  __shared__ float sv[64];
  sv[i] = s;
  __syncthreads();
  int rank = 0;
  for (int j = 0; j < 64; ++j) {
    float o = sv[j];
    rank += (o > s) || (o == s && j < i);
  }
  bool sel = rank < KK;
  unsigned long long mask = __ballot(sel);
  if (sel) {
    int pos = __popcll(mask & ((1ull << i) - 1ull));
    topidx[row * KK + pos] = i;
  }
}

__global__ __launch_bounds__(128) void k_build_main(const int* __restrict__ x,
                                                    const int* __restrict__ self_loc,
                                                    const float* __restrict__ emb,
                                                    const int* __restrict__ topidx,
                                                    __hip_bfloat16* __restrict__ em,
                                                    float* __restrict__ dtm,
                                                    float* __restrict__ xself) {
  int n = blockIdx.x, t = blockIdx.y, d = threadIdx.x;
  int b = n >> 4, s = n & 15;
  bool ovr = (s == 0) && (t == KK - 1);
  int item = ovr ? self_loc[b] : topidx[n * KK + t];
  const int* xr = x + ((size_t)n * II + item) * 8;
  float acc = 0.f;
#pragma unroll
  for (int jj = 0; jj < 6; ++jj) acc += emb[(size_t)xr[jj] * DD + d];
  em[((size_t)t * 8192 + n) * DD + d] = __float2bfloat16(acc);
  if (ovr) xself[b * DD + d] = acc;
  if (d == 0) {
    float dtv = 0.f;
    if (t > 0) {
      int pitem = topidx[n * KK + t - 1];
      dtv = (float)xr[6] - (float)x[((size_t)n * II + pitem) * 8 + 6];
    }
    dtm[t * 8192 + n] = dtv;
  }
}

__global__ __launch_bounds__(128) void k_build_cont(const int* __restrict__ xc,
                                                    const float* __restrict__ emb,
                                                    __hip_bfloat16* __restrict__ ec,
                                                    float* __restrict__ dtc) {
  int p = blockIdx.x, t = blockIdx.y, d = threadIdx.x;
  const int* xr = xc + ((size_t)p * 128 + t) * 8;
  float acc = 0.f;
#pragma unroll
  for (int jj = 0; jj < 6; ++jj) acc += emb[(size_t)xr[jj] * DD + d];
  ec[((size_t)p * 128 + t) * DD + d] = __float2bfloat16(acc);
  if (d == 0) dtc[p * 128 + t] = (t > 0) ? ((float)xr[6] - (float)xr[-2]) : 0.f;
}

// main RNN: 512 blocks (one per b, 16 rows), 256 threads (one gate-col triple each)
__global__ __launch_bounds__(256) void k_rnn_main(const __hip_bfloat16* __restrict__ em,
                                                  const float* __restrict__ dtm,
                                                  const float* __restrict__ xself,
                                                  const float* __restrict__ W,
                                                  const float* __restrict__ U,
                                                  const float* __restrict__ bg,
                                                  const float* __restrict__ wt,
                                                  float* __restrict__ hmain) {
  int b = blockIdx.x;
  int tid = threadIdx.x;
  __shared__ float xs[128];
  __shared__ float el[16 * 128];
  __shared__ float dts[16];
  __shared__ float hl[16 * 256];
  __shared__ float hd[16 * 256];

  if (tid < 128) xs[tid] = xself[b * DD + tid];
#pragma unroll
  for (int r = 0; r < 16; ++r) hl[r * 256 + tid] = 0.f;
  const int c0 = tid, c1 = tid + 256, c2 = tid + 512;
  float bz = bg[c0], br = bg[c1], bn = bg[c2];
  float wtc = wt[tid];
  __syncthreads();

  float gs0 = 0.f, gs1 = 0.f, gs2 = 0.f;
  for (int k = 0; k < 128; ++k) {
    float xv = xs[k];
    gs0 = fmaf(xv, W[k * 768 + c0], gs0);
    gs1 = fmaf(xv, W[k * 768 + c1], gs1);
    gs2 = fmaf(xv, W[k * 768 + c2], gs2);
  }

  for (int t = 0; t < KK; ++t) {
    const __hip_bfloat16* p = em + ((size_t)t * 8192 + b * SS) * DD;
    for (int idx = tid; idx < 2048; idx += 256) el[idx] = __bfloat162float(p[idx]);
    if (tid < 16) dts[tid] = dtm[t * 8192 + b * SS + tid];
    __syncthreads();
#pragma unroll
    for (int r = 0; r < 16; ++r) {
      float dv = dts[r] * wtc;
      hd[r * 256 + tid] = hl[r * 256 + tid] * expf(-fmaxf(dv, 0.f));
    }
    __syncthreads();
#pragma unroll
    for (int h2 = 0; h2 < 2; ++h2) {
      const int r0 = h2 * 8;
      float ge[8][3], uu[8][3];
#pragma unroll
      for (int r = 0; r < 8; ++r) {
        ge[r][0] = ge[r][1] = ge[r][2] = 0.f;
        uu[r][0] = uu[r][1] = uu[r][2] = 0.f;
      }
      for (int k = 0; k < 128; ++k) {
        float w0 = W[(128 + k) * 768 + c0];
        float w1 = W[(128 + k) * 768 + c1];
        float w2 = W[(128 + k) * 768 + c2];
#pragma unroll
        for (int r = 0; r < 8; ++r) {
          float ev = el[(r0 + r) * 128 + k];
          ge[r][0] = fmaf(ev, w0, ge[r][0]);
          ge[r][1] = fmaf(ev, w1, ge[r][1]);
          ge[r][2] = fmaf(ev, w2, ge[r][2]);
        }
      }
      for (int k = 0; k < 256; ++k) {
        float u0 = U[k * 768 + c0];
        float u1 = U[k * 768 + c1];
        float u2 = U[k * 768 + c2];
#pragma unroll
        for (int r = 0; r < 8; ++r) {
          float hv = hd[(r0 + r) * 256 + k];
          uu[r][0] = fmaf(hv, u0, uu[r][0]);
          uu[r][1] = fmaf(hv, u1, uu[r][1]);
          uu[r][2] = fmaf(hv, u2, uu[r][2]);
        }
      }
#pragma unroll
      for (int r = 0; r < 8; ++r) {
        float z = 1.f / (1.f + expf(-(gs0 + ge[r][0] + bz + uu[r][0])));
        float rr = 1.f / (1.f + expf(-(gs1 + ge[r][1] + br + uu[r][1])));
        float nn = tanhf(gs2 + ge[r][2] + bn + rr * uu[r][2]);
        float hdv = hd[(r0 + r) * 256 + tid];
        hl[(r0 + r) * 256 + tid] = (1.f - z) * hdv + z * nn;
      }
    }
    __syncthreads();
  }
#pragma unroll
  for (int r = 0; r < 16; ++r)
    hmain[((size_t)(b * SS + r)) * HH + tid] = hl[r * 256 + tid];
}

// cont RNN: 64 blocks x 2 rows, 256 threads
__global__ __launch_bounds__(256) void k_rnn_cont(const __hip_bfloat16* __restrict__ ec,
                                                  const float* __restrict__ dtc,
                                                  const float* __restrict__ W,
                                                  const float* __restrict__ U,
                                                  const float* __restrict__ bg,
                                                  const float* __restrict__ wt,
                                                  float* __restrict__ hcont) {
  int p0 = blockIdx.x * 2;
  int tid = threadIdx.x;
  __shared__ float el[2 * 128];
  __shared__ float dts[2];
  __shared__ float hl[2 * 256];
  __shared__ float hd[2 * 256];
  const int c0 = tid, c1 = tid + 256, c2 = tid + 512;
  float bz = bg[c0], br = bg[c1], bn = bg[c2], wtc = wt[tid];
  hl[tid] = 0.f;
  hl[256 + tid] = 0.f;
  __syncthreads();
  for (int t = 0; t < 128; ++t) {
    {
      int r = tid >> 7, d = tid & 127;
      el[tid] = __bfloat162float(ec[((size_t)(p0 + r) * 128 + t) * DD + d]);
    }
    if (tid < 2) dts[tid] = dtc[(p0 + tid) * 128 + t];
    __syncthreads();
    hd[tid] = hl[tid] * expf(-fmaxf(dts[0] * wtc, 0.f));
    hd[256 + tid] = hl[256 + tid] * expf(-fmaxf(dts[1] * wtc, 0.f));
    __syncthreads();
    float g[2][3], u[2][3];
#pragma unroll
    for (int r = 0; r < 2; ++r) {
      g[r][0] = g[r][1] = g[r][2] = 0.f;
      u[r][0] = u[r][1] = u[r][2] = 0.f;
    }
    for (int k = 0; k < 128; ++k) {
      float w0 = W[k * 768 + c0], w1 = W[k * 768 + c1], w2 = W[k * 768 + c2];
      float e0 = el[k], e1 = el[128 + k];
      g[0][0] = fmaf(e0, w0, g[0][0]);
      g[0][1] = fmaf(e0, w1, g[0][1]);
      g[0][2] = fmaf(e0, w2, g[0][2]);
      g[1][0] = fmaf(e1, w0, g[1][0]);
      g[1][1] = fmaf(e1, w1, g[1][1]);
      g[1][2] = fmaf(e1, w2, g[1][2]);
    }
    for (int k = 0; k < 256; ++k) {
      float u0 = U[k * 768 + c0], u1 = U[k * 768 + c1], u2 = U[k * 768 + c2];
      float h0 = hd[k], h1 = hd[256 + k];
      u[0][0] = fmaf(h0, u0, u[0][0]);
      u[0][1] = fmaf(h0, u1, u[0][1]);
      u[0][2] = fmaf(h0, u2, u[0][2]);
      u[1][0] = fmaf(h1, u0, u[1][0]);
      u[1][1] = fmaf(h1, u1, u[1][1]);
      u[1][2] = fmaf(h1, u2, u[1][2]);
    }
#pragma unroll
    for (int r = 0; r < 2; ++r) {
      float z = 1.f / (1.f + expf(-(g[r][0] + bz + u[r][0])));
      float rr = 1.f / (1.f + expf(-(g[r][1] + br + u[r][1])));
      float nn = tanhf(g[r][2] + bn + rr * u[r][2]);
      float hdv = hd[r * 256 + tid];
      float hnew = (1.f - z) * hdv + z * nn;
      hl[r * 256 + tid] = hnew;
      if (t >= 124)
        hcont[((size_t)(p0 + r) * 4 + (t - 124)) * HH + tid] = hnew;
    }
    __syncthreads();
  }
}

__global__ __launch_bounds__(256) void k_att(const float* __restrict__ hmain,
                                             const float* __restrict__ xself,
                                             const float* __restrict__ hc,
                                             const float* __restrict__ Wv,
                                             const float* __restrict__ bv,
                                             float* __restrict__ hh) {
  int b = blockIdx.x, tid = threadIdx.x;
  __shared__ float hl[16 * 256];
  __shared__ float aa[16 * 4];
  for (int idx = tid; idx < 4096; idx += 256) hl[idx] = hmain[(size_t)b * SS * HH + idx];
  __syncthreads();
  if (tid < 64) {
    int s = tid >> 2, m = tid & 3;
    float acc = bv[m];
    for (int j = 0; j < 256; ++j)
      acc += hl[s * 256 + j] * Wv[j * 4 + m] + hl[j] * Wv[(256 + j) * 4 + m];
    aa[s * 4 + m] = tanhf(acc);
  }
  __syncthreads();
  if (tid < 4) {
    int m = tid;
    float mx = -1e30f;
    for (int s = 0; s < 16; ++s) mx = fmaxf(mx, aa[s * 4 + m]);
    float sum = 0.f;
    for (int s = 0; s < 16; ++s) sum += expf(aa[s * 4 + m] - mx);
    float inv = 1.f / sum;
    for (int s = 0; s < 16; ++s) aa[s * 4 + m] = expf(aa[s * 4 + m] - mx) * inv;
  }
  __syncthreads();
  float a0 = 0.f, a1 = 0.f, a2 = 0.f, a3 = 0.f;
  for (int s = 0; s < 16; ++s) {
    float hv = hl[s * 256 + tid];
    a0 = fmaf(aa[s * 4 + 0], hv, a0);
    a1 = fmaf(aa[s * 4 + 1], hv, a1);
    a2 = fmaf(aa[s * 4 + 2], hv, a2);
    a3 = fmaf(aa[s * 4 + 3], hv, a3);
  }
  float* hb = hh + (size_t)b * 1664;
  hb[384 + 0 * 256 + tid] = a0;
  hb[384 + 1 * 256 + tid] = a1;
  hb[384 + 2 * 256 + tid] = a2;
  hb[384 + 3 * 256 + tid] = a3;
  if (tid < 128) hb[tid] = xself[b * DD + tid];
  hb[128 + tid] = hl[tid];
  hb[1408 + tid] = hc[(size_t)b * HH + tid];
}

__global__ __launch_bounds__(256) void k_mlp(const float* __restrict__ A,
                                             const float* __restrict__ W,
                                             const float* __restrict__ bias,
                                             float* __restrict__ C, int K, int N) {
  int tid = threadIdx.x;
  int j = blockIdx.x * 256 + tid;
  int rb = blockIdx.y * 16;
  __shared__ float al[16 * 512];
  float acc[16];
#pragma unroll
  for (int r = 0; r < 16; ++r) acc[r] = 0.f;
  for (int kc = 0; kc < K; kc += 512) {
    int ch = K - kc;
    if (ch > 512) ch = 512;
    __syncthreads();
#pragma unroll
    for (int r = 0; r < 16; ++r)
      for (int k = tid; k < ch; k += 256) al[r * 512 + k] = A[(size_t)(rb + r) * K + kc + k];
    __syncthreads();
    for (int k = 0; k < ch; ++k) {
      float w = W[(size_t)(kc + k) * N + j];
#pragma unroll
      for (int r = 0; r < 16; ++r) acc[r] = fmaf(al[r * 512 + k], w, acc[r]);
    }
  }
  float bj = bias[j];
#pragma unroll
  for (int r = 0; r < 16; ++r) {
    float v = acc[r] + bj;
    C[(size_t)(rb + r) * N + j] = v > 0.f ? v : 0.01f * v;
  }
}

__global__ __launch_bounds__(64) void k_head(const float* __restrict__ A,
                                             const float* __restrict__ Wp,
                                             const float* __restrict__ bp,
                                             float* __restrict__ out) {
  int row = blockIdx.x, l = threadIdx.x;
  float acc = 0.f;
  for (int j = l; j < 256; j += 64) acc = fmaf(A[(size_t)row * 256 + j], Wp[j], acc);
  for (int o = 32; o; o >>= 1) acc += __shfl_xor(acc, o);
  if (l == 0) out[row] = 1.f / (1.f + expf(-(acc + bp[0])));
}

extern "C" void kernel_launch(void* const* d_in, const int* in_sizes, int n_in,
                              void* d_out, int out_size, void* d_ws, size_t ws_size,
                              hipStream_t stream) {
  const int* x = (const int*)d_in[0];
  const int* xc = (const int*)d_in[1];
  const int* self_loc = (const int*)d_in[2];
  const float* emb = (const float*)d_in[3];
  const float* W_rnn = (const float*)d_in[4];
  const float* U_rnn = (const float*)d_in[5];
  const float* b_rnn = (const float*)d_in[6];
  const float* wt_rnn = (const float*)d_in[7];
  const float* W_c = (const float*)d_in[8];
  const float* U_c = (const float*)d_in[9];
  const float* b_c = (const float*)d_in[10];
  const float* wt_c = (const float*)d_in[11];
  const float* Wv = (const float*)d_in[12];
  const float* bv = (const float*)d_in[13];
  const float* W0 = (const float*)d_in[14];
  const float* b0 = (const float*)d_in[15];
  const float* W1 = (const float*)d_in[16];
  const float* b1 = (const float*)d_in[17];
  const float* W2 = (const float*)d_in[18];
  const float* b2 = (const float*)d_in[19];
  const float* Wp = (const float*)d_in[20];
  const float* bp = (const float*)d_in[21];
  float* out = (float*)d_out;

  char* ws = (char*)d_ws;
  size_t cur = 0;
  auto alloc = [&](size_t bytes) {
    char* p = ws + cur;
    cur += (bytes + 255) & ~(size_t)255;
    return p;
  };
  float* es = (float*)alloc(BB * DD * 4);
  float* ns = (float*)alloc(BB * 4);
  unsigned* minu = (unsigned*)alloc(4);
  float* simw = (float*)alloc((size_t)BB * SS * II * 4);
  int* topidx = (int*)alloc((size_t)BB * SS * KK * 4);
  float* xself = (float*)alloc(BB * DD * 4);
  float* dtm = (float*)alloc((size_t)KK * 8192 * 4);
  float* dtc = (float*)alloc((size_t)128 * 128 * 4);
  float* hcont = (float*)alloc((size_t)BB * HH * 4);
  float* hh = (float*)alloc((size_t)BB * 1664 * 4);
  float* z0 = (float*)alloc((size_t)BB * 1024 * 4);
  float* z1 = (float*)alloc((size_t)BB * 512 * 4);
  float* z2 = (float*)alloc((size_t)BB * 256 * 4);
  float* hmain = (float*)alloc((size_t)8192 * HH * 4);
  __hip_bfloat16* ec = (__hip_bfloat16*)alloc((size_t)128 * 128 * DD * 2);
  __hip_bfloat16* em = (__hip_bfloat16*)alloc((size_t)KK * 8192 * DD * 2);
  (void)ws_size;

  hipLaunchKernelGGL(k_init, dim3(1), dim3(1), 0, stream, minu);
  hipLaunchKernelGGL(k_eself, dim3(BB), dim3(128), 0, stream, x, self_loc, emb, es, ns);
  hipLaunchKernelGGL(k_cos, dim3(BB * SS), dim3(256), 0, stream, x, emb, es, ns, simw, minu);
  hipLaunchKernelGGL(k_topk, dim3(BB * SS), dim3(64), 0, stream, x, simw, minu, topidx);
  hipLaunchKernelGGL(k_build_main, dim3(8192, KK), dim3(128), 0, stream, x, self_loc, emb,
                     topidx, em, dtm, xself);
  hipLaunchKernelGGL(k_build_cont, dim3(128, 128), dim3(128), 0, stream, xc, emb, ec, dtc);
  hipLaunchKernelGGL(k_rnn_main, dim3(BB), dim3(256), 0, stream, em, dtm, xself, W_rnn,
                     U_rnn, b_rnn, wt_rnn, hmain);
  hipLaunchKernelGGL(k_rnn_cont, dim3(64), dim3(256), 0, stream, ec, dtc, W_c, U_c, b_c,
                     wt_c, hcont);
  hipLaunchKernelGGL(k_att, dim3(BB), dim3(256), 0, stream, hmain, xself, hcont, Wv, bv, hh);
  hipLaunchKernelGGL(k_mlp, dim3(4, 32), dim3(256), 0, stream, hh, W0, b0, z0, 1664, 1024);
  hipLaunchKernelGGL(k_mlp, dim3(2, 32), dim3(256), 0, stream, z0, W1, b1, z1, 1024, 512);
  hipLaunchKernelGGL(k_mlp, dim3(1, 32), dim3(256), 0, stream, z1, W2, b2, z2, 512, 256);
  hipLaunchKernelGGL(k_head, dim3(BB), dim3(64), 0, stream, z2, Wp, bp, out);
}

// Round 2
// 2441.026 us; speedup vs baseline: 2.0239x; 2.0239x over previous
//
#include <hip/hip_runtime.h>
#include <hip/hip_bf16.h>

// SearchPredictModel round 2: MFMA time-decay GRUs.
//  - main RNN: 256 blocks x (M=32 rows), 8 waves x 32 gate-cols, per-step
//    e-GEMM (K=128) + u-GEMM (K=256 from XOR-swizzled LDS bf16 h), gs hoisted.
//  - cont RNN: g precomputed time-parallel into G (bf16); sequential loop is
//    u-GEMM only with U_c fragments persistent in VGPRs (8 blocks x M=16).

#define PAD_TOK 200000
#define DD 128
#define HH 256
#define KK 15
#define BB 512
#define SS 16
#define II 64

typedef __bf16 bf16x8 __attribute__((ext_vector_type(8)));
typedef float f32x4 __attribute__((ext_vector_type(4)));
#define MFMA16 __builtin_amdgcn_mfma_f32_16x16x32_bf16

__device__ __forceinline__ float sigm(float x) { return 1.f / (1.f + __expf(-x)); }
__device__ __forceinline__ float tanh_fast(float x) {
  x = fminf(fmaxf(x, -15.f), 15.f);
  float e2 = __expf(2.f * x);
  return (e2 - 1.f) / (e2 + 1.f);
}

// ---------------------------------------------------------------- front end
__global__ __launch_bounds__(128) void k_eself(const int* __restrict__ x,
                                               const int* __restrict__ self_loc,
                                               const float* __restrict__ emb,
                                               float* __restrict__ es,
                                               float* __restrict__ ns) {
  int b = blockIdx.x, d = threadIdx.x;
  int tok = x[((size_t)(b * SS + 0) * II + self_loc[b]) * 8 + 5];
  float v = emb[(size_t)tok * DD + d];
  es[b * DD + d] = v;
  __shared__ float red[128];
  red[d] = v * v;
  __syncthreads();
  for (int o = 64; o > 0; o >>= 1) {
    if (d < o) red[d] += red[d + o];
    __syncthreads();
  }
  if (d == 0) ns[b] = fmaxf(sqrtf(red[0]), 1e-8f);
}

__global__ void k_init(unsigned* minu) { *minu = 0xFFFFFFFFu; }

__global__ __launch_bounds__(256) void k_cos(const int* __restrict__ x,
                                             const float* __restrict__ emb,
                                             const float* __restrict__ es,
                                             const float* __restrict__ ns,
                                             float* __restrict__ simw,
                                             unsigned* __restrict__ minu) {
  int row = blockIdx.x;  // b*16+s
  int b = row >> 4;
  int tid = threadIdx.x, wave = tid >> 6, lane = tid & 63;
  const float2 ev = reinterpret_cast<const float2*>(es + b * DD)[lane];
  float nsb = ns[b];
  unsigned localmin = 0xFFFFFFFFu;
  for (int it = 0; it < 16; ++it) {
    int i = wave * 16 + it;
    const int* xr = x + ((size_t)row * II + i) * 8;
    int tok = xr[5];
    float2 a = *reinterpret_cast<const float2*>(emb + (size_t)tok * DD + lane * 2);
    float dot = a.x * ev.x + a.y * ev.y;
    float ss = a.x * a.x + a.y * a.y;
    for (int o = 32; o; o >>= 1) {
      dot += __shfl_xor(dot, o);
      ss += __shfl_xor(ss, o);
    }
    if (lane == 0) {
      float cosv = dot / (fmaxf(sqrtf(ss), 1e-8f) * nsb);
      simw[(size_t)row * II + i] = cosv;
      if (xr[0] != PAD_TOK) {
        unsigned u = __float_as_uint(cosv);
        unsigned key = (cosv < 0.f) ? ~u : (u | 0x80000000u);
        localmin = min(localmin, key);
      }
    }
  }
  if (lane == 0 && localmin != 0xFFFFFFFFu) atomicMin(minu, localmin);
}

__global__ __launch_bounds__(64) void k_topk(const int* __restrict__ x,
                                             const float* __restrict__ simw,
                                             const unsigned* __restrict__ minu,
                                             int* __restrict__ topidx) {
  int row = blockIdx.x, i = threadIdx.x;
  unsigned mk = *minu;
  float neg = ((mk & 0x80000000u) ? __uint_as_float(mk ^ 0x80000000u) : __uint_as_float(~mk)) - 1.0f;
  float c = simw[(size_t)row * II + i];
  bool real = x[((size_t)row * II + i) * 8] != PAD_TOK;
  float s = real ? c : neg;
  __shared__ float sv[64];
  sv[i] = s;
  __syncthreads();
  int rank = 0;
  for (int j = 0; j < 64; ++j) {
    float o = sv[j];
    rank += (o > s) || (o == s && j < i);
  }
  bool sel = rank < KK;
  unsigned long long mask = __ballot(sel);
  if (sel) {
    int pos = __popcll(mask & ((1ull << i) - 1ull));
    topidx[row * KK + pos] = i;
  }
}

__global__ __launch_bounds__(128) void k_build_main(const int* __restrict__ x,
                                                    const int* __restrict__ self_loc,
                                                    const float* __restrict__ emb,
                                                    const int* __restrict__ topidx,
                                                    __hip_bfloat16* __restrict__ em,
                                                    float* __restrict__ dtm,
                                                    float* __restrict__ xself,
                                                    __bf16* __restrict__ xself_bf) {
  int n = blockIdx.x, t = blockIdx.y, d = threadIdx.x;
  int b = n >> 4, s = n & 15;
  bool ovr = (s == 0) && (t == KK - 1);
  int item = ovr ? self_loc[b] : topidx[n * KK + t];
  const int* xr = x + ((size_t)n * II + item) * 8;
  float acc = 0.f;
#pragma unroll
  for (int jj = 0; jj < 6; ++jj) acc += emb[(size_t)xr[jj] * DD + d];
  em[((size_t)t * 8192 + n) * DD + d] = __float2bfloat16(acc);
  if (ovr) {
    xself[b * DD + d] = acc;
    xself_bf[b * DD + d] = (__bf16)acc;
  }
  if (d == 0) {
    float dtv = 0.f;
    if (t > 0) {
      int pitem = topidx[n * KK + t - 1];
      dtv = (float)xr[6] - (float)x[((size_t)n * II + pitem) * 8 + 6];
    }
    dtm[t * 8192 + n] = dtv;
  }
}

__global__ __launch_bounds__(128) void k_build_cont(const int* __restrict__ xc,
                                                    const float* __restrict__ emb,
                                                    __hip_bfloat16* __restrict__ ec,
                                                    float* __restrict__ dtc) {
  int p = blockIdx.x, t = blockIdx.y, d = threadIdx.x;
  const int* xr = xc + ((size_t)p * 128 + t) * 8;
  float acc = 0.f;
#pragma unroll
  for (int jj = 0; jj < 6; ++jj) acc += emb[(size_t)xr[jj] * DD + d];
  ec[((size_t)p * 128 + t) * DD + d] = __float2bfloat16(acc);
  if (d == 0) dtc[p * 128 + t] = (t > 0) ? ((float)xr[6] - (float)xr[-2]) : 0.f;
}

// ------------------------------------------------- weight fragment packing
// out[((kt*48+tile)*64+lane)*8 + i] = B[(kt*32+(lane>>4)*8+i)*768 + tile*16+(lane&15)]
__global__ __launch_bounds__(64) void k_pack(const float* __restrict__ B,
                                             __bf16* __restrict__ out) {
  int kt = blockIdx.x, tile = blockIdx.y, lane = threadIdx.x;
  const float* src = B + (size_t)(kt * 32 + (lane >> 4) * 8) * 768 + tile * 16 + (lane & 15);
  __bf16* o = out + (((size_t)(kt * 48 + tile) * 64 + lane) * 8);
#pragma unroll
  for (int i = 0; i < 8; ++i) o[i] = (__bf16)src[(size_t)i * 768];
}

// --------------------------------------- cont-RNN g precompute: G = ec@Wc + b
__global__ __launch_bounds__(512) void k_gemm_g(const __hip_bfloat16* __restrict__ A,
                                                const __bf16* __restrict__ pB,
                                                const float* __restrict__ bias,
                                                __bf16* __restrict__ G) {
  const int wv = threadIdx.x >> 6, lane = threadIdx.x & 63;
  const int lr = lane & 15, lg = lane >> 4;
  const int r0 = blockIdx.x * 32;
  f32x4 z4 = {0.f, 0.f, 0.f, 0.f};
  f32x4 acc[2][6];
#pragma unroll
  for (int mt = 0; mt < 2; ++mt)
#pragma unroll
    for (int n = 0; n < 6; ++n) acc[mt][n] = z4;
#pragma unroll
  for (int kt = 0; kt < 4; ++kt) {
    bf16x8 a[2];
#pragma unroll
    for (int mt = 0; mt < 2; ++mt)
      a[mt] = *(const bf16x8*)(A + (size_t)(r0 + mt * 16 + lr) * 128 + kt * 32 + lg * 8);
#pragma unroll
    for (int n = 0; n < 6; ++n) {
      bf16x8 b = *(const bf16x8*)(pB + (((size_t)kt * 48 + wv * 6 + n) * 64 + lane) * 8);
      acc[0][n] = MFMA16(a[0], b, acc[0][n], 0, 0, 0);
      acc[1][n] = MFMA16(a[1], b, acc[1][n], 0, 0, 0);
    }
  }
#pragma unroll
  for (int mt = 0; mt < 2; ++mt)
#pragma unroll
    for (int n = 0; n < 6; ++n) {
      int col = wv * 96 + n * 16 + lr;
      float bc = bias[col];
#pragma unroll
      for (int r = 0; r < 4; ++r) {
        int row = r0 + mt * 16 + lg * 4 + r;
        G[(size_t)row * 768 + col] = (__bf16)(acc[mt][n][r] + bc);
      }
    }
}

// ------------------------------------------------------------ main RNN MFMA
__global__ __launch_bounds__(512, 2) void k_rnn_main_mfma(
    const __hip_bfloat16* __restrict__ em, const float* __restrict__ dtm,
    const __bf16* __restrict__ xself_bf, const __bf16* __restrict__ pWs,
    const __bf16* __restrict__ pWe, const __bf16* __restrict__ pU,
    const float* __restrict__ bg, const float* __restrict__ wt,
    float* __restrict__ hmain) {
  const int wv = threadIdx.x >> 6, lane = threadIdx.x & 63;
  const int lr = lane & 15, lg = lane >> 4;
  const int n0 = blockIdx.x * 32;
  __shared__ __align__(16) __bf16 hbuf[32 * 256];
  f32x4 z4 = {0.f, 0.f, 0.f, 0.f};

  float bz[2], br[2], bn[2], wtv[2];
#pragma unroll
  for (int nt = 0; nt < 2; ++nt) {
    int c = wv * 32 + nt * 16 + lr;
    bz[nt] = bg[c];
    br[nt] = bg[c + 256];
    bn[nt] = bg[c + 512];
    wtv[nt] = wt[c];
  }

  // gs = xself @ W[0:128]  (constant over t)
  f32x4 gs[3][2][2];
#pragma unroll
  for (int g = 0; g < 3; ++g)
#pragma unroll
    for (int mt = 0; mt < 2; ++mt)
#pragma unroll
      for (int nt = 0; nt < 2; ++nt) gs[g][mt][nt] = z4;
#pragma unroll
  for (int kt = 0; kt < 4; ++kt) {
    bf16x8 a[2];
#pragma unroll
    for (int mt = 0; mt < 2; ++mt)
      a[mt] = *(const bf16x8*)(xself_bf + (size_t)((n0 + mt * 16) >> 4) * 128 + kt * 32 + lg * 8);
#pragma unroll
    for (int g = 0; g < 3; ++g)
#pragma unroll
      for (int nt = 0; nt < 2; ++nt) {
        bf16x8 b = *(const bf16x8*)(pWs + (((size_t)kt * 48 + g * 16 + wv * 2 + nt) * 64 + lane) * 8);
#pragma unroll
        for (int mt = 0; mt < 2; ++mt) gs[g][mt][nt] = MFMA16(a[mt], b, gs[g][mt][nt], 0, 0, 0);
      }
  }

  float h[2][2][4];
#pragma unroll
  for (int mt = 0; mt < 2; ++mt)
#pragma unroll
    for (int nt = 0; nt < 2; ++nt)
#pragma unroll
      for (int r = 0; r < 4; ++r) h[mt][nt][r] = 0.f;

  for (int t = 0; t < KK; ++t) {
    // hd = h * decay(dt[t])
    float hd[2][2][4];
#pragma unroll
    for (int mt = 0; mt < 2; ++mt)
#pragma unroll
      for (int r = 0; r < 4; ++r) {
        float dtv = dtm[t * 8192 + n0 + mt * 16 + lg * 4 + r];
#pragma unroll
        for (int nt = 0; nt < 2; ++nt)
          hd[mt][nt][r] = h[mt][nt][r] * __expf(-fmaxf(dtv * wtv[nt], 0.f));
      }
    __syncthreads();  // prev-step hbuf reads done
#pragma unroll
    for (int mt = 0; mt < 2; ++mt)
#pragma unroll
      for (int nt = 0; nt < 2; ++nt)
#pragma unroll
        for (int r = 0; r < 4; ++r) {
          int row = mt * 16 + lg * 4 + r;
          hbuf[((row * 256) + (wv * 32 + nt * 16 + lr)) ^ ((row & 7) << 3)] = (__bf16)hd[mt][nt][r];
        }
    __syncthreads();

    // acc: 0=z(g+u), 1=r(g+u), 2=g_n, 3=u_n
    f32x4 acc[4][2][2];
#pragma unroll
    for (int mt = 0; mt < 2; ++mt)
#pragma unroll
      for (int nt = 0; nt < 2; ++nt) {
        acc[0][mt][nt] = gs[0][mt][nt];
        acc[1][mt][nt] = gs[1][mt][nt];
        acc[2][mt][nt] = gs[2][mt][nt];
        acc[3][mt][nt] = z4;
      }
    // e-GEMM (K=128)
#pragma unroll
    for (int kt = 0; kt < 4; ++kt) {
      bf16x8 a[2];
#pragma unroll
      for (int mt = 0; mt < 2; ++mt)
        a[mt] = *(const bf16x8*)(em + ((size_t)t * 8192 + n0 + mt * 16 + lr) * 128 + kt * 32 + lg * 8);
#pragma unroll
      for (int g = 0; g < 3; ++g)
#pragma unroll
        for (int nt = 0; nt < 2; ++nt) {
          bf16x8 b = *(const bf16x8*)(pWe + (((size_t)kt * 48 + g * 16 + wv * 2 + nt) * 64 + lane) * 8);
#pragma unroll
          for (int mt = 0; mt < 2; ++mt) acc[g][mt][nt] = MFMA16(a[mt], b, acc[g][mt][nt], 0, 0, 0);
        }
    }
    // u-GEMM (K=256) from LDS hd
#pragma unroll
    for (int kt = 0; kt < 8; ++kt) {
      bf16x8 a[2];
#pragma unroll
      for (int mt = 0; mt < 2; ++mt) {
        int row = mt * 16 + lr;
        int s = ((row * 256) + (kt * 32 + lg * 8)) ^ ((row & 7) << 3);
        a[mt] = *(const bf16x8*)&hbuf[s];
      }
#pragma unroll
      for (int g = 0; g < 3; ++g) {
        const int ai = (g < 2) ? g : 3;
#pragma unroll
        for (int nt = 0; nt < 2; ++nt) {
          bf16x8 b = *(const bf16x8*)(pU + (((size_t)kt * 48 + g * 16 + wv * 2 + nt) * 64 + lane) * 8);
#pragma unroll
          for (int mt = 0; mt < 2; ++mt) acc[ai][mt][nt] = MFMA16(a[mt], b, acc[ai][mt][nt], 0, 0, 0);
        }
      }
    }
    // gates
#pragma unroll
    for (int mt = 0; mt < 2; ++mt)
#pragma unroll
      for (int nt = 0; nt < 2; ++nt)
#pragma unroll
        for (int r = 0; r < 4; ++r) {
          float zz = sigm(acc[0][mt][nt][r] + bz[nt]);
          float rr = sigm(acc[1][mt][nt][r] + br[nt]);
          float nn = tanh_fast(acc[2][mt][nt][r] + bn[nt] + rr * acc[3][mt][nt][r]);
          h[mt][nt][r] = (1.f - zz) * hd[mt][nt][r] + zz * nn;
        }
    __syncthreads();
  }
#pragma unroll
  for (int mt = 0; mt < 2; ++mt)
#pragma unroll
    for (int nt = 0; nt < 2; ++nt)
#pragma unroll
      for (int r = 0; r < 4; ++r)
        hmain[(size_t)(n0 + mt * 16 + lg * 4 + r) * 256 + wv * 32 + nt * 16 + lr] = h[mt][nt][r];
}

// ------------------------------------------------------------ cont RNN MFMA
__global__ __launch_bounds__(512, 2) void k_rnn_cont_mfma(const __bf16* __restrict__ G,
                                                          const float* __restrict__ dtc,
                                                          const __bf16* __restrict__ pUc,
                                                          const float* __restrict__ wt,
                                                          float* __restrict__ hcont) {
  const int wv = threadIdx.x >> 6, lane = threadIdx.x & 63;
  const int lr = lane & 15, lg = lane >> 4;
  const int p0 = blockIdx.x * 16;
  __shared__ __align__(16) __bf16 hbuf[16 * 256];
  float wtv[2];
#pragma unroll
  for (int nt = 0; nt < 2; ++nt) wtv[nt] = wt[wv * 32 + nt * 16 + lr];
  // persistent U_c fragments: [gate][nt][kt]  (192 VGPR)
  bf16x8 bfr[3][2][8];
#pragma unroll
  for (int g = 0; g < 3; ++g)
#pragma unroll
    for (int nt = 0; nt < 2; ++nt)
#pragma unroll
      for (int kt = 0; kt < 8; ++kt)
        bfr[g][nt][kt] =
            *(const bf16x8*)(pUc + (((size_t)kt * 48 + g * 16 + wv * 2 + nt) * 64 + lane) * 8);
  float h[2][4];
#pragma unroll
  for (int nt = 0; nt < 2; ++nt)
#pragma unroll
    for (int r = 0; r < 4; ++r) h[nt][r] = 0.f;

  for (int t = 0; t < 128; ++t) {
    float hd[2][4];
#pragma unroll
    for (int r = 0; r < 4; ++r) {
      float dtv = dtc[(p0 + lg * 4 + r) * 128 + t];
#pragma unroll
      for (int nt = 0; nt < 2; ++nt) hd[nt][r] = h[nt][r] * __expf(-fmaxf(dtv * wtv[nt], 0.f));
    }
    __syncthreads();
#pragma unroll
    for (int nt = 0; nt < 2; ++nt)
#pragma unroll
      for (int r = 0; r < 4; ++r) {
        int row = lg * 4 + r;
        hbuf[((row * 256) + (wv * 32 + nt * 16 + lr)) ^ ((row & 7) << 3)] = (__bf16)hd[nt][r];
      }
    __syncthreads();
    f32x4 acc[4][2];
#pragma unroll
    for (int nt = 0; nt < 2; ++nt) {
#pragma unroll
      for (int r = 0; r < 4; ++r) {
        size_t base = ((size_t)(p0 + lg * 4 + r) * 128 + t) * 768 + wv * 32 + nt * 16 + lr;
        acc[0][nt][r] = (float)G[base];
        acc[1][nt][r] = (float)G[base + 256];
        acc[2][nt][r] = (float)G[base + 512];
        acc[3][nt][r] = 0.f;
      }
    }
#pragma unroll
    for (int kt = 0; kt < 8; ++kt) {
      int s = ((lr * 256) + (kt * 32 + lg * 8)) ^ ((lr & 7) << 3);
      bf16x8 a = *(const bf16x8*)&hbuf[s];
#pragma unroll
      for (int nt = 0; nt < 2; ++nt) {
        acc[0][nt] = MFMA16(a, bfr[0][nt][kt], acc[0][nt], 0, 0, 0);
        acc[1][nt] = MFMA16(a, bfr[1][nt][kt], acc[1][nt], 0, 0, 0);
        acc[3][nt] = MFMA16(a, bfr[2][nt][kt], acc[3][nt], 0, 0, 0);
      }
    }
#pragma unroll
    for (int nt = 0; nt < 2; ++nt)
#pragma unroll
      for (int r = 0; r < 4; ++r) {
        float zz = sigm(acc[0][nt][r]);
        float rr = sigm(acc[1][nt][r]);
        float nn = tanh_fast(acc[2][nt][r] + rr * acc[3][nt][r]);
        float hnew = (1.f - zz) * hd[nt][r] + zz * nn;
        h[nt][r] = hnew;
        if (t >= 124)
          hcont[((size_t)(p0 + lg * 4 + r) * 4 + (t - 124)) * 256 + wv * 32 + nt * 16 + lr] = hnew;
      }
  }
}

// ------------------------------------------------------------------ tail
__global__ __launch_bounds__(256) void k_att(const float* __restrict__ hmain,
                                             const float* __restrict__ xself,
                                             const float* __restrict__ hc,
                                             const float* __restrict__ Wv,
                                             const float* __restrict__ bv,
                                             float* __restrict__ hh) {
  int b = blockIdx.x, tid = threadIdx.x;
  __shared__ float hl[16 * 256];
  __shared__ float aa[16 * 4];
  for (int idx = tid; idx < 4096; idx += 256) hl[idx] = hmain[(size_t)b * SS * HH + idx];
  __syncthreads();
  if (tid < 64) {
    int s = tid >> 2, m = tid & 3;
    float acc = bv[m];
    for (int j = 0; j < 256; ++j)
      acc += hl[s * 256 + j] * Wv[j * 4 + m] + hl[j] * Wv[(256 + j) * 4 + m];
    aa[s * 4 + m] = tanh_fast(acc);
  }
  __syncthreads();
  if (tid < 4) {
    int m = tid;
    float mx = -1e30f;
    for (int s = 0; s < 16; ++s) mx = fmaxf(mx, aa[s * 4 + m]);
    float sum = 0.f;
    for (int s = 0; s < 16; ++s) sum += __expf(aa[s * 4 + m] - mx);
    float inv = 1.f / sum;
    for (int s = 0; s < 16; ++s) aa[s * 4 + m] = __expf(aa[s * 4 + m] - mx) * inv;
  }
  __syncthreads();
  float a0 = 0.f, a1 = 0.f, a2 = 0.f, a3 = 0.f;
  for (int s = 0; s < 16; ++s) {
    float hv = hl[s * 256 + tid];
    a0 = fmaf(aa[s * 4 + 0], hv, a0);
    a1 = fmaf(aa[s * 4 + 1], hv, a1);
    a2 = fmaf(aa[s * 4 + 2], hv, a2);
    a3 = fmaf(aa[s * 4 + 3], hv, a3);
  }
  float* hb = hh + (size_t)b * 1664;
  hb[384 + 0 * 256 + tid] = a0;
  hb[384 + 1 * 256 + tid] = a1;
  hb[384 + 2 * 256 + tid] = a2;
  hb[384 + 3 * 256 + tid] = a3;
  if (tid < 128) hb[tid] = xself[b * DD + tid];
  hb[128 + tid] = hl[tid];
  hb[1408 + tid] = hc[(size_t)b * HH + tid];
}

__global__ __launch_bounds__(256) void k_mlp(const float* __restrict__ A,
                                             const float* __restrict__ W,
                                             const float* __restrict__ bias,
                                             float* __restrict__ C, int K, int N) {
  int tid = threadIdx.x;
  int j = blockIdx.x * 256 + tid;
  int rb = blockIdx.y * 16;
  __shared__ float al[16 * 512];
  float acc[16];
#pragma unroll
  for (int r = 0; r < 16; ++r) acc[r] = 0.f;
  for (int kc = 0; kc < K; kc += 512) {
    int ch = K - kc;
    if (ch > 512) ch = 512;
    __syncthreads();
#pragma unroll
    for (int r = 0; r < 16; ++r)
      for (int k = tid; k < ch; k += 256) al[r * 512 + k] = A[(size_t)(rb + r) * K + kc + k];
    __syncthreads();
    for (int k = 0; k < ch; ++k) {
      float w = W[(size_t)(kc + k) * N + j];
#pragma unroll
      for (int r = 0; r < 16; ++r) acc[r] = fmaf(al[r * 512 + k], w, acc[r]);
    }
  }
  float bj = bias[j];
#pragma unroll
  for (int r = 0; r < 16; ++r) {
    float v = acc[r] + bj;
    C[(size_t)(rb + r) * N + j] = v > 0.f ? v : 0.01f * v;
  }
}

__global__ __launch_bounds__(64) void k_head(const float* __restrict__ A,
                                             const float* __restrict__ Wp,
                                             const float* __restrict__ bp,
                                             float* __restrict__ out) {
  int row = blockIdx.x, l = threadIdx.x;
  float acc = 0.f;
  for (int j = l; j < 256; j += 64) acc = fmaf(A[(size_t)row * 256 + j], Wp[j], acc);
  for (int o = 32; o; o >>= 1) acc += __shfl_xor(acc, o);
  if (l == 0) out[row] = 1.f / (1.f + __expf(-(acc + bp[0])));
}

extern "C" void kernel_launch(void* const* d_in, const int* in_sizes, int n_in,
                              void* d_out, int out_size, void* d_ws, size_t ws_size,
                              hipStream_t stream) {
  const int* x = (const int*)d_in[0];
  const int* xc = (const int*)d_in[1];
  const int* self_loc = (const int*)d_in[2];
  const float* emb = (const float*)d_in[3];
  const float* W_rnn = (const float*)d_in[4];
  const float* U_rnn = (const float*)d_in[5];
  const float* b_rnn = (const float*)d_in[6];
  const float* wt_rnn = (const float*)d_in[7];
  const float* W_c = (const float*)d_in[8];
  const float* U_c = (const float*)d_in[9];
  const float* b_c = (const float*)d_in[10];
  const float* wt_c = (const float*)d_in[11];
  const float* Wv = (const float*)d_in[12];
  const float* bv = (const float*)d_in[13];
  const float* W0 = (const float*)d_in[14];
  const float* b0 = (const float*)d_in[15];
  const float* W1 = (const float*)d_in[16];
  const float* b1 = (const float*)d_in[17];
  const float* W2 = (const float*)d_in[18];
  const float* b2 = (const float*)d_in[19];
  const float* Wp = (const float*)d_in[20];
  const float* bp = (const float*)d_in[21];
  float* out = (float*)d_out;

  char* ws = (char*)d_ws;
  size_t cur = 0;
  auto alloc = [&](size_t bytes) {
    char* p = ws + cur;
    cur += (bytes + 255) & ~(size_t)255;
    return p;
  };
  float* es = (float*)alloc((size_t)BB * DD * 4);
  float* ns = (float*)alloc(BB * 4);
  unsigned* minu = (unsigned*)alloc(4);
  float* simw = (float*)alloc((size_t)BB * SS * II * 4);
  int* topidx = (int*)alloc((size_t)BB * SS * KK * 4);
  float* xself = (float*)alloc((size_t)BB * DD * 4);
  __bf16* xself_bf = (__bf16*)alloc((size_t)BB * DD * 2);
  float* dtm = (float*)alloc((size_t)KK * 8192 * 4);
  float* dtc = (float*)alloc((size_t)128 * 128 * 4);
  float* hcont = (float*)alloc((size_t)BB * HH * 4);
  float* hh = (float*)alloc((size_t)BB * 1664 * 4);
  float* z0 = (float*)alloc((size_t)BB * 1024 * 4);
  float* z1 = (float*)alloc((size_t)BB * 512 * 4);
  float* z2 = (float*)alloc((size_t)BB * 256 * 4);
  float* hmain = (float*)alloc((size_t)8192 * HH * 4);
  __hip_bfloat16* ec = (__hip_bfloat16*)alloc((size_t)16384 * DD * 2);
  __hip_bfloat16* em = (__hip_bfloat16*)alloc((size_t)KK * 8192 * DD * 2);
  __bf16* Gc = (__bf16*)alloc((size_t)16384 * 768 * 2);
  __bf16* pWs = (__bf16*)alloc((size_t)4 * 48 * 64 * 8 * 2);
  __bf16* pWe = (__bf16*)alloc((size_t)4 * 48 * 64 * 8 * 2);
  __bf16* pU = (__bf16*)alloc((size_t)8 * 48 * 64 * 8 * 2);
  __bf16* pWc = (__bf16*)alloc((size_t)4 * 48 * 64 * 8 * 2);
  __bf16* pUc = (__bf16*)alloc((size_t)8 * 48 * 64 * 8 * 2);
  (void)ws_size;

  hipLaunchKernelGGL(k_init, dim3(1), dim3(1), 0, stream, minu);
  hipLaunchKernelGGL(k_eself, dim3(BB), dim3(128), 0, stream, x, self_loc, emb, es, ns);
  hipLaunchKernelGGL(k_cos, dim3(BB * SS), dim3(256), 0, stream, x, emb, es, ns, simw, minu);
  hipLaunchKernelGGL(k_topk, dim3(BB * SS), dim3(64), 0, stream, x, simw, minu, topidx);
  hipLaunchKernelGGL(k_build_main, dim3(8192, KK), dim3(128), 0, stream, x, self_loc, emb,
                     topidx, em, dtm, xself, xself_bf);
  hipLaunchKernelGGL(k_build_cont, dim3(128, 128), dim3(128), 0, stream, xc, emb, ec, dtc);
  hipLaunchKernelGGL(k_pack, dim3(4, 48), dim3(64), 0, stream, W_rnn, pWs);
  hipLaunchKernelGGL(k_pack, dim3(4, 48), dim3(64), 0, stream, W_rnn + 128 * 768, pWe);
  hipLaunchKernelGGL(k_pack, dim3(8, 48), dim3(64), 0, stream, U_rnn, pU);
  hipLaunchKernelGGL(k_pack, dim3(4, 48), dim3(64), 0, stream, W_c, pWc);
  hipLaunchKernelGGL(k_pack, dim3(8, 48), dim3(64), 0, stream, U_c, pUc);
  hipLaunchKernelGGL(k_gemm_g, dim3(512), dim3(512), 0, stream, ec, pWc, b_c, Gc);
  hipLaunchKernelGGL(k_rnn_main_mfma, dim3(256), dim3(512), 0, stream, em, dtm, xself_bf,
                     pWs, pWe, pU, b_rnn, wt_rnn, hmain);
  hipLaunchKernelGGL(k_rnn_cont_mfma, dim3(8), dim3(512), 0, stream, Gc, dtc, pUc, wt_c,
                     hcont);
  hipLaunchKernelGGL(k_att, dim3(BB), dim3(256), 0, stream, hmain, xself, hcont, Wv, bv, hh);
  hipLaunchKernelGGL(k_mlp, dim3(4, 32), dim3(256), 0, stream, hh, W0, b0, z0, 1664, 1024);
  hipLaunchKernelGGL(k_mlp, dim3(2, 32), dim3(256), 0, stream, z0, W1, b1, z1, 1024, 512);
  hipLaunchKernelGGL(k_mlp, dim3(1, 32), dim3(256), 0, stream, z1, W2, b2, z2, 512, 256);
  hipLaunchKernelGGL(k_head, dim3(BB), dim3(64), 0, stream, z2, Wp, bp, out);
}

// Round 3
// 2178.651 us; speedup vs baseline: 2.2677x; 1.1204x over previous
//
#include <hip/hip_runtime.h>
#include <hip/hip_bf16.h>

// SearchPredictModel round 3: fix VGPR spills (waves_per_eu(2,2)), cont RNN
// restructured: packed-G fragment prefetch, single barrier/step, dt in LDS.

#define PAD_TOK 200000
#define DD 128
#define HH 256
#define KK 15
#define BB 512
#define SS 16
#define II 64

typedef __bf16 bf16x8 __attribute__((ext_vector_type(8)));
typedef float f32x4 __attribute__((ext_vector_type(4)));
#define MFMA16 __builtin_amdgcn_mfma_f32_16x16x32_bf16

__device__ __forceinline__ float sigm(float x) { return 1.f / (1.f + __expf(-x)); }
__device__ __forceinline__ float tanh_fast(float x) {
  x = fminf(fmaxf(x, -15.f), 15.f);
  float e2 = __expf(2.f * x);
  return (e2 - 1.f) / (e2 + 1.f);
}
__device__ __forceinline__ float bfu(unsigned u16) { return __uint_as_float(u16 << 16); }

// ---------------------------------------------------------------- front end
__global__ __launch_bounds__(128) void k_eself(const int* __restrict__ x,
                                               const int* __restrict__ self_loc,
                                               const float* __restrict__ emb,
                                               float* __restrict__ es,
                                               float* __restrict__ ns) {
  int b = blockIdx.x, d = threadIdx.x;
  int tok = x[((size_t)(b * SS + 0) * II + self_loc[b]) * 8 + 5];
  float v = emb[(size_t)tok * DD + d];
  es[b * DD + d] = v;
  __shared__ float red[128];
  red[d] = v * v;
  __syncthreads();
  for (int o = 64; o > 0; o >>= 1) {
    if (d < o) red[d] += red[d + o];
    __syncthreads();
  }
  if (d == 0) ns[b] = fmaxf(sqrtf(red[0]), 1e-8f);
}

__global__ void k_init(unsigned* minu) { *minu = 0xFFFFFFFFu; }

__global__ __launch_bounds__(256) void k_cos(const int* __restrict__ x,
                                             const float* __restrict__ emb,
                                             const float* __restrict__ es,
                                             const float* __restrict__ ns,
                                             float* __restrict__ simw,
                                             unsigned* __restrict__ minu) {
  int row = blockIdx.x;  // b*16+s
  int b = row >> 4;
  int tid = threadIdx.x, wave = tid >> 6, lane = tid & 63;
  const float2 ev = reinterpret_cast<const float2*>(es + b * DD)[lane];
  float nsb = ns[b];
  unsigned localmin = 0xFFFFFFFFu;
  for (int it = 0; it < 16; ++it) {
    int i = wave * 16 + it;
    const int* xr = x + ((size_t)row * II + i) * 8;
    int tok = xr[5];
    float2 a = *reinterpret_cast<const float2*>(emb + (size_t)tok * DD + lane * 2);
    float dot = a.x * ev.x + a.y * ev.y;
    float ss = a.x * a.x + a.y * a.y;
    for (int o = 32; o; o >>= 1) {
      dot += __shfl_xor(dot, o);
      ss += __shfl_xor(ss, o);
    }
    if (lane == 0) {
      float cosv = dot / (fmaxf(sqrtf(ss), 1e-8f) * nsb);
      simw[(size_t)row * II + i] = cosv;
      if (xr[0] != PAD_TOK) {
        unsigned u = __float_as_uint(cosv);
        unsigned key = (cosv < 0.f) ? ~u : (u | 0x80000000u);
        localmin = min(localmin, key);
      }
    }
  }
  if (lane == 0 && localmin != 0xFFFFFFFFu) atomicMin(minu, localmin);
}

__global__ __launch_bounds__(64) void k_topk(const int* __restrict__ x,
                                             const float* __restrict__ simw,
                                             const unsigned* __restrict__ minu,
                                             int* __restrict__ topidx) {
  int row = blockIdx.x, i = threadIdx.x;
  unsigned mk = *minu;
  float neg = ((mk & 0x80000000u) ? __uint_as_float(mk ^ 0x80000000u) : __uint_as_float(~mk)) - 1.0f;
  float c = simw[(size_t)row * II + i];
  bool real = x[((size_t)row * II + i) * 8] != PAD_TOK;
  float s = real ? c : neg;
  __shared__ float sv[64];
  sv[i] = s;
  __syncthreads();
  int rank = 0;
  for (int j = 0; j < 64; ++j) {
    float o = sv[j];
    rank += (o > s) || (o == s && j < i);
  }
  bool sel = rank < KK;
  unsigned long long mask = __ballot(sel);
  if (sel) {
    int pos = __popcll(mask & ((1ull << i) - 1ull));
    topidx[row * KK + pos] = i;
  }
}

__global__ __launch_bounds__(128) void k_build_main(const int* __restrict__ x,
                                                    const int* __restrict__ self_loc,
                                                    const float* __restrict__ emb,
                                                    const int* __restrict__ topidx,
                                                    __hip_bfloat16* __restrict__ em,
                                                    float* __restrict__ dtm,
                                                    float* __restrict__ xself,
                                                    __bf16* __restrict__ xself_bf) {
  int n = blockIdx.x, t = blockIdx.y, d = threadIdx.x;
  int b = n >> 4, s = n & 15;
  bool ovr = (s == 0) && (t == KK - 1);
  int item = ovr ? self_loc[b] : topidx[n * KK + t];
  const int* xr = x + ((size_t)n * II + item) * 8;
  float acc = 0.f;
#pragma unroll
  for (int jj = 0; jj < 6; ++jj) acc += emb[(size_t)xr[jj] * DD + d];
  em[((size_t)t * 8192 + n) * DD + d] = __float2bfloat16(acc);
  if (ovr) {
    xself[b * DD + d] = acc;
    xself_bf[b * DD + d] = (__bf16)acc;
  }
  if (d == 0) {
    float dtv = 0.f;
    if (t > 0) {
      int pitem = topidx[n * KK + t - 1];
      dtv = (float)xr[6] - (float)x[((size_t)n * II + pitem) * 8 + 6];
    }
    dtm[t * 8192 + n] = dtv;
  }
}

__global__ __launch_bounds__(128) void k_build_cont(const int* __restrict__ xc,
                                                    const float* __restrict__ emb,
                                                    __hip_bfloat16* __restrict__ ec,
                                                    float* __restrict__ dtc) {
  int p = blockIdx.x, t = blockIdx.y, d = threadIdx.x;
  const int* xr = xc + ((size_t)p * 128 + t) * 8;
  float acc = 0.f;
#pragma unroll
  for (int jj = 0; jj < 6; ++jj) acc += emb[(size_t)xr[jj] * DD + d];
  ec[((size_t)p * 128 + t) * DD + d] = __float2bfloat16(acc);
  if (d == 0) dtc[p * 128 + t] = (t > 0) ? ((float)xr[6] - (float)xr[-2]) : 0.f;
}

// ------------------------------------------------- weight fragment packing
__global__ __launch_bounds__(64) void k_pack(const float* __restrict__ B,
                                             __bf16* __restrict__ out) {
  int kt = blockIdx.x, tile = blockIdx.y, lane = threadIdx.x;
  const float* src = B + (size_t)(kt * 32 + (lane >> 4) * 8) * 768 + tile * 16 + (lane & 15);
  __bf16* o = out + (((size_t)(kt * 48 + tile) * 64 + lane) * 8);
#pragma unroll
  for (int i = 0; i < 8; ++i) o[i] = (__bf16)src[(size_t)i * 768];
}

// -------- cont-RNN g precompute: G2 (fragment-packed) = ec@Wc + b
// G2[rowflat*1024 + wvc*128 + lr*8 + gate*2 + nt], rowflat = p*128+t
__global__ __launch_bounds__(512) void k_gemm_g(const __hip_bfloat16* __restrict__ A,
                                                const __bf16* __restrict__ pB,
                                                const float* __restrict__ bias,
                                                __bf16* __restrict__ G2) {
  const int wv = threadIdx.x >> 6, lane = threadIdx.x & 63;
  const int lr = lane & 15, lg = lane >> 4;
  const int r0 = blockIdx.x * 32;
  f32x4 z4 = {0.f, 0.f, 0.f, 0.f};
  f32x4 acc[2][6];
#pragma unroll
  for (int mt = 0; mt < 2; ++mt)
#pragma unroll
    for (int n = 0; n < 6; ++n) acc[mt][n] = z4;
#pragma unroll
  for (int kt = 0; kt < 4; ++kt) {
    bf16x8 a[2];
#pragma unroll
    for (int mt = 0; mt < 2; ++mt)
      a[mt] = *(const bf16x8*)(A + (size_t)(r0 + mt * 16 + lr) * 128 + kt * 32 + lg * 8);
#pragma unroll
    for (int n = 0; n < 6; ++n) {
      bf16x8 b = *(const bf16x8*)(pB + (((size_t)kt * 48 + wv * 6 + n) * 64 + lane) * 8);
      acc[0][n] = MFMA16(a[0], b, acc[0][n], 0, 0, 0);
      acc[1][n] = MFMA16(a[1], b, acc[1][n], 0, 0, 0);
    }
  }
#pragma unroll
  for (int mt = 0; mt < 2; ++mt)
#pragma unroll
    for (int n = 0; n < 6; ++n) {
      int col = wv * 96 + n * 16 + lr;
      int gate = col >> 8, wvc = (col >> 5) & 7, nt = (col >> 4) & 1;
      float bc = bias[col];
#pragma unroll
      for (int r = 0; r < 4; ++r) {
        int row = r0 + mt * 16 + lg * 4 + r;
        G2[(size_t)row * 1024 + wvc * 128 + lr * 8 + gate * 2 + nt] = (__bf16)(acc[mt][n][r] + bc);
      }
    }
}

// ------------------------------------------------------------ main RNN MFMA
__global__ __launch_bounds__(512, 2) __attribute__((amdgpu_waves_per_eu(2, 2)))
void k_rnn_main_mfma(const __hip_bfloat16* __restrict__ em, const float* __restrict__ dtm,
                     const __bf16* __restrict__ xself_bf, const __bf16* __restrict__ pWs,
                     const __bf16* __restrict__ pWe, const __bf16* __restrict__ pU,
                     const float* __restrict__ bg, const float* __restrict__ wt,
                     float* __restrict__ hmain) {
  const int wv = threadIdx.x >> 6, lane = threadIdx.x & 63;
  const int lr = lane & 15, lg = lane >> 4;
  const int n0 = blockIdx.x * 32;
  __shared__ __align__(16) __bf16 hbuf[2][32 * 256];  // 32 KB
  __shared__ float dl[KK * 32];                       // 1.9 KB
  f32x4 z4 = {0.f, 0.f, 0.f, 0.f};

  for (int idx = threadIdx.x; idx < KK * 32; idx += 512)
    dl[idx] = dtm[(idx >> 5) * 8192 + n0 + (idx & 31)];

  float bz[2], br[2], bn[2], wtv[2];
#pragma unroll
  for (int nt = 0; nt < 2; ++nt) {
    int c = wv * 32 + nt * 16 + lr;
    bz[nt] = bg[c];
    br[nt] = bg[c + 256];
    bn[nt] = bg[c + 512];
    wtv[nt] = wt[c];
  }

  // gs = xself @ W[0:128]  (constant over t; rows within a 16-tile share b)
  f32x4 gs[3][2][2];
#pragma unroll
  for (int g = 0; g < 3; ++g)
#pragma unroll
    for (int mt = 0; mt < 2; ++mt)
#pragma unroll
      for (int nt = 0; nt < 2; ++nt) gs[g][mt][nt] = z4;
#pragma unroll
  for (int kt = 0; kt < 4; ++kt) {
    bf16x8 a[2];
#pragma unroll
    for (int mt = 0; mt < 2; ++mt)
      a[mt] = *(const bf16x8*)(xself_bf + (size_t)((n0 + mt * 16) >> 4) * 128 + kt * 32 + lg * 8);
#pragma unroll
    for (int g = 0; g < 3; ++g)
#pragma unroll
      for (int nt = 0; nt < 2; ++nt) {
        bf16x8 b = *(const bf16x8*)(pWs + (((size_t)kt * 48 + g * 16 + wv * 2 + nt) * 64 + lane) * 8);
#pragma unroll
        for (int mt = 0; mt < 2; ++mt) gs[g][mt][nt] = MFMA16(a[mt], b, gs[g][mt][nt], 0, 0, 0);
      }
  }

  float h[2][2][4];
#pragma unroll
  for (int mt = 0; mt < 2; ++mt)
#pragma unroll
    for (int nt = 0; nt < 2; ++nt)
#pragma unroll
      for (int r = 0; r < 4; ++r) h[mt][nt][r] = 0.f;
  __syncthreads();

  for (int t = 0; t < KK; ++t) {
    __bf16* hb = hbuf[t & 1];
    float hd[2][2][4];
#pragma unroll
    for (int mt = 0; mt < 2; ++mt)
#pragma unroll
      for (int r = 0; r < 4; ++r) {
        float dtv = dl[t * 32 + mt * 16 + lg * 4 + r];
#pragma unroll
        for (int nt = 0; nt < 2; ++nt)
          hd[mt][nt][r] = h[mt][nt][r] * __expf(-fmaxf(dtv * wtv[nt], 0.f));
      }
#pragma unroll
    for (int mt = 0; mt < 2; ++mt)
#pragma unroll
      for (int nt = 0; nt < 2; ++nt)
#pragma unroll
        for (int r = 0; r < 4; ++r) {
          int row = mt * 16 + lg * 4 + r;
          hb[((row * 256) + (wv * 32 + nt * 16 + lr)) ^ ((row & 7) << 3)] = (__bf16)hd[mt][nt][r];
        }
    __syncthreads();

    // acc: 0=z(g+u), 1=r(g+u), 2=g_n, 3=u_n
    f32x4 acc[4][2][2];
#pragma unroll
    for (int mt = 0; mt < 2; ++mt)
#pragma unroll
      for (int nt = 0; nt < 2; ++nt) {
        acc[0][mt][nt] = gs[0][mt][nt];
        acc[1][mt][nt] = gs[1][mt][nt];
        acc[2][mt][nt] = gs[2][mt][nt];
        acc[3][mt][nt] = z4;
      }
    // issue em A-frag loads early; their latency hides under the u-GEMM
    bf16x8 ae[2][4];
#pragma unroll
    for (int kt = 0; kt < 4; ++kt)
#pragma unroll
      for (int mt = 0; mt < 2; ++mt)
        ae[mt][kt] =
            *(const bf16x8*)(em + ((size_t)t * 8192 + n0 + mt * 16 + lr) * 128 + kt * 32 + lg * 8);
    // u-GEMM (K=256) from LDS hd
#pragma unroll
    for (int kt = 0; kt < 8; ++kt) {
      bf16x8 a[2];
#pragma unroll
      for (int mt = 0; mt < 2; ++mt) {
        int row = mt * 16 + lr;
        int s = ((row * 256) + (kt * 32 + lg * 8)) ^ ((row & 7) << 3);
        a[mt] = *(const bf16x8*)&hb[s];
      }
#pragma unroll
      for (int g = 0; g < 3; ++g) {
        const int ai = (g < 2) ? g : 3;
#pragma unroll
        for (int nt = 0; nt < 2; ++nt) {
          bf16x8 b = *(const bf16x8*)(pU + (((size_t)kt * 48 + g * 16 + wv * 2 + nt) * 64 + lane) * 8);
#pragma unroll
          for (int mt = 0; mt < 2; ++mt) acc[ai][mt][nt] = MFMA16(a[mt], b, acc[ai][mt][nt], 0, 0, 0);
        }
      }
    }
    // e-GEMM (K=128)
#pragma unroll
    for (int kt = 0; kt < 4; ++kt) {
#pragma unroll
      for (int g = 0; g < 3; ++g)
#pragma unroll
        for (int nt = 0; nt < 2; ++nt) {
          bf16x8 b = *(const bf16x8*)(pWe + (((size_t)kt * 48 + g * 16 + wv * 2 + nt) * 64 + lane) * 8);
#pragma unroll
          for (int mt = 0; mt < 2; ++mt) acc[g][mt][nt] = MFMA16(ae[mt][kt], b, acc[g][mt][nt], 0, 0, 0);
        }
    }
    // gates
#pragma unroll
    for (int mt = 0; mt < 2; ++mt)
#pragma unroll
      for (int nt = 0; nt < 2; ++nt)
#pragma unroll
        for (int r = 0; r < 4; ++r) {
          float zz = sigm(acc[0][mt][nt][r] + bz[nt]);
          float rr = sigm(acc[1][mt][nt][r] + br[nt]);
          float nn = tanh_fast(acc[2][mt][nt][r] + bn[nt] + rr * acc[3][mt][nt][r]);
          h[mt][nt][r] = (1.f - zz) * hd[mt][nt][r] + zz * nn;
        }
  }
  __syncthreads();
#pragma unroll
  for (int mt = 0; mt < 2; ++mt)
#pragma unroll
    for (int nt = 0; nt < 2; ++nt)
#pragma unroll
      for (int r = 0; r < 4; ++r)
        hmain[(size_t)(n0 + mt * 16 + lg * 4 + r) * 256 + wv * 32 + nt * 16 + lr] = h[mt][nt][r];
}

// ------------------------------------------------------------ cont RNN MFMA
__global__ __launch_bounds__(512, 2) __attribute__((amdgpu_waves_per_eu(2, 2)))
void k_rnn_cont_mfma(const __bf16* __restrict__ G2, const float* __restrict__ dtc,
                     const __bf16* __restrict__ pUc, const float* __restrict__ wt,
                     float* __restrict__ hcont) {
  const int wv = threadIdx.x >> 6, lane = threadIdx.x & 63;
  const int lr = lane & 15, lg = lane >> 4;
  const int p0 = blockIdx.x * 16;
  __shared__ __align__(16) __bf16 hbuf[2][16 * 256];  // 16 KB
  __shared__ float dl[16 * 128];                      // 8 KB
  for (int idx = threadIdx.x; idx < 2048; idx += 512)
    dl[idx] = dtc[(p0 + (idx >> 7)) * 128 + (idx & 127)];
  float wtv[2];
#pragma unroll
  for (int nt = 0; nt < 2; ++nt) wtv[nt] = wt[wv * 32 + nt * 16 + lr];
  // persistent U_c fragments: [gate][nt][kt] (192 VGPR)
  bf16x8 bfr[3][2][8];
#pragma unroll
  for (int g = 0; g < 3; ++g)
#pragma unroll
    for (int nt = 0; nt < 2; ++nt)
#pragma unroll
      for (int kt = 0; kt < 8; ++kt)
        bfr[g][nt][kt] =
            *(const bf16x8*)(pUc + (((size_t)kt * 48 + g * 16 + wv * 2 + nt) * 64 + lane) * 8);
  float h[2][4];
#pragma unroll
  for (int nt = 0; nt < 2; ++nt)
#pragma unroll
    for (int r = 0; r < 4; ++r) h[nt][r] = 0.f;

  const uint4* G2v = (const uint4*)G2;
  size_t gbase[4];
  uint4 Gv[4];
#pragma unroll
  for (int r = 0; r < 4; ++r) {
    gbase[r] = (size_t)(p0 + lg * 4 + r) * 16384 + wv * 16 + lr;
    Gv[r] = G2v[gbase[r]];  // t = 0
  }
  __syncthreads();  // dl ready

  for (int t = 0; t < 128; ++t) {
    __bf16* hb = hbuf[t & 1];
    float hd[2][4];
#pragma unroll
    for (int r = 0; r < 4; ++r) {
      float dtv = dl[(lg * 4 + r) * 128 + t];
#pragma unroll
      for (int nt = 0; nt < 2; ++nt) hd[nt][r] = h[nt][r] * __expf(-fmaxf(dtv * wtv[nt], 0.f));
    }
#pragma unroll
    for (int nt = 0; nt < 2; ++nt)
#pragma unroll
      for (int r = 0; r < 4; ++r) {
        int row = lg * 4 + r;
        hb[((row * 256) + (wv * 32 + nt * 16 + lr)) ^ ((row & 7) << 3)] = (__bf16)hd[nt][r];
      }
    __syncthreads();
    f32x4 acc[3][2];
#pragma unroll
    for (int g = 0; g < 3; ++g)
#pragma unroll
      for (int nt = 0; nt < 2; ++nt) acc[g][nt] = f32x4{0.f, 0.f, 0.f, 0.f};
#pragma unroll
    for (int kt = 0; kt < 8; ++kt) {
      int s = ((lr * 256) + (kt * 32 + lg * 8)) ^ ((lr & 7) << 3);
      bf16x8 a = *(const bf16x8*)&hb[s];
#pragma unroll
      for (int nt = 0; nt < 2; ++nt) {
        acc[0][nt] = MFMA16(a, bfr[0][nt][kt], acc[0][nt], 0, 0, 0);
        acc[1][nt] = MFMA16(a, bfr[1][nt][kt], acc[1][nt], 0, 0, 0);
        acc[2][nt] = MFMA16(a, bfr[2][nt][kt], acc[2][nt], 0, 0, 0);
      }
    }
#pragma unroll
    for (int nt = 0; nt < 2; ++nt)
#pragma unroll
      for (int r = 0; r < 4; ++r) {
        unsigned uz = nt ? (Gv[r].x >> 16) : (Gv[r].x & 0xffffu);
        unsigned ur = nt ? (Gv[r].y >> 16) : (Gv[r].y & 0xffffu);
        unsigned un = nt ? (Gv[r].z >> 16) : (Gv[r].z & 0xffffu);
        float zz = sigm(bfu(uz) + acc[0][nt][r]);
        float rr = sigm(bfu(ur) + acc[1][nt][r]);
        float nn = tanh_fast(bfu(un) + rr * acc[2][nt][r]);
        float hnew = (1.f - zz) * hd[nt][r] + zz * nn;
        h[nt][r] = hnew;
        if (t >= 124)
          hcont[((size_t)(p0 + lg * 4 + r) * 4 + (t - 124)) * 256 + wv * 32 + nt * 16 + lr] = hnew;
      }
    // prefetch next step's G fragments (consumed end of t+1: ~full step of slack)
    if (t < 127) {
#pragma unroll
      for (int r = 0; r < 4; ++r) Gv[r] = G2v[gbase[r] + (size_t)(t + 1) * 128];
    }
  }
}

// ------------------------------------------------------------------ tail
__global__ __launch_bounds__(256) void k_att(const float* __restrict__ hmain,
                                             const float* __restrict__ xself,
                                             const float* __restrict__ hc,
                                             const float* __restrict__ Wv,
                                             const float* __restrict__ bv,
                                             float* __restrict__ hh) {
  int b = blockIdx.x, tid = threadIdx.x;
  __shared__ float hl[16 * 256];
  __shared__ float aa[16 * 4];
  for (int idx = tid; idx < 4096; idx += 256) hl[idx] = hmain[(size_t)b * SS * HH + idx];
  __syncthreads();
  if (tid < 64) {
    int s = tid >> 2, m = tid & 3;
    float acc = bv[m];
    for (int j = 0; j < 256; ++j)
      acc += hl[s * 256 + j] * Wv[j * 4 + m] + hl[j] * Wv[(256 + j) * 4 + m];
    aa[s * 4 + m] = tanh_fast(acc);
  }
  __syncthreads();
  if (tid < 4) {
    int m = tid;
    float mx = -1e30f;
    for (int s = 0; s < 16; ++s) mx = fmaxf(mx, aa[s * 4 + m]);
    float sum = 0.f;
    for (int s = 0; s < 16; ++s) sum += __expf(aa[s * 4 + m] - mx);
    float inv = 1.f / sum;
    for (int s = 0; s < 16; ++s) aa[s * 4 + m] = __expf(aa[s * 4 + m] - mx) * inv;
  }
  __syncthreads();
  float a0 = 0.f, a1 = 0.f, a2 = 0.f, a3 = 0.f;
  for (int s = 0; s < 16; ++s) {
    float hv = hl[s * 256 + tid];
    a0 = fmaf(aa[s * 4 + 0], hv, a0);
    a1 = fmaf(aa[s * 4 + 1], hv, a1);
    a2 = fmaf(aa[s * 4 + 2], hv, a2);
    a3 = fmaf(aa[s * 4 + 3], hv, a3);
  }
  float* hb = hh + (size_t)b * 1664;
  hb[384 + 0 * 256 + tid] = a0;
  hb[384 + 1 * 256 + tid] = a1;
  hb[384 + 2 * 256 + tid] = a2;
  hb[384 + 3 * 256 + tid] = a3;
  if (tid < 128) hb[tid] = xself[b * DD + tid];
  hb[128 + tid] = hl[tid];
  hb[1408 + tid] = hc[(size_t)b * HH + tid];
}

__global__ __launch_bounds__(256) void k_mlp(const float* __restrict__ A,
                                             const float* __restrict__ W,
                                             const float* __restrict__ bias,
                                             float* __restrict__ C, int K, int N) {
  int tid = threadIdx.x;
  int j = blockIdx.x * 256 + tid;
  int rb = blockIdx.y * 16;
  __shared__ float al[16 * 512];
  float acc[16];
#pragma unroll
  for (int r = 0; r < 16; ++r) acc[r] = 0.f;
  for (int kc = 0; kc < K; kc += 512) {
    int ch = K - kc;
    if (ch > 512) ch = 512;
    __syncthreads();
#pragma unroll
    for (int r = 0; r < 16; ++r)
      for (int k = tid; k < ch; k += 256) al[r * 512 + k] = A[(size_t)(rb + r) * K + kc + k];
    __syncthreads();
    for (int k = 0; k < ch; ++k) {
      float w = W[(size_t)(kc + k) * N + j];
#pragma unroll
      for (int r = 0; r < 16; ++r) acc[r] = fmaf(al[r * 512 + k], w, acc[r]);
    }
  }
  float bj = bias[j];
#pragma unroll
  for (int r = 0; r < 16; ++r) {
    float v = acc[r] + bj;
    C[(size_t)(rb + r) * N + j] = v > 0.f ? v : 0.01f * v;
  }
}

__global__ __launch_bounds__(64) void k_head(const float* __restrict__ A,
                                             const float* __restrict__ Wp,
                                             const float* __restrict__ bp,
                                             float* __restrict__ out) {
  int row = blockIdx.x, l = threadIdx.x;
  float acc = 0.f;
  for (int j = l; j < 256; j += 64) acc = fmaf(A[(size_t)row * 256 + j], Wp[j], acc);
  for (int o = 32; o; o >>= 1) acc += __shfl_xor(acc, o);
  if (l == 0) out[row] = 1.f / (1.f + __expf(-(acc + bp[0])));
}

extern "C" void kernel_launch(void* const* d_in, const int* in_sizes, int n_in,
                              void* d_out, int out_size, void* d_ws, size_t ws_size,
                              hipStream_t stream) {
  const int* x = (const int*)d_in[0];
  const int* xc = (const int*)d_in[1];
  const int* self_loc = (const int*)d_in[2];
  const float* emb = (const float*)d_in[3];
  const float* W_rnn = (const float*)d_in[4];
  const float* U_rnn = (const float*)d_in[5];
  const float* b_rnn = (const float*)d_in[6];
  const float* wt_rnn = (const float*)d_in[7];
  const float* W_c = (const float*)d_in[8];
  const float* U_c = (const float*)d_in[9];
  const float* b_c = (const float*)d_in[10];
  const float* wt_c = (const float*)d_in[11];
  const float* Wv = (const float*)d_in[12];
  const float* bv = (const float*)d_in[13];
  const float* W0 = (const float*)d_in[14];
  const float* b0 = (const float*)d_in[15];
  const float* W1 = (const float*)d_in[16];
  const float* b1 = (const float*)d_in[17];
  const float* W2 = (const float*)d_in[18];
  const float* b2 = (const float*)d_in[19];
  const float* Wp = (const float*)d_in[20];
  const float* bp = (const float*)d_in[21];
  float* out = (float*)d_out;

  char* ws = (char*)d_ws;
  size_t cur = 0;
  auto alloc = [&](size_t bytes) {
    char* p = ws + cur;
    cur += (bytes + 255) & ~(size_t)255;
    return p;
  };
  float* es = (float*)alloc((size_t)BB * DD * 4);
  float* ns = (float*)alloc(BB * 4);
  unsigned* minu = (unsigned*)alloc(4);
  float* simw = (float*)alloc((size_t)BB * SS * II * 4);
  int* topidx = (int*)alloc((size_t)BB * SS * KK * 4);
  float* xself = (float*)alloc((size_t)BB * DD * 4);
  __bf16* xself_bf = (__bf16*)alloc((size_t)BB * DD * 2);
  float* dtm = (float*)alloc((size_t)KK * 8192 * 4);
  float* dtc = (float*)alloc((size_t)128 * 128 * 4);
  float* hcont = (float*)alloc((size_t)BB * HH * 4);
  float* hh = (float*)alloc((size_t)BB * 1664 * 4);
  float* z0 = (float*)alloc((size_t)BB * 1024 * 4);
  float* z1 = (float*)alloc((size_t)BB * 512 * 4);
  float* z2 = (float*)alloc((size_t)BB * 256 * 4);
  float* hmain = (float*)alloc((size_t)8192 * HH * 4);
  __hip_bfloat16* ec = (__hip_bfloat16*)alloc((size_t)16384 * DD * 2);
  __hip_bfloat16* em = (__hip_bfloat16*)alloc((size_t)KK * 8192 * DD * 2);
  __bf16* G2 = (__bf16*)alloc((size_t)16384 * 1024 * 2);
  __bf16* pWs = (__bf16*)alloc((size_t)4 * 48 * 64 * 8 * 2);
  __bf16* pWe = (__bf16*)alloc((size_t)4 * 48 * 64 * 8 * 2);
  __bf16* pU = (__bf16*)alloc((size_t)8 * 48 * 64 * 8 * 2);
  __bf16* pWc = (__bf16*)alloc((size_t)4 * 48 * 64 * 8 * 2);
  __bf16* pUc = (__bf16*)alloc((size_t)8 * 48 * 64 * 8 * 2);
  (void)ws_size;

  hipLaunchKernelGGL(k_init, dim3(1), dim3(1), 0, stream, minu);
  hipLaunchKernelGGL(k_eself, dim3(BB), dim3(128), 0, stream, x, self_loc, emb, es, ns);
  hipLaunchKernelGGL(k_cos, dim3(BB * SS), dim3(256), 0, stream, x, emb, es, ns, simw, minu);
  hipLaunchKernelGGL(k_topk, dim3(BB * SS), dim3(64), 0, stream, x, simw, minu, topidx);
  hipLaunchKernelGGL(k_build_main, dim3(8192, KK), dim3(128), 0, stream, x, self_loc, emb,
                     topidx, em, dtm, xself, xself_bf);
  hipLaunchKernelGGL(k_build_cont, dim3(128, 128), dim3(128), 0, stream, xc, emb, ec, dtc);
  hipLaunchKernelGGL(k_pack, dim3(4, 48), dim3(64), 0, stream, W_rnn, pWs);
  hipLaunchKernelGGL(k_pack, dim3(4, 48), dim3(64), 0, stream, W_rnn + 128 * 768, pWe);
  hipLaunchKernelGGL(k_pack, dim3(8, 48), dim3(64), 0, stream, U_rnn, pU);
  hipLaunchKernelGGL(k_pack, dim3(4, 48), dim3(64), 0, stream, W_c, pWc);
  hipLaunchKernelGGL(k_pack, dim3(8, 48), dim3(64), 0, stream, U_c, pUc);
  hipLaunchKernelGGL(k_gemm_g, dim3(512), dim3(512), 0, stream, ec, pWc, b_c, G2);
  hipLaunchKernelGGL(k_rnn_main_mfma, dim3(256), dim3(512), 0, stream, em, dtm, xself_bf,
                     pWs, pWe, pU, b_rnn, wt_rnn, hmain);
  hipLaunchKernelGGL(k_rnn_cont_mfma, dim3(8), dim3(512), 0, stream, G2, dtc, pUc, wt_c,
                     hcont);
  hipLaunchKernelGGL(k_att, dim3(BB), dim3(256), 0, stream, hmain, xself, hcont, Wv, bv, hh);
  hipLaunchKernelGGL(k_mlp, dim3(4, 32), dim3(256), 0, stream, hh, W0, b0, z0, 1664, 1024);
  hipLaunchKernelGGL(k_mlp, dim3(2, 32), dim3(256), 0, stream, z0, W1, b1, z1, 1024, 512);
  hipLaunchKernelGGL(k_mlp, dim3(1, 32), dim3(256), 0, stream, z1, W2, b2, z2, 512, 256);
  hipLaunchKernelGGL(k_head, dim3(BB), dim3(64), 0, stream, z2, Wp, bp, out);
}

// Round 4
// 2060.258 us; speedup vs baseline: 2.3980x; 1.0575x over previous
//
#include <hip/hip_runtime.h>
#include <hip/hip_bf16.h>

// SearchPredictModel round 4: register-budget-proof RNN kernels.
//  - attribute-only occupancy control (flat_work_group_size + waves_per_eu).
//  - cont RNN: U_c kt0-5 persistent in regs (144), kt6-7 staged in LDS (96KB).
//  - main RNN: 1-ahead e-GEMM A pipeline instead of bulk preload.

#define PAD_TOK 200000
#define DD 128
#define HH 256
#define KK 15
#define BB 512
#define SS 16
#define II 64

typedef __bf16 bf16x8 __attribute__((ext_vector_type(8)));
typedef float f32x4 __attribute__((ext_vector_type(4)));
#define MFMA16 __builtin_amdgcn_mfma_f32_16x16x32_bf16

__device__ __forceinline__ float sigm(float x) { return 1.f / (1.f + __expf(-x)); }
__device__ __forceinline__ float tanh_fast(float x) {
  x = fminf(fmaxf(x, -15.f), 15.f);
  float e2 = __expf(2.f * x);
  return (e2 - 1.f) / (e2 + 1.f);
}
__device__ __forceinline__ float bfu(unsigned u16) { return __uint_as_float(u16 << 16); }

// ---------------------------------------------------------------- front end
__global__ __launch_bounds__(128) void k_eself(const int* __restrict__ x,
                                               const int* __restrict__ self_loc,
                                               const float* __restrict__ emb,
                                               float* __restrict__ es,
                                               float* __restrict__ ns) {
  int b = blockIdx.x, d = threadIdx.x;
  int tok = x[((size_t)(b * SS + 0) * II + self_loc[b]) * 8 + 5];
  float v = emb[(size_t)tok * DD + d];
  es[b * DD + d] = v;
  __shared__ float red[128];
  red[d] = v * v;
  __syncthreads();
  for (int o = 64; o > 0; o >>= 1) {
    if (d < o) red[d] += red[d + o];
    __syncthreads();
  }
  if (d == 0) ns[b] = fmaxf(sqrtf(red[0]), 1e-8f);
}

__global__ void k_init(unsigned* minu) { *minu = 0xFFFFFFFFu; }

__global__ __launch_bounds__(256) void k_cos(const int* __restrict__ x,
                                             const float* __restrict__ emb,
                                             const float* __restrict__ es,
                                             const float* __restrict__ ns,
                                             float* __restrict__ simw,
                                             unsigned* __restrict__ minu) {
  int row = blockIdx.x;  // b*16+s
  int b = row >> 4;
  int tid = threadIdx.x, wave = tid >> 6, lane = tid & 63;
  const float2 ev = reinterpret_cast<const float2*>(es + b * DD)[lane];
  float nsb = ns[b];
  unsigned localmin = 0xFFFFFFFFu;
  for (int it = 0; it < 16; ++it) {
    int i = wave * 16 + it;
    const int* xr = x + ((size_t)row * II + i) * 8;
    int tok = xr[5];
    float2 a = *reinterpret_cast<const float2*>(emb + (size_t)tok * DD + lane * 2);
    float dot = a.x * ev.x + a.y * ev.y;
    float ss = a.x * a.x + a.y * a.y;
    for (int o = 32; o; o >>= 1) {
      dot += __shfl_xor(dot, o);
      ss += __shfl_xor(ss, o);
    }
    if (lane == 0) {
      float cosv = dot / (fmaxf(sqrtf(ss), 1e-8f) * nsb);
      simw[(size_t)row * II + i] = cosv;
      if (xr[0] != PAD_TOK) {
        unsigned u = __float_as_uint(cosv);
        unsigned key = (cosv < 0.f) ? ~u : (u | 0x80000000u);
        localmin = min(localmin, key);
      }
    }
  }
  if (lane == 0 && localmin != 0xFFFFFFFFu) atomicMin(minu, localmin);
}

__global__ __launch_bounds__(64) void k_topk(const int* __restrict__ x,
                                             const float* __restrict__ simw,
                                             const unsigned* __restrict__ minu,
                                             int* __restrict__ topidx) {
  int row = blockIdx.x, i = threadIdx.x;
  unsigned mk = *minu;
  float neg = ((mk & 0x80000000u) ? __uint_as_float(mk ^ 0x80000000u) : __uint_as_float(~mk)) - 1.0f;
  float c = simw[(size_t)row * II + i];
  bool real = x[((size_t)row * II + i) * 8] != PAD_TOK;
  float s = real ? c : neg;
  __shared__ float sv[64];
  sv[i] = s;
  __syncthreads();
  int rank = 0;
  for (int j = 0; j < 64; ++j) {
    float o = sv[j];
    rank += (o > s) || (o == s && j < i);
  }
  bool sel = rank < KK;
  unsigned long long mask = __ballot(sel);
  if (sel) {
    int pos = __popcll(mask & ((1ull << i) - 1ull));
    topidx[row * KK + pos] = i;
  }
}

__global__ __launch_bounds__(128) void k_build_main(const int* __restrict__ x,
                                                    const int* __restrict__ self_loc,
                                                    const float* __restrict__ emb,
                                                    const int* __restrict__ topidx,
                                                    __hip_bfloat16* __restrict__ em,
                                                    float* __restrict__ dtm,
                                                    float* __restrict__ xself,
                                                    __bf16* __restrict__ xself_bf) {
  int n = blockIdx.x, t = blockIdx.y, d = threadIdx.x;
  int b = n >> 4, s = n & 15;
  bool ovr = (s == 0) && (t == KK - 1);
  int item = ovr ? self_loc[b] : topidx[n * KK + t];
  const int* xr = x + ((size_t)n * II + item) * 8;
  float acc = 0.f;
#pragma unroll
  for (int jj = 0; jj < 6; ++jj) acc += emb[(size_t)xr[jj] * DD + d];
  em[((size_t)t * 8192 + n) * DD + d] = __float2bfloat16(acc);
  if (ovr) {
    xself[b * DD + d] = acc;
    xself_bf[b * DD + d] = (__bf16)acc;
  }
  if (d == 0) {
    float dtv = 0.f;
    if (t > 0) {
      int pitem = topidx[n * KK + t - 1];
      dtv = (float)xr[6] - (float)x[((size_t)n * II + pitem) * 8 + 6];
    }
    dtm[t * 8192 + n] = dtv;
  }
}

__global__ __launch_bounds__(128) void k_build_cont(const int* __restrict__ xc,
                                                    const float* __restrict__ emb,
                                                    __hip_bfloat16* __restrict__ ec,
                                                    float* __restrict__ dtc) {
  int p = blockIdx.x, t = blockIdx.y, d = threadIdx.x;
  const int* xr = xc + ((size_t)p * 128 + t) * 8;
  float acc = 0.f;
#pragma unroll
  for (int jj = 0; jj < 6; ++jj) acc += emb[(size_t)xr[jj] * DD + d];
  ec[((size_t)p * 128 + t) * DD + d] = __float2bfloat16(acc);
  if (d == 0) dtc[p * 128 + t] = (t > 0) ? ((float)xr[6] - (float)xr[-2]) : 0.f;
}

// ------------------------------------------------- weight fragment packing
__global__ __launch_bounds__(64) void k_pack(const float* __restrict__ B,
                                             __bf16* __restrict__ out) {
  int kt = blockIdx.x, tile = blockIdx.y, lane = threadIdx.x;
  const float* src = B + (size_t)(kt * 32 + (lane >> 4) * 8) * 768 + tile * 16 + (lane & 15);
  __bf16* o = out + (((size_t)(kt * 48 + tile) * 64 + lane) * 8);
#pragma unroll
  for (int i = 0; i < 8; ++i) o[i] = (__bf16)src[(size_t)i * 768];
}

// -------- cont-RNN g precompute: G2 (fragment-packed) = ec@Wc + b
// G2[rowflat*1024 + wvc*128 + lr*8 + gate*2 + nt], rowflat = p*128+t
__global__ __launch_bounds__(512) void k_gemm_g(const __hip_bfloat16* __restrict__ A,
                                                const __bf16* __restrict__ pB,
                                                const float* __restrict__ bias,
                                                __bf16* __restrict__ G2) {
  const int wv = threadIdx.x >> 6, lane = threadIdx.x & 63;
  const int lr = lane & 15, lg = lane >> 4;
  const int r0 = blockIdx.x * 32;
  f32x4 z4 = {0.f, 0.f, 0.f, 0.f};
  f32x4 acc[2][6];
#pragma unroll
  for (int mt = 0; mt < 2; ++mt)
#pragma unroll
    for (int n = 0; n < 6; ++n) acc[mt][n] = z4;
#pragma unroll
  for (int kt = 0; kt < 4; ++kt) {
    bf16x8 a[2];
#pragma unroll
    for (int mt = 0; mt < 2; ++mt)
      a[mt] = *(const bf16x8*)(A + (size_t)(r0 + mt * 16 + lr) * 128 + kt * 32 + lg * 8);
#pragma unroll
    for (int n = 0; n < 6; ++n) {
      bf16x8 b = *(const bf16x8*)(pB + (((size_t)kt * 48 + wv * 6 + n) * 64 + lane) * 8);
      acc[0][n] = MFMA16(a[0], b, acc[0][n], 0, 0, 0);
      acc[1][n] = MFMA16(a[1], b, acc[1][n], 0, 0, 0);
    }
  }
#pragma unroll
  for (int mt = 0; mt < 2; ++mt)
#pragma unroll
    for (int n = 0; n < 6; ++n) {
      int col = wv * 96 + n * 16 + lr;
      int gate = col >> 8, wvc = (col >> 5) & 7, nt = (col >> 4) & 1;
      float bc = bias[col];
#pragma unroll
      for (int r = 0; r < 4; ++r) {
        int row = r0 + mt * 16 + lg * 4 + r;
        G2[(size_t)row * 1024 + wvc * 128 + lr * 8 + gate * 2 + nt] = (__bf16)(acc[mt][n][r] + bc);
      }
    }
}

// ------------------------------------------------------------ main RNN MFMA
__global__ __attribute__((amdgpu_flat_work_group_size(512, 512)))
__attribute__((amdgpu_waves_per_eu(2, 2))) void k_rnn_main_mfma(
    const __hip_bfloat16* __restrict__ em, const float* __restrict__ dtm,
    const __bf16* __restrict__ xself_bf, const __bf16* __restrict__ pWs,
    const __bf16* __restrict__ pWe, const __bf16* __restrict__ pU,
    const float* __restrict__ bg, const float* __restrict__ wt,
    float* __restrict__ hmain) {
  const int wv = threadIdx.x >> 6, lane = threadIdx.x & 63;
  const int lr = lane & 15, lg = lane >> 4;
  const int n0 = blockIdx.x * 32;
  __shared__ __align__(16) __bf16 hbuf[2][32 * 256];  // 32 KB
  __shared__ float dl[KK * 32];                       // 1.9 KB
  f32x4 z4 = {0.f, 0.f, 0.f, 0.f};

  for (int idx = threadIdx.x; idx < KK * 32; idx += 512)
    dl[idx] = dtm[(idx >> 5) * 8192 + n0 + (idx & 31)];

  float bz[2], br[2], bn[2], wtv[2];
#pragma unroll
  for (int nt = 0; nt < 2; ++nt) {
    int c = wv * 32 + nt * 16 + lr;
    bz[nt] = bg[c];
    br[nt] = bg[c + 256];
    bn[nt] = bg[c + 512];
    wtv[nt] = wt[c];
  }

  // gs = xself @ W[0:128]  (constant over t)
  f32x4 gs[3][2][2];
#pragma unroll
  for (int g = 0; g < 3; ++g)
#pragma unroll
    for (int mt = 0; mt < 2; ++mt)
#pragma unroll
      for (int nt = 0; nt < 2; ++nt) gs[g][mt][nt] = z4;
#pragma unroll
  for (int kt = 0; kt < 4; ++kt) {
    bf16x8 a[2];
#pragma unroll
    for (int mt = 0; mt < 2; ++mt)
      a[mt] = *(const bf16x8*)(xself_bf + (size_t)((n0 + mt * 16) >> 4) * 128 + kt * 32 + lg * 8);
#pragma unroll
    for (int g = 0; g < 3; ++g)
#pragma unroll
      for (int nt = 0; nt < 2; ++nt) {
        bf16x8 b = *(const bf16x8*)(pWs + (((size_t)kt * 48 + g * 16 + wv * 2 + nt) * 64 + lane) * 8);
#pragma unroll
        for (int mt = 0; mt < 2; ++mt) gs[g][mt][nt] = MFMA16(a[mt], b, gs[g][mt][nt], 0, 0, 0);
      }
  }

  float h[2][2][4];
#pragma unroll
  for (int mt = 0; mt < 2; ++mt)
#pragma unroll
    for (int nt = 0; nt < 2; ++nt)
#pragma unroll
      for (int r = 0; r < 4; ++r) h[mt][nt][r] = 0.f;
  __syncthreads();

  for (int t = 0; t < KK; ++t) {
    __bf16* hb = hbuf[t & 1];
    float hd[2][2][4];
#pragma unroll
    for (int mt = 0; mt < 2; ++mt)
#pragma unroll
      for (int r = 0; r < 4; ++r) {
        float dtv = dl[t * 32 + mt * 16 + lg * 4 + r];
#pragma unroll
        for (int nt = 0; nt < 2; ++nt)
          hd[mt][nt][r] = h[mt][nt][r] * __expf(-fmaxf(dtv * wtv[nt], 0.f));
      }
#pragma unroll
    for (int mt = 0; mt < 2; ++mt)
#pragma unroll
      for (int nt = 0; nt < 2; ++nt)
#pragma unroll
        for (int r = 0; r < 4; ++r) {
          int row = mt * 16 + lg * 4 + r;
          hb[((row * 256) + (wv * 32 + nt * 16 + lr)) ^ ((row & 7) << 3)] = (__bf16)hd[mt][nt][r];
        }
    __syncthreads();

    // acc: 0=z(g+u), 1=r(g+u), 2=g_n, 3=u_n
    f32x4 acc[4][2][2];
#pragma unroll
    for (int mt = 0; mt < 2; ++mt)
#pragma unroll
      for (int nt = 0; nt < 2; ++nt) {
        acc[0][mt][nt] = gs[0][mt][nt];
        acc[1][mt][nt] = gs[1][mt][nt];
        acc[2][mt][nt] = gs[2][mt][nt];
        acc[3][mt][nt] = z4;
      }
    // first e-GEMM A-tile issued early; latency hides under the u-GEMM
    bf16x8 ac[2], an[2];
#pragma unroll
    for (int mt = 0; mt < 2; ++mt)
      ac[mt] = *(const bf16x8*)(em + ((size_t)t * 8192 + n0 + mt * 16 + lr) * 128 + 0 * 32 + lg * 8);
    // u-GEMM (K=256) from LDS hd
#pragma unroll
    for (int kt = 0; kt < 8; ++kt) {
      bf16x8 a[2];
#pragma unroll
      for (int mt = 0; mt < 2; ++mt) {
        int row = mt * 16 + lr;
        int s = ((row * 256) + (kt * 32 + lg * 8)) ^ ((row & 7) << 3);
        a[mt] = *(const bf16x8*)&hb[s];
      }
#pragma unroll
      for (int g = 0; g < 3; ++g) {
        const int ai = (g < 2) ? g : 3;
#pragma unroll
        for (int nt = 0; nt < 2; ++nt) {
          bf16x8 b = *(const bf16x8*)(pU + (((size_t)kt * 48 + g * 16 + wv * 2 + nt) * 64 + lane) * 8);
#pragma unroll
          for (int mt = 0; mt < 2; ++mt) acc[ai][mt][nt] = MFMA16(a[mt], b, acc[ai][mt][nt], 0, 0, 0);
        }
      }
    }
    // e-GEMM (K=128), 1-kt-ahead A pipeline
#pragma unroll
    for (int kt = 0; kt < 4; ++kt) {
      if (kt < 3) {
#pragma unroll
        for (int mt = 0; mt < 2; ++mt)
          an[mt] = *(const bf16x8*)(em + ((size_t)t * 8192 + n0 + mt * 16 + lr) * 128 +
                                    (kt + 1) * 32 + lg * 8);
      }
#pragma unroll
      for (int g = 0; g < 3; ++g)
#pragma unroll
        for (int nt = 0; nt < 2; ++nt) {
          bf16x8 b = *(const bf16x8*)(pWe + (((size_t)kt * 48 + g * 16 + wv * 2 + nt) * 64 + lane) * 8);
#pragma unroll
          for (int mt = 0; mt < 2; ++mt) acc[g][mt][nt] = MFMA16(ac[mt], b, acc[g][mt][nt], 0, 0, 0);
        }
#pragma unroll
      for (int mt = 0; mt < 2; ++mt) ac[mt] = an[mt];
    }
    // gates
#pragma unroll
    for (int mt = 0; mt < 2; ++mt)
#pragma unroll
      for (int nt = 0; nt < 2; ++nt)
#pragma unroll
        for (int r = 0; r < 4; ++r) {
          float zz = sigm(acc[0][mt][nt][r] + bz[nt]);
          float rr = sigm(acc[1][mt][nt][r] + br[nt]);
          float nn = tanh_fast(acc[2][mt][nt][r] + bn[nt] + rr * acc[3][mt][nt][r]);
          h[mt][nt][r] = (1.f - zz) * hd[mt][nt][r] + zz * nn;
        }
  }
  __syncthreads();
#pragma unroll
  for (int mt = 0; mt < 2; ++mt)
#pragma unroll
    for (int nt = 0; nt < 2; ++nt)
#pragma unroll
      for (int r = 0; r < 4; ++r)
        hmain[(size_t)(n0 + mt * 16 + lg * 4 + r) * 256 + wv * 32 + nt * 16 + lr] = h[mt][nt][r];
}

// ------------------------------------------------------------ cont RNN MFMA
// U_c kt0-5 persistent in registers (144 VGPR); kt6-7 staged in LDS (96KB).
__global__ __attribute__((amdgpu_flat_work_group_size(512, 512)))
__attribute__((amdgpu_waves_per_eu(2, 2))) void k_rnn_cont_mfma(
    const __bf16* __restrict__ G2, const float* __restrict__ dtc,
    const __bf16* __restrict__ pUc, const float* __restrict__ wt,
    float* __restrict__ hcont) {
  const int wv = threadIdx.x >> 6, lane = threadIdx.x & 63;
  const int lr = lane & 15, lg = lane >> 4;
  const int p0 = blockIdx.x * 16;
  __shared__ __align__(16) __bf16 hbuf[2][16 * 256];   // 16 KB
  __shared__ __align__(16) __bf16 uLds[2 * 48 * 512];  // 96 KB: kt 6,7
  __shared__ float dl[16 * 128];                       // 8 KB
  for (int idx = threadIdx.x; idx < 2048; idx += 512)
    dl[idx] = dtc[(p0 + (idx >> 7)) * 128 + (idx & 127)];
  // stage U kt6-7 into LDS (each thread 12 x 16B)
  {
    const uint4* src = (const uint4*)(pUc + (size_t)6 * 48 * 512);
    uint4* dst = (uint4*)uLds;
    for (int idx = threadIdx.x; idx < 2 * 48 * 64; idx += 512) dst[idx] = src[idx];
  }
  float wtv[2];
#pragma unroll
  for (int nt = 0; nt < 2; ++nt) wtv[nt] = wt[wv * 32 + nt * 16 + lr];
  // persistent U_c fragments kt0-5: [gate][nt][kt] (144 VGPR)
  bf16x8 bfr[3][2][6];
#pragma unroll
  for (int g = 0; g < 3; ++g)
#pragma unroll
    for (int nt = 0; nt < 2; ++nt)
#pragma unroll
      for (int kt = 0; kt < 6; ++kt)
        bfr[g][nt][kt] =
            *(const bf16x8*)(pUc + (((size_t)kt * 48 + g * 16 + wv * 2 + nt) * 64 + lane) * 8);
  float h[2][4];
#pragma unroll
  for (int nt = 0; nt < 2; ++nt)
#pragma unroll
    for (int r = 0; r < 4; ++r) h[nt][r] = 0.f;

  const uint4* G2v = (const uint4*)G2;
  const size_t gb0 = (size_t)(p0 + lg * 4) * 16384 + wv * 16 + lr;
  __syncthreads();  // dl + uLds ready

  for (int t = 0; t < 128; ++t) {
    __bf16* hb = hbuf[t & 1];
    // issue this step's G loads early (consumed at gates, ~1k cyc later)
    uint4 Gv[4];
#pragma unroll
    for (int r = 0; r < 4; ++r) Gv[r] = G2v[gb0 + (size_t)r * 16384 + (size_t)t * 128];
    float hd[2][4];
#pragma unroll
    for (int r = 0; r < 4; ++r) {
      float dtv = dl[(lg * 4 + r) * 128 + t];
#pragma unroll
      for (int nt = 0; nt < 2; ++nt) hd[nt][r] = h[nt][r] * __expf(-fmaxf(dtv * wtv[nt], 0.f));
    }
#pragma unroll
    for (int nt = 0; nt < 2; ++nt)
#pragma unroll
      for (int r = 0; r < 4; ++r) {
        int row = lg * 4 + r;
        hb[((row * 256) + (wv * 32 + nt * 16 + lr)) ^ ((row & 7) << 3)] = (__bf16)hd[nt][r];
      }
    __syncthreads();
    f32x4 acc[3][2];
#pragma unroll
    for (int g = 0; g < 3; ++g)
#pragma unroll
      for (int nt = 0; nt < 2; ++nt) acc[g][nt] = f32x4{0.f, 0.f, 0.f, 0.f};
#pragma unroll
    for (int kt = 0; kt < 8; ++kt) {
      int s = ((lr * 256) + (kt * 32 + lg * 8)) ^ ((lr & 7) << 3);
      bf16x8 a = *(const bf16x8*)&hb[s];
      if (kt < 6) {
#pragma unroll
        for (int nt = 0; nt < 2; ++nt) {
          acc[0][nt] = MFMA16(a, bfr[0][nt][kt], acc[0][nt], 0, 0, 0);
          acc[1][nt] = MFMA16(a, bfr[1][nt][kt], acc[1][nt], 0, 0, 0);
          acc[2][nt] = MFMA16(a, bfr[2][nt][kt], acc[2][nt], 0, 0, 0);
        }
      } else {
#pragma unroll
        for (int g = 0; g < 3; ++g)
#pragma unroll
          for (int nt = 0; nt < 2; ++nt) {
            bf16x8 b = *(const bf16x8*)&uLds[(((kt - 6) * 48 + g * 16 + wv * 2 + nt) * 64 + lane) * 8];
            acc[g][nt] = MFMA16(a, b, acc[g][nt], 0, 0, 0);
          }
      }
    }
#pragma unroll
    for (int nt = 0; nt < 2; ++nt)
#pragma unroll
      for (int r = 0; r < 4; ++r) {
        unsigned uz = nt ? (Gv[r].x >> 16) : (Gv[r].x & 0xffffu);
        unsigned ur = nt ? (Gv[r].y >> 16) : (Gv[r].y & 0xffffu);
        unsigned un = nt ? (Gv[r].z >> 16) : (Gv[r].z & 0xffffu);
        float zz = sigm(bfu(uz) + acc[0][nt][r]);
        float rr = sigm(bfu(ur) + acc[1][nt][r]);
        float nn = tanh_fast(bfu(un) + rr * acc[2][nt][r]);
        float hnew = (1.f - zz) * hd[nt][r] + zz * nn;
        h[nt][r] = hnew;
        if (t >= 124)
          hcont[((size_t)(p0 + lg * 4 + r) * 4 + (t - 124)) * 256 + wv * 32 + nt * 16 + lr] = hnew;
      }
  }
}

// ------------------------------------------------------------------ tail
__global__ __launch_bounds__(256) void k_att(const float* __restrict__ hmain,
                                             const float* __restrict__ xself,
                                             const float* __restrict__ hc,
                                             const float* __restrict__ Wv,
                                             const float* __restrict__ bv,
                                             float* __restrict__ hh) {
  int b = blockIdx.x, tid = threadIdx.x;
  __shared__ float hl[16 * 256];
  __shared__ float aa[16 * 4];
  for (int idx = tid; idx < 4096; idx += 256) hl[idx] = hmain[(size_t)b * SS * HH + idx];
  __syncthreads();
  if (tid < 64) {
    int s = tid >> 2, m = tid & 3;
    float acc = bv[m];
    for (int j = 0; j < 256; ++j)
      acc += hl[s * 256 + j] * Wv[j * 4 + m] + hl[j] * Wv[(256 + j) * 4 + m];
    aa[s * 4 + m] = tanh_fast(acc);
  }
  __syncthreads();
  if (tid < 4) {
    int m = tid;
    float mx = -1e30f;
    for (int s = 0; s < 16; ++s) mx = fmaxf(mx, aa[s * 4 + m]);
    float sum = 0.f;
    for (int s = 0; s < 16; ++s) sum += __expf(aa[s * 4 + m] - mx);
    float inv = 1.f / sum;
    for (int s = 0; s < 16; ++s) aa[s * 4 + m] = __expf(aa[s * 4 + m] - mx) * inv;
  }
  __syncthreads();
  float a0 = 0.f, a1 = 0.f, a2 = 0.f, a3 = 0.f;
  for (int s = 0; s < 16; ++s) {
    float hv = hl[s * 256 + tid];
    a0 = fmaf(aa[s * 4 + 0], hv, a0);
    a1 = fmaf(aa[s * 4 + 1], hv, a1);
    a2 = fmaf(aa[s * 4 + 2], hv, a2);
    a3 = fmaf(aa[s * 4 + 3], hv, a3);
  }
  float* hb = hh + (size_t)b * 1664;
  hb[384 + 0 * 256 + tid] = a0;
  hb[384 + 1 * 256 + tid] = a1;
  hb[384 + 2 * 256 + tid] = a2;
  hb[384 + 3 * 256 + tid] = a3;
  if (tid < 128) hb[tid] = xself[b * DD + tid];
  hb[128 + tid] = hl[tid];
  hb[1408 + tid] = hc[(size_t)b * HH + tid];
}

__global__ __launch_bounds__(256) void k_mlp(const float* __restrict__ A,
                                             const float* __restrict__ W,
                                             const float* __restrict__ bias,
                                             float* __restrict__ C, int K, int N) {
  int tid = threadIdx.x;
  int j = blockIdx.x * 256 + tid;
  int rb = blockIdx.y * 16;
  __shared__ float al[16 * 512];
  float acc[16];
#pragma unroll
  for (int r = 0; r < 16; ++r) acc[r] = 0.f;
  for (int kc = 0; kc < K; kc += 512) {
    int ch = K - kc;
    if (ch > 512) ch = 512;
    __syncthreads();
#pragma unroll
    for (int r = 0; r < 16; ++r)
      for (int k = tid; k < ch; k += 256) al[r * 512 + k] = A[(size_t)(rb + r) * K + kc + k];
    __syncthreads();
    for (int k = 0; k < ch; ++k) {
      float w = W[(size_t)(kc + k) * N + j];
#pragma unroll
      for (int r = 0; r < 16; ++r) acc[r] = fmaf(al[r * 512 + k], w, acc[r]);
    }
  }
  float bj = bias[j];
#pragma unroll
  for (int r = 0; r < 16; ++r) {
    float v = acc[r] + bj;
    C[(size_t)(rb + r) * N + j] = v > 0.f ? v : 0.01f * v;
  }
}

__global__ __launch_bounds__(64) void k_head(const float* __restrict__ A,
                                             const float* __restrict__ Wp,
                                             const float* __restrict__ bp,
                                             float* __restrict__ out) {
  int row = blockIdx.x, l = threadIdx.x;
  float acc = 0.f;
  for (int j = l; j < 256; j += 64) acc = fmaf(A[(size_t)row * 256 + j], Wp[j], acc);
  for (int o = 32; o; o >>= 1) acc += __shfl_xor(acc, o);
  if (l == 0) out[row] = 1.f / (1.f + __expf(-(acc + bp[0])));
}

extern "C" void kernel_launch(void* const* d_in, const int* in_sizes, int n_in,
                              void* d_out, int out_size, void* d_ws, size_t ws_size,
                              hipStream_t stream) {
  const int* x = (const int*)d_in[0];
  const int* xc = (const int*)d_in[1];
  const int* self_loc = (const int*)d_in[2];
  const float* emb = (const float*)d_in[3];
  const float* W_rnn = (const float*)d_in[4];
  const float* U_rnn = (const float*)d_in[5];
  const float* b_rnn = (const float*)d_in[6];
  const float* wt_rnn = (const float*)d_in[7];
  const float* W_c = (const float*)d_in[8];
  const float* U_c = (const float*)d_in[9];
  const float* b_c = (const float*)d_in[10];
  const float* wt_c = (const float*)d_in[11];
  const float* Wv = (const float*)d_in[12];
  const float* bv = (const float*)d_in[13];
  const float* W0 = (const float*)d_in[14];
  const float* b0 = (const float*)d_in[15];
  const float* W1 = (const float*)d_in[16];
  const float* b1 = (const float*)d_in[17];
  const float* W2 = (const float*)d_in[18];
  const float* b2 = (const float*)d_in[19];
  const float* Wp = (const float*)d_in[20];
  const float* bp = (const float*)d_in[21];
  float* out = (float*)d_out;

  char* ws = (char*)d_ws;
  size_t cur = 0;
  auto alloc = [&](size_t bytes) {
    char* p = ws + cur;
    cur += (bytes + 255) & ~(size_t)255;
    return p;
  };
  float* es = (float*)alloc((size_t)BB * DD * 4);
  float* ns = (float*)alloc(BB * 4);
  unsigned* minu = (unsigned*)alloc(4);
  float* simw = (float*)alloc((size_t)BB * SS * II * 4);
  int* topidx = (int*)alloc((size_t)BB * SS * KK * 4);
  float* xself = (float*)alloc((size_t)BB * DD * 4);
  __bf16* xself_bf = (__bf16*)alloc((size_t)BB * DD * 2);
  float* dtm = (float*)alloc((size_t)KK * 8192 * 4);
  float* dtc = (float*)alloc((size_t)128 * 128 * 4);
  float* hcont = (float*)alloc((size_t)BB * HH * 4);
  float* hh = (float*)alloc((size_t)BB * 1664 * 4);
  float* z0 = (float*)alloc((size_t)BB * 1024 * 4);
  float* z1 = (float*)alloc((size_t)BB * 512 * 4);
  float* z2 = (float*)alloc((size_t)BB * 256 * 4);
  float* hmain = (float*)alloc((size_t)8192 * HH * 4);
  __hip_bfloat16* ec = (__hip_bfloat16*)alloc((size_t)16384 * DD * 2);
  __hip_bfloat16* em = (__hip_bfloat16*)alloc((size_t)KK * 8192 * DD * 2);
  __bf16* G2 = (__bf16*)alloc((size_t)16384 * 1024 * 2);
  __bf16* pWs = (__bf16*)alloc((size_t)4 * 48 * 64 * 8 * 2);
  __bf16* pWe = (__bf16*)alloc((size_t)4 * 48 * 64 * 8 * 2);
  __bf16* pU = (__bf16*)alloc((size_t)8 * 48 * 64 * 8 * 2);
  __bf16* pWc = (__bf16*)alloc((size_t)4 * 48 * 64 * 8 * 2);
  __bf16* pUc = (__bf16*)alloc((size_t)8 * 48 * 64 * 8 * 2);
  (void)ws_size;

  hipLaunchKernelGGL(k_init, dim3(1), dim3(1), 0, stream, minu);
  hipLaunchKernelGGL(k_eself, dim3(BB), dim3(128), 0, stream, x, self_loc, emb, es, ns);
  hipLaunchKernelGGL(k_cos, dim3(BB * SS), dim3(256), 0, stream, x, emb, es, ns, simw, minu);
  hipLaunchKernelGGL(k_topk, dim3(BB * SS), dim3(64), 0, stream, x, simw, minu, topidx);
  hipLaunchKernelGGL(k_build_main, dim3(8192, KK), dim3(128), 0, stream, x, self_loc, emb,
                     topidx, em, dtm, xself, xself_bf);
  hipLaunchKernelGGL(k_build_cont, dim3(128, 128), dim3(128), 0, stream, xc, emb, ec, dtc);
  hipLaunchKernelGGL(k_pack, dim3(4, 48), dim3(64), 0, stream, W_rnn, pWs);
  hipLaunchKernelGGL(k_pack, dim3(4, 48), dim3(64), 0, stream, W_rnn + 128 * 768, pWe);
  hipLaunchKernelGGL(k_pack, dim3(8, 48), dim3(64), 0, stream, U_rnn, pU);
  hipLaunchKernelGGL(k_pack, dim3(4, 48), dim3(64), 0, stream, W_c, pWc);
  hipLaunchKernelGGL(k_pack, dim3(8, 48), dim3(64), 0, stream, U_c, pUc);
  hipLaunchKernelGGL(k_gemm_g, dim3(512), dim3(512), 0, stream, ec, pWc, b_c, G2);
  hipLaunchKernelGGL(k_rnn_main_mfma, dim3(256), dim3(512), 0, stream, em, dtm, xself_bf,
                     pWs, pWe, pU, b_rnn, wt_rnn, hmain);
  hipLaunchKernelGGL(k_rnn_cont_mfma, dim3(8), dim3(512), 0, stream, G2, dtc, pUc, wt_c,
                     hcont);
  hipLaunchKernelGGL(k_att, dim3(BB), dim3(256), 0, stream, hmain, xself, hcont, Wv, bv, hh);
  hipLaunchKernelGGL(k_mlp, dim3(4, 32), dim3(256), 0, stream, hh, W0, b0, z0, 1664, 1024);
  hipLaunchKernelGGL(k_mlp, dim3(2, 32), dim3(256), 0, stream, z0, W1, b1, z1, 1024, 512);
  hipLaunchKernelGGL(k_mlp, dim3(1, 32), dim3(256), 0, stream, z1, W2, b2, z2, 512, 256);
  hipLaunchKernelGGL(k_head, dim3(BB), dim3(64), 0, stream, z2, Wp, bp, out);
}

// Round 5
// 1755.221 us; speedup vs baseline: 2.8147x; 1.1738x over previous
//
#include <hip/hip_runtime.h>
#include <hip/hip_bf16.h>

// SearchPredictModel round 5: k_cos restructured (4 lanes/item, 2-level
// shuffle reduce, 1 atomic/block); k_build_main vectorized (float4, 8
// items/block). RNN kernels unchanged from round 4.

#define PAD_TOK 200000
#define DD 128
#define HH 256
#define KK 15
#define BB 512
#define SS 16
#define II 64

typedef __bf16 bf16x8 __attribute__((ext_vector_type(8)));
typedef __bf16 bf16x4 __attribute__((ext_vector_type(4)));
typedef float f32x4 __attribute__((ext_vector_type(4)));
#define MFMA16 __builtin_amdgcn_mfma_f32_16x16x32_bf16

__device__ __forceinline__ float sigm(float x) { return 1.f / (1.f + __expf(-x)); }
__device__ __forceinline__ float tanh_fast(float x) {
  x = fminf(fmaxf(x, -15.f), 15.f);
  float e2 = __expf(2.f * x);
  return (e2 - 1.f) / (e2 + 1.f);
}
__device__ __forceinline__ float bfu(unsigned u16) { return __uint_as_float(u16 << 16); }

// ---------------------------------------------------------------- front end
__global__ __launch_bounds__(128) void k_eself(const int* __restrict__ x,
                                               const int* __restrict__ self_loc,
                                               const float* __restrict__ emb,
                                               float* __restrict__ es,
                                               float* __restrict__ ns) {
  int b = blockIdx.x, d = threadIdx.x;
  int tok = x[((size_t)(b * SS + 0) * II + self_loc[b]) * 8 + 5];
  float v = emb[(size_t)tok * DD + d];
  es[b * DD + d] = v;
  __shared__ float red[128];
  red[d] = v * v;
  __syncthreads();
  for (int o = 64; o > 0; o >>= 1) {
    if (d < o) red[d] += red[d + o];
    __syncthreads();
  }
  if (d == 0) ns[b] = fmaxf(sqrtf(red[0]), 1e-8f);
}

__global__ void k_init(unsigned* minu) { *minu = 0xFFFFFFFFu; }

// one block per row (b,s); 64 items x 4 lanes each
__global__ __launch_bounds__(256) void k_cos(const int* __restrict__ x,
                                             const float* __restrict__ emb,
                                             const float* __restrict__ es,
                                             const float* __restrict__ ns,
                                             float* __restrict__ simw,
                                             unsigned* __restrict__ minu) {
  int row = blockIdx.x;
  int b = row >> 4;
  int tid = threadIdx.x;
  int i = tid >> 2;  // item
  int q = tid & 3;   // dim quarter (32 dims)
  __shared__ float esl[128];
  __shared__ unsigned smin[64];
  if (tid < 128) esl[tid] = es[b * DD + tid];
  __syncthreads();
  const int* xr = x + ((size_t)row * II + i) * 8;
  int tok = xr[5];
  int first = xr[0];
  const float4* ep = (const float4*)(emb + (size_t)tok * DD + q * 32);
  const float4* sp = (const float4*)(esl + q * 32);
  float dot = 0.f, ss = 0.f;
#pragma unroll
  for (int j = 0; j < 8; ++j) {
    float4 a = ep[j];
    float4 e = sp[j];
    dot += a.x * e.x + a.y * e.y + a.z * e.z + a.w * e.w;
    ss += a.x * a.x + a.y * a.y + a.z * a.z + a.w * a.w;
  }
  dot += __shfl_xor(dot, 1);
  ss += __shfl_xor(ss, 1);
  dot += __shfl_xor(dot, 2);
  ss += __shfl_xor(ss, 2);
  if (q == 0) {
    float cosv = dot / (fmaxf(sqrtf(ss), 1e-8f) * ns[b]);
    simw[(size_t)row * II + i] = cosv;
    unsigned key = 0xFFFFFFFFu;
    if (first != PAD_TOK) {
      unsigned u = __float_as_uint(cosv);
      key = (cosv < 0.f) ? ~u : (u | 0x80000000u);
    }
    smin[i] = key;
  }
  __syncthreads();
  if (tid < 64) {
    unsigned m = smin[tid];
    for (int o = 32; o; o >>= 1) m = min(m, __shfl_xor(m, o));
    if (tid == 0 && m != 0xFFFFFFFFu) atomicMin(minu, m);
  }
}

__global__ __launch_bounds__(64) void k_topk(const int* __restrict__ x,
                                             const float* __restrict__ simw,
                                             const unsigned* __restrict__ minu,
                                             int* __restrict__ topidx) {
  int row = blockIdx.x, i = threadIdx.x;
  unsigned mk = *minu;
  float neg = ((mk & 0x80000000u) ? __uint_as_float(mk ^ 0x80000000u) : __uint_as_float(~mk)) - 1.0f;
  float c = simw[(size_t)row * II + i];
  bool real = x[((size_t)row * II + i) * 8] != PAD_TOK;
  float s = real ? c : neg;
  __shared__ float sv[64];
  sv[i] = s;
  __syncthreads();
  int rank = 0;
  for (int j = 0; j < 64; ++j) {
    float o = sv[j];
    rank += (o > s) || (o == s && j < i);
  }
  bool sel = rank < KK;
  unsigned long long mask = __ballot(sel);
  if (sel) {
    int pos = __popcll(mask & ((1ull << i) - 1ull));
    topidx[row * KK + pos] = i;
  }
}

// 8 items/block x 32 lanes (float4 per lane)
__global__ __launch_bounds__(256) void k_build_main(const int* __restrict__ x,
                                                    const int* __restrict__ self_loc,
                                                    const float* __restrict__ emb,
                                                    const int* __restrict__ topidx,
                                                    __hip_bfloat16* __restrict__ em,
                                                    float* __restrict__ dtm,
                                                    float* __restrict__ xself,
                                                    __bf16* __restrict__ xself_bf) {
  int t = blockIdx.y;
  int n = blockIdx.x * 8 + (threadIdx.x >> 5);
  int q = threadIdx.x & 31;  // dims [q*4, q*4+4)
  int b = n >> 4, s = n & 15;
  bool ovr = (s == 0) && (t == KK - 1);
  int item = ovr ? self_loc[b] : topidx[n * KK + t];
  const int* xr = x + ((size_t)n * II + item) * 8;
  int toks[6];
#pragma unroll
  for (int jj = 0; jj < 6; ++jj) toks[jj] = xr[jj];
  float4 acc = {0.f, 0.f, 0.f, 0.f};
#pragma unroll
  for (int jj = 0; jj < 6; ++jj) {
    float4 v = *(const float4*)(emb + (size_t)toks[jj] * DD + q * 4);
    acc.x += v.x;
    acc.y += v.y;
    acc.z += v.z;
    acc.w += v.w;
  }
  bf16x4 ov = {(__bf16)acc.x, (__bf16)acc.y, (__bf16)acc.z, (__bf16)acc.w};
  *(bf16x4*)((__bf16*)em + ((size_t)t * 8192 + n) * DD + q * 4) = ov;
  if (ovr) {
    *(float4*)(xself + b * DD + q * 4) = acc;
    *(bf16x4*)(xself_bf + b * DD + q * 4) = ov;
  }
  if (q == 0) {
    float dtv = 0.f;
    if (t > 0) {
      int pitem = topidx[n * KK + t - 1];
      dtv = (float)xr[6] - (float)x[((size_t)n * II + pitem) * 8 + 6];
    }
    dtm[t * 8192 + n] = dtv;
  }
}

__global__ __launch_bounds__(128) void k_build_cont(const int* __restrict__ xc,
                                                    const float* __restrict__ emb,
                                                    __hip_bfloat16* __restrict__ ec,
                                                    float* __restrict__ dtc) {
  int p = blockIdx.x, t = blockIdx.y, d = threadIdx.x;
  const int* xr = xc + ((size_t)p * 128 + t) * 8;
  float acc = 0.f;
#pragma unroll
  for (int jj = 0; jj < 6; ++jj) acc += emb[(size_t)xr[jj] * DD + d];
  ec[((size_t)p * 128 + t) * DD + d] = __float2bfloat16(acc);
  if (d == 0) dtc[p * 128 + t] = (t > 0) ? ((float)xr[6] - (float)xr[-2]) : 0.f;
}

// ------------------------------------------------- weight fragment packing
__global__ __launch_bounds__(64) void k_pack(const float* __restrict__ B,
                                             __bf16* __restrict__ out) {
  int kt = blockIdx.x, tile = blockIdx.y, lane = threadIdx.x;
  const float* src = B + (size_t)(kt * 32 + (lane >> 4) * 8) * 768 + tile * 16 + (lane & 15);
  __bf16* o = out + (((size_t)(kt * 48 + tile) * 64 + lane) * 8);
#pragma unroll
  for (int i = 0; i < 8; ++i) o[i] = (__bf16)src[(size_t)i * 768];
}

// -------- cont-RNN g precompute: G2 (fragment-packed) = ec@Wc + b
// G2[rowflat*1024 + wvc*128 + lr*8 + gate*2 + nt], rowflat = p*128+t
__global__ __launch_bounds__(512) void k_gemm_g(const __hip_bfloat16* __restrict__ A,
                                                const __bf16* __restrict__ pB,
                                                const float* __restrict__ bias,
                                                __bf16* __restrict__ G2) {
  const int wv = threadIdx.x >> 6, lane = threadIdx.x & 63;
  const int lr = lane & 15, lg = lane >> 4;
  const int r0 = blockIdx.x * 32;
  f32x4 z4 = {0.f, 0.f, 0.f, 0.f};
  f32x4 acc[2][6];
#pragma unroll
  for (int mt = 0; mt < 2; ++mt)
#pragma unroll
    for (int n = 0; n < 6; ++n) acc[mt][n] = z4;
#pragma unroll
  for (int kt = 0; kt < 4; ++kt) {
    bf16x8 a[2];
#pragma unroll
    for (int mt = 0; mt < 2; ++mt)
      a[mt] = *(const bf16x8*)(A + (size_t)(r0 + mt * 16 + lr) * 128 + kt * 32 + lg * 8);
#pragma unroll
    for (int n = 0; n < 6; ++n) {
      bf16x8 b = *(const bf16x8*)(pB + (((size_t)kt * 48 + wv * 6 + n) * 64 + lane) * 8);
      acc[0][n] = MFMA16(a[0], b, acc[0][n], 0, 0, 0);
      acc[1][n] = MFMA16(a[1], b, acc[1][n], 0, 0, 0);
    }
  }
#pragma unroll
  for (int mt = 0; mt < 2; ++mt)
#pragma unroll
    for (int n = 0; n < 6; ++n) {
      int col = wv * 96 + n * 16 + lr;
      int gate = col >> 8, wvc = (col >> 5) & 7, nt = (col >> 4) & 1;
      float bc = bias[col];
#pragma unroll
      for (int r = 0; r < 4; ++r) {
        int row = r0 + mt * 16 + lg * 4 + r;
        G2[(size_t)row * 1024 + wvc * 128 + lr * 8 + gate * 2 + nt] = (__bf16)(acc[mt][n][r] + bc);
      }
    }
}

// ------------------------------------------------------------ main RNN MFMA
__global__ __attribute__((amdgpu_flat_work_group_size(512, 512)))
__attribute__((amdgpu_waves_per_eu(2, 2))) void k_rnn_main_mfma(
    const __hip_bfloat16* __restrict__ em, const float* __restrict__ dtm,
    const __bf16* __restrict__ xself_bf, const __bf16* __restrict__ pWs,
    const __bf16* __restrict__ pWe, const __bf16* __restrict__ pU,
    const float* __restrict__ bg, const float* __restrict__ wt,
    float* __restrict__ hmain) {
  const int wv = threadIdx.x >> 6, lane = threadIdx.x & 63;
  const int lr = lane & 15, lg = lane >> 4;
  const int n0 = blockIdx.x * 32;
  __shared__ __align__(16) __bf16 hbuf[2][32 * 256];  // 32 KB
  __shared__ float dl[KK * 32];                       // 1.9 KB
  f32x4 z4 = {0.f, 0.f, 0.f, 0.f};

  for (int idx = threadIdx.x; idx < KK * 32; idx += 512)
    dl[idx] = dtm[(idx >> 5) * 8192 + n0 + (idx & 31)];

  float bz[2], br[2], bn[2], wtv[2];
#pragma unroll
  for (int nt = 0; nt < 2; ++nt) {
    int c = wv * 32 + nt * 16 + lr;
    bz[nt] = bg[c];
    br[nt] = bg[c + 256];
    bn[nt] = bg[c + 512];
    wtv[nt] = wt[c];
  }

  // gs = xself @ W[0:128]  (constant over t)
  f32x4 gs[3][2][2];
#pragma unroll
  for (int g = 0; g < 3; ++g)
#pragma unroll
    for (int mt = 0; mt < 2; ++mt)
#pragma unroll
      for (int nt = 0; nt < 2; ++nt) gs[g][mt][nt] = z4;
#pragma unroll
  for (int kt = 0; kt < 4; ++kt) {
    bf16x8 a[2];
#pragma unroll
    for (int mt = 0; mt < 2; ++mt)
      a[mt] = *(const bf16x8*)(xself_bf + (size_t)((n0 + mt * 16) >> 4) * 128 + kt * 32 + lg * 8);
#pragma unroll
    for (int g = 0; g < 3; ++g)
#pragma unroll
      for (int nt = 0; nt < 2; ++nt) {
        bf16x8 b = *(const bf16x8*)(pWs + (((size_t)kt * 48 + g * 16 + wv * 2 + nt) * 64 + lane) * 8);
#pragma unroll
        for (int mt = 0; mt < 2; ++mt) gs[g][mt][nt] = MFMA16(a[mt], b, gs[g][mt][nt], 0, 0, 0);
      }
  }

  float h[2][2][4];
#pragma unroll
  for (int mt = 0; mt < 2; ++mt)
#pragma unroll
    for (int nt = 0; nt < 2; ++nt)
#pragma unroll
      for (int r = 0; r < 4; ++r) h[mt][nt][r] = 0.f;
  __syncthreads();

  for (int t = 0; t < KK; ++t) {
    __bf16* hb = hbuf[t & 1];
    float hd[2][2][4];
#pragma unroll
    for (int mt = 0; mt < 2; ++mt)
#pragma unroll
      for (int r = 0; r < 4; ++r) {
        float dtv = dl[t * 32 + mt * 16 + lg * 4 + r];
#pragma unroll
        for (int nt = 0; nt < 2; ++nt)
          hd[mt][nt][r] = h[mt][nt][r] * __expf(-fmaxf(dtv * wtv[nt], 0.f));
      }
#pragma unroll
    for (int mt = 0; mt < 2; ++mt)
#pragma unroll
      for (int nt = 0; nt < 2; ++nt)
#pragma unroll
        for (int r = 0; r < 4; ++r) {
          int row = mt * 16 + lg * 4 + r;
          hb[((row * 256) + (wv * 32 + nt * 16 + lr)) ^ ((row & 7) << 3)] = (__bf16)hd[mt][nt][r];
        }
    __syncthreads();

    // acc: 0=z(g+u), 1=r(g+u), 2=g_n, 3=u_n
    f32x4 acc[4][2][2];
#pragma unroll
    for (int mt = 0; mt < 2; ++mt)
#pragma unroll
      for (int nt = 0; nt < 2; ++nt) {
        acc[0][mt][nt] = gs[0][mt][nt];
        acc[1][mt][nt] = gs[1][mt][nt];
        acc[2][mt][nt] = gs[2][mt][nt];
        acc[3][mt][nt] = z4;
      }
    // first e-GEMM A-tile issued early; latency hides under the u-GEMM
    bf16x8 ac[2], an[2];
#pragma unroll
    for (int mt = 0; mt < 2; ++mt)
      ac[mt] = *(const bf16x8*)(em + ((size_t)t * 8192 + n0 + mt * 16 + lr) * 128 + 0 * 32 + lg * 8);
    // u-GEMM (K=256) from LDS hd
#pragma unroll
    for (int kt = 0; kt < 8; ++kt) {
      bf16x8 a[2];
#pragma unroll
      for (int mt = 0; mt < 2; ++mt) {
        int row = mt * 16 + lr;
        int s = ((row * 256) + (kt * 32 + lg * 8)) ^ ((row & 7) << 3);
        a[mt] = *(const bf16x8*)&hb[s];
      }
#pragma unroll
      for (int g = 0; g < 3; ++g) {
        const int ai = (g < 2) ? g : 3;
#pragma unroll
        for (int nt = 0; nt < 2; ++nt) {
          bf16x8 b = *(const bf16x8*)(pU + (((size_t)kt * 48 + g * 16 + wv * 2 + nt) * 64 + lane) * 8);
#pragma unroll
          for (int mt = 0; mt < 2; ++mt) acc[ai][mt][nt] = MFMA16(a[mt], b, acc[ai][mt][nt], 0, 0, 0);
        }
      }
    }
    // e-GEMM (K=128), 1-kt-ahead A pipeline
#pragma unroll
    for (int kt = 0; kt < 4; ++kt) {
      if (kt < 3) {
#pragma unroll
        for (int mt = 0; mt < 2; ++mt)
          an[mt] = *(const bf16x8*)(em + ((size_t)t * 8192 + n0 + mt * 16 + lr) * 128 +
                                    (kt + 1) * 32 + lg * 8);
      }
#pragma unroll
      for (int g = 0; g < 3; ++g)
#pragma unroll
        for (int nt = 0; nt < 2; ++nt) {
          bf16x8 b = *(const bf16x8*)(pWe + (((size_t)kt * 48 + g * 16 + wv * 2 + nt) * 64 + lane) * 8);
#pragma unroll
          for (int mt = 0; mt < 2; ++mt) acc[g][mt][nt] = MFMA16(ac[mt], b, acc[g][mt][nt], 0, 0, 0);
        }
#pragma unroll
      for (int mt = 0; mt < 2; ++mt) ac[mt] = an[mt];
    }
    // gates
#pragma unroll
    for (int mt = 0; mt < 2; ++mt)
#pragma unroll
      for (int nt = 0; nt < 2; ++nt)
#pragma unroll
        for (int r = 0; r < 4; ++r) {
          float zz = sigm(acc[0][mt][nt][r] + bz[nt]);
          float rr = sigm(acc[1][mt][nt][r] + br[nt]);
          float nn = tanh_fast(acc[2][mt][nt][r] + bn[nt] + rr * acc[3][mt][nt][r]);
          h[mt][nt][r] = (1.f - zz) * hd[mt][nt][r] + zz * nn;
        }
  }
  __syncthreads();
#pragma unroll
  for (int mt = 0; mt < 2; ++mt)
#pragma unroll
    for (int nt = 0; nt < 2; ++nt)
#pragma unroll
      for (int r = 0; r < 4; ++r)
        hmain[(size_t)(n0 + mt * 16 + lg * 4 + r) * 256 + wv * 32 + nt * 16 + lr] = h[mt][nt][r];
}

// ------------------------------------------------------------ cont RNN MFMA
// U_c kt0-5 persistent in registers (144 VGPR); kt6-7 staged in LDS (96KB).
__global__ __attribute__((amdgpu_flat_work_group_size(512, 512)))
__attribute__((amdgpu_waves_per_eu(2, 2))) void k_rnn_cont_mfma(
    const __bf16* __restrict__ G2, const float* __restrict__ dtc,
    const __bf16* __restrict__ pUc, const float* __restrict__ wt,
    float* __restrict__ hcont) {
  const int wv = threadIdx.x >> 6, lane = threadIdx.x & 63;
  const int lr = lane & 15, lg = lane >> 4;
  const int p0 = blockIdx.x * 16;
  __shared__ __align__(16) __bf16 hbuf[2][16 * 256];   // 16 KB
  __shared__ __align__(16) __bf16 uLds[2 * 48 * 512];  // 96 KB: kt 6,7
  __shared__ float dl[16 * 128];                       // 8 KB
  for (int idx = threadIdx.x; idx < 2048; idx += 512)
    dl[idx] = dtc[(p0 + (idx >> 7)) * 128 + (idx & 127)];
  // stage U kt6-7 into LDS
  {
    const uint4* src = (const uint4*)(pUc + (size_t)6 * 48 * 512);
    uint4* dst = (uint4*)uLds;
    for (int idx = threadIdx.x; idx < 2 * 48 * 64; idx += 512) dst[idx] = src[idx];
  }
  float wtv[2];
#pragma unroll
  for (int nt = 0; nt < 2; ++nt) wtv[nt] = wt[wv * 32 + nt * 16 + lr];
  // persistent U_c fragments kt0-5: [gate][nt][kt] (144 VGPR)
  bf16x8 bfr[3][2][6];
#pragma unroll
  for (int g = 0; g < 3; ++g)
#pragma unroll
    for (int nt = 0; nt < 2; ++nt)
#pragma unroll
      for (int kt = 0; kt < 6; ++kt)
        bfr[g][nt][kt] =
            *(const bf16x8*)(pUc + (((size_t)kt * 48 + g * 16 + wv * 2 + nt) * 64 + lane) * 8);
  float h[2][4];
#pragma unroll
  for (int nt = 0; nt < 2; ++nt)
#pragma unroll
    for (int r = 0; r < 4; ++r) h[nt][r] = 0.f;

  const uint4* G2v = (const uint4*)G2;
  const size_t gb0 = (size_t)(p0 + lg * 4) * 16384 + wv * 16 + lr;
  __syncthreads();  // dl + uLds ready

  for (int t = 0; t < 128; ++t) {
    __bf16* hb = hbuf[t & 1];
    // issue this step's G loads early (consumed at gates, ~1k cyc later)
    uint4 Gv[4];
#pragma unroll
    for (int r = 0; r < 4; ++r) Gv[r] = G2v[gb0 + (size_t)r * 16384 + (size_t)t * 128];
    float hd[2][4];
#pragma unroll
    for (int r = 0; r < 4; ++r) {
      float dtv = dl[(lg * 4 + r) * 128 + t];
#pragma unroll
      for (int nt = 0; nt < 2; ++nt) hd[nt][r] = h[nt][r] * __expf(-fmaxf(dtv * wtv[nt], 0.f));
    }
#pragma unroll
    for (int nt = 0; nt < 2; ++nt)
#pragma unroll
      for (int r = 0; r < 4; ++r) {
        int row = lg * 4 + r;
        hb[((row * 256) + (wv * 32 + nt * 16 + lr)) ^ ((row & 7) << 3)] = (__bf16)hd[nt][r];
      }
    __syncthreads();
    f32x4 acc[3][2];
#pragma unroll
    for (int g = 0; g < 3; ++g)
#pragma unroll
      for (int nt = 0; nt < 2; ++nt) acc[g][nt] = f32x4{0.f, 0.f, 0.f, 0.f};
#pragma unroll
    for (int kt = 0; kt < 8; ++kt) {
      int s = ((lr * 256) + (kt * 32 + lg * 8)) ^ ((lr & 7) << 3);
      bf16x8 a = *(const bf16x8*)&hb[s];
      if (kt < 6) {
#pragma unroll
        for (int nt = 0; nt < 2; ++nt) {
          acc[0][nt] = MFMA16(a, bfr[0][nt][kt], acc[0][nt], 0, 0, 0);
          acc[1][nt] = MFMA16(a, bfr[1][nt][kt], acc[1][nt], 0, 0, 0);
          acc[2][nt] = MFMA16(a, bfr[2][nt][kt], acc[2][nt], 0, 0, 0);
        }
      } else {
#pragma unroll
        for (int g = 0; g < 3; ++g)
#pragma unroll
          for (int nt = 0; nt < 2; ++nt) {
            bf16x8 b = *(const bf16x8*)&uLds[(((kt - 6) * 48 + g * 16 + wv * 2 + nt) * 64 + lane) * 8];
            acc[g][nt] = MFMA16(a, b, acc[g][nt], 0, 0, 0);
          }
      }
    }
#pragma unroll
    for (int nt = 0; nt < 2; ++nt)
#pragma unroll
      for (int r = 0; r < 4; ++r) {
        unsigned uz = nt ? (Gv[r].x >> 16) : (Gv[r].x & 0xffffu);
        unsigned ur = nt ? (Gv[r].y >> 16) : (Gv[r].y & 0xffffu);
        unsigned un = nt ? (Gv[r].z >> 16) : (Gv[r].z & 0xffffu);
        float zz = sigm(bfu(uz) + acc[0][nt][r]);
        float rr = sigm(bfu(ur) + acc[1][nt][r]);
        float nn = tanh_fast(bfu(un) + rr * acc[2][nt][r]);
        float hnew = (1.f - zz) * hd[nt][r] + zz * nn;
        h[nt][r] = hnew;
        if (t >= 124)
          hcont[((size_t)(p0 + lg * 4 + r) * 4 + (t - 124)) * 256 + wv * 32 + nt * 16 + lr] = hnew;
      }
  }
}

// ------------------------------------------------------------------ tail
__global__ __launch_bounds__(256) void k_att(const float* __restrict__ hmain,
                                             const float* __restrict__ xself,
                                             const float* __restrict__ hc,
                                             const float* __restrict__ Wv,
                                             const float* __restrict__ bv,
                                             float* __restrict__ hh) {
  int b = blockIdx.x, tid = threadIdx.x;
  __shared__ float hl[16 * 256];
  __shared__ float aa[16 * 4];
  for (int idx = tid; idx < 4096; idx += 256) hl[idx] = hmain[(size_t)b * SS * HH + idx];
  __syncthreads();
  if (tid < 64) {
    int s = tid >> 2, m = tid & 3;
    float acc = bv[m];
    for (int j = 0; j < 256; ++j)
      acc += hl[s * 256 + j] * Wv[j * 4 + m] + hl[j] * Wv[(256 + j) * 4 + m];
    aa[s * 4 + m] = tanh_fast(acc);
  }
  __syncthreads();
  if (tid < 4) {
    int m = tid;
    float mx = -1e30f;
    for (int s = 0; s < 16; ++s) mx = fmaxf(mx, aa[s * 4 + m]);
    float sum = 0.f;
    for (int s = 0; s < 16; ++s) sum += __expf(aa[s * 4 + m] - mx);
    float inv = 1.f / sum;
    for (int s = 0; s < 16; ++s) aa[s * 4 + m] = __expf(aa[s * 4 + m] - mx) * inv;
  }
  __syncthreads();
  float a0 = 0.f, a1 = 0.f, a2 = 0.f, a3 = 0.f;
  for (int s = 0; s < 16; ++s) {
    float hv = hl[s * 256 + tid];
    a0 = fmaf(aa[s * 4 + 0], hv, a0);
    a1 = fmaf(aa[s * 4 + 1], hv, a1);
    a2 = fmaf(aa[s * 4 + 2], hv, a2);
    a3 = fmaf(aa[s * 4 + 3], hv, a3);
  }
  float* hb = hh + (size_t)b * 1664;
  hb[384 + 0 * 256 + tid] = a0;
  hb[384 + 1 * 256 + tid] = a1;
  hb[384 + 2 * 256 + tid] = a2;
  hb[384 + 3 * 256 + tid] = a3;
  if (tid < 128) hb[tid] = xself[b * DD + tid];
  hb[128 + tid] = hl[tid];
  hb[1408 + tid] = hc[(size_t)b * HH + tid];
}

__global__ __launch_bounds__(256) void k_mlp(const float* __restrict__ A,
                                             const float* __restrict__ W,
                                             const float* __restrict__ bias,
                                             float* __restrict__ C, int K, int N) {
  int tid = threadIdx.x;
  int j = blockIdx.x * 256 + tid;
  int rb = blockIdx.y * 16;
  __shared__ float al[16 * 512];
  float acc[16];
#pragma unroll
  for (int r = 0; r < 16; ++r) acc[r] = 0.f;
  for (int kc = 0; kc < K; kc += 512) {
    int ch = K - kc;
    if (ch > 512) ch = 512;
    __syncthreads();
#pragma unroll
    for (int r = 0; r < 16; ++r)
      for (int k = tid; k < ch; k += 256) al[r * 512 + k] = A[(size_t)(rb + r) * K + kc + k];
    __syncthreads();
    for (int k = 0; k < ch; ++k) {
      float w = W[(size_t)(kc + k) * N + j];
#pragma unroll
      for (int r = 0; r < 16; ++r) acc[r] = fmaf(al[r * 512 + k], w, acc[r]);
    }
  }
  float bj = bias[j];
#pragma unroll
  for (int r = 0; r < 16; ++r) {
    float v = acc[r] + bj;
    C[(size_t)(rb + r) * N + j] = v > 0.f ? v : 0.01f * v;
  }
}

__global__ __launch_bounds__(64) void k_head(const float* __restrict__ A,
                                             const float* __restrict__ Wp,
                                             const float* __restrict__ bp,
                                             float* __restrict__ out) {
  int row = blockIdx.x, l = threadIdx.x;
  float acc = 0.f;
  for (int j = l; j < 256; j += 64) acc = fmaf(A[(size_t)row * 256 + j], Wp[j], acc);
  for (int o = 32; o; o >>= 1) acc += __shfl_xor(acc, o);
  if (l == 0) out[row] = 1.f / (1.f + __expf(-(acc + bp[0])));
}

extern "C" void kernel_launch(void* const* d_in, const int* in_sizes, int n_in,
                              void* d_out, int out_size, void* d_ws, size_t ws_size,
                              hipStream_t stream) {
  const int* x = (const int*)d_in[0];
  const int* xc = (const int*)d_in[1];
  const int* self_loc = (const int*)d_in[2];
  const float* emb = (const float*)d_in[3];
  const float* W_rnn = (const float*)d_in[4];
  const float* U_rnn = (const float*)d_in[5];
  const float* b_rnn = (const float*)d_in[6];
  const float* wt_rnn = (const float*)d_in[7];
  const float* W_c = (const float*)d_in[8];
  const float* U_c = (const float*)d_in[9];
  const float* b_c = (const float*)d_in[10];
  const float* wt_c = (const float*)d_in[11];
  const float* Wv = (const float*)d_in[12];
  const float* bv = (const float*)d_in[13];
  const float* W0 = (const float*)d_in[14];
  const float* b0 = (const float*)d_in[15];
  const float* W1 = (const float*)d_in[16];
  const float* b1 = (const float*)d_in[17];
  const float* W2 = (const float*)d_in[18];
  const float* b2 = (const float*)d_in[19];
  const float* Wp = (const float*)d_in[20];
  const float* bp = (const float*)d_in[21];
  float* out = (float*)d_out;

  char* ws = (char*)d_ws;
  size_t cur = 0;
  auto alloc = [&](size_t bytes) {
    char* p = ws + cur;
    cur += (bytes + 255) & ~(size_t)255;
    return p;
  };
  float* es = (float*)alloc((size_t)BB * DD * 4);
  float* ns = (float*)alloc(BB * 4);
  unsigned* minu = (unsigned*)alloc(4);
  float* simw = (float*)alloc((size_t)BB * SS * II * 4);
  int* topidx = (int*)alloc((size_t)BB * SS * KK * 4);
  float* xself = (float*)alloc((size_t)BB * DD * 4);
  __bf16* xself_bf = (__bf16*)alloc((size_t)BB * DD * 2);
  float* dtm = (float*)alloc((size_t)KK * 8192 * 4);
  float* dtc = (float*)alloc((size_t)128 * 128 * 4);
  float* hcont = (float*)alloc((size_t)BB * HH * 4);
  float* hh = (float*)alloc((size_t)BB * 1664 * 4);
  float* z0 = (float*)alloc((size_t)BB * 1024 * 4);
  float* z1 = (float*)alloc((size_t)BB * 512 * 4);
  float* z2 = (float*)alloc((size_t)BB * 256 * 4);
  float* hmain = (float*)alloc((size_t)8192 * HH * 4);
  __hip_bfloat16* ec = (__hip_bfloat16*)alloc((size_t)16384 * DD * 2);
  __hip_bfloat16* em = (__hip_bfloat16*)alloc((size_t)KK * 8192 * DD * 2);
  __bf16* G2 = (__bf16*)alloc((size_t)16384 * 1024 * 2);
  __bf16* pWs = (__bf16*)alloc((size_t)4 * 48 * 64 * 8 * 2);
  __bf16* pWe = (__bf16*)alloc((size_t)4 * 48 * 64 * 8 * 2);
  __bf16* pU = (__bf16*)alloc((size_t)8 * 48 * 64 * 8 * 2);
  __bf16* pWc = (__bf16*)alloc((size_t)4 * 48 * 64 * 8 * 2);
  __bf16* pUc = (__bf16*)alloc((size_t)8 * 48 * 64 * 8 * 2);
  (void)ws_size;

  hipLaunchKernelGGL(k_init, dim3(1), dim3(1), 0, stream, minu);
  hipLaunchKernelGGL(k_eself, dim3(BB), dim3(128), 0, stream, x, self_loc, emb, es, ns);
  hipLaunchKernelGGL(k_cos, dim3(BB * SS), dim3(256), 0, stream, x, emb, es, ns, simw, minu);
  hipLaunchKernelGGL(k_topk, dim3(BB * SS), dim3(64), 0, stream, x, simw, minu, topidx);
  hipLaunchKernelGGL(k_build_main, dim3(1024, KK), dim3(256), 0, stream, x, self_loc, emb,
                     topidx, em, dtm, xself, xself_bf);
  hipLaunchKernelGGL(k_build_cont, dim3(128, 128), dim3(128), 0, stream, xc, emb, ec, dtc);
  hipLaunchKernelGGL(k_pack, dim3(4, 48), dim3(64), 0, stream, W_rnn, pWs);
  hipLaunchKernelGGL(k_pack, dim3(4, 48), dim3(64), 0, stream, W_rnn + 128 * 768, pWe);
  hipLaunchKernelGGL(k_pack, dim3(8, 48), dim3(64), 0, stream, U_rnn, pU);
  hipLaunchKernelGGL(k_pack, dim3(4, 48), dim3(64), 0, stream, W_c, pWc);
  hipLaunchKernelGGL(k_pack, dim3(8, 48), dim3(64), 0, stream, U_c, pUc);
  hipLaunchKernelGGL(k_gemm_g, dim3(512), dim3(512), 0, stream, ec, pWc, b_c, G2);
  hipLaunchKernelGGL(k_rnn_main_mfma, dim3(256), dim3(512), 0, stream, em, dtm, xself_bf,
                     pWs, pWe, pU, b_rnn, wt_rnn, hmain);
  hipLaunchKernelGGL(k_rnn_cont_mfma, dim3(8), dim3(512), 0, stream, G2, dtc, pUc, wt_c,
                     hcont);
  hipLaunchKernelGGL(k_att, dim3(BB), dim3(256), 0, stream, hmain, xself, hcont, Wv, bv, hh);
  hipLaunchKernelGGL(k_mlp, dim3(4, 32), dim3(256), 0, stream, hh, W0, b0, z0, 1664, 1024);
  hipLaunchKernelGGL(k_mlp, dim3(2, 32), dim3(256), 0, stream, z0, W1, b1, z1, 1024, 512);
  hipLaunchKernelGGL(k_mlp, dim3(1, 32), dim3(256), 0, stream, z1, W2, b2, z2, 512, 256);
  hipLaunchKernelGGL(k_head, dim3(BB), dim3(64), 0, stream, z2, Wp, bp, out);
}

// Round 6
// 1744.612 us; speedup vs baseline: 2.8318x; 1.0061x over previous
//
#include <hip/hip_runtime.h>
#include <hip/hip_bf16.h>

// SearchPredictModel round 6: main RNN re-tiled to 16 waves x 1024 threads
// (each wave 1 N-tile/gate) -> ~116 VGPR demand, no spill, 4 waves/SIMD.
// Everything else unchanged from round 5.

#define PAD_TOK 200000
#define DD 128
#define HH 256
#define KK 15
#define BB 512
#define SS 16
#define II 64

typedef __bf16 bf16x8 __attribute__((ext_vector_type(8)));
typedef __bf16 bf16x4 __attribute__((ext_vector_type(4)));
typedef float f32x4 __attribute__((ext_vector_type(4)));
#define MFMA16 __builtin_amdgcn_mfma_f32_16x16x32_bf16

__device__ __forceinline__ float sigm(float x) { return 1.f / (1.f + __expf(-x)); }
__device__ __forceinline__ float tanh_fast(float x) {
  x = fminf(fmaxf(x, -15.f), 15.f);
  float e2 = __expf(2.f * x);
  return (e2 - 1.f) / (e2 + 1.f);
}
__device__ __forceinline__ float bfu(unsigned u16) { return __uint_as_float(u16 << 16); }

// ---------------------------------------------------------------- front end
__global__ __launch_bounds__(128) void k_eself(const int* __restrict__ x,
                                               const int* __restrict__ self_loc,
                                               const float* __restrict__ emb,
                                               float* __restrict__ es,
                                               float* __restrict__ ns) {
  int b = blockIdx.x, d = threadIdx.x;
  int tok = x[((size_t)(b * SS + 0) * II + self_loc[b]) * 8 + 5];
  float v = emb[(size_t)tok * DD + d];
  es[b * DD + d] = v;
  __shared__ float red[128];
  red[d] = v * v;
  __syncthreads();
  for (int o = 64; o > 0; o >>= 1) {
    if (d < o) red[d] += red[d + o];
    __syncthreads();
  }
  if (d == 0) ns[b] = fmaxf(sqrtf(red[0]), 1e-8f);
}

__global__ void k_init(unsigned* minu) { *minu = 0xFFFFFFFFu; }

// one block per row (b,s); 64 items x 4 lanes each
__global__ __launch_bounds__(256) void k_cos(const int* __restrict__ x,
                                             const float* __restrict__ emb,
                                             const float* __restrict__ es,
                                             const float* __restrict__ ns,
                                             float* __restrict__ simw,
                                             unsigned* __restrict__ minu) {
  int row = blockIdx.x;
  int b = row >> 4;
  int tid = threadIdx.x;
  int i = tid >> 2;  // item
  int q = tid & 3;   // dim quarter (32 dims)
  __shared__ float esl[128];
  __shared__ unsigned smin[64];
  if (tid < 128) esl[tid] = es[b * DD + tid];
  __syncthreads();
  const int* xr = x + ((size_t)row * II + i) * 8;
  int tok = xr[5];
  int first = xr[0];
  const float4* ep = (const float4*)(emb + (size_t)tok * DD + q * 32);
  const float4* sp = (const float4*)(esl + q * 32);
  float dot = 0.f, ss = 0.f;
#pragma unroll
  for (int j = 0; j < 8; ++j) {
    float4 a = ep[j];
    float4 e = sp[j];
    dot += a.x * e.x + a.y * e.y + a.z * e.z + a.w * e.w;
    ss += a.x * a.x + a.y * a.y + a.z * a.z + a.w * a.w;
  }
  dot += __shfl_xor(dot, 1);
  ss += __shfl_xor(ss, 1);
  dot += __shfl_xor(dot, 2);
  ss += __shfl_xor(ss, 2);
  if (q == 0) {
    float cosv = dot / (fmaxf(sqrtf(ss), 1e-8f) * ns[b]);
    simw[(size_t)row * II + i] = cosv;
    unsigned key = 0xFFFFFFFFu;
    if (first != PAD_TOK) {
      unsigned u = __float_as_uint(cosv);
      key = (cosv < 0.f) ? ~u : (u | 0x80000000u);
    }
    smin[i] = key;
  }
  __syncthreads();
  if (tid < 64) {
    unsigned m = smin[tid];
    for (int o = 32; o; o >>= 1) m = min(m, __shfl_xor(m, o));
    if (tid == 0 && m != 0xFFFFFFFFu) atomicMin(minu, m);
  }
}

__global__ __launch_bounds__(64) void k_topk(const int* __restrict__ x,
                                             const float* __restrict__ simw,
                                             const unsigned* __restrict__ minu,
                                             int* __restrict__ topidx) {
  int row = blockIdx.x, i = threadIdx.x;
  unsigned mk = *minu;
  float neg = ((mk & 0x80000000u) ? __uint_as_float(mk ^ 0x80000000u) : __uint_as_float(~mk)) - 1.0f;
  float c = simw[(size_t)row * II + i];
  bool real = x[((size_t)row * II + i) * 8] != PAD_TOK;
  float s = real ? c : neg;
  __shared__ float sv[64];
  sv[i] = s;
  __syncthreads();
  int rank = 0;
  for (int j = 0; j < 64; ++j) {
    float o = sv[j];
    rank += (o > s) || (o == s && j < i);
  }
  bool sel = rank < KK;
  unsigned long long mask = __ballot(sel);
  if (sel) {
    int pos = __popcll(mask & ((1ull << i) - 1ull));
    topidx[row * KK + pos] = i;
  }
}

// 8 items/block x 32 lanes (float4 per lane)
__global__ __launch_bounds__(256) void k_build_main(const int* __restrict__ x,
                                                    const int* __restrict__ self_loc,
                                                    const float* __restrict__ emb,
                                                    const int* __restrict__ topidx,
                                                    __hip_bfloat16* __restrict__ em,
                                                    float* __restrict__ dtm,
                                                    float* __restrict__ xself,
                                                    __bf16* __restrict__ xself_bf) {
  int t = blockIdx.y;
  int n = blockIdx.x * 8 + (threadIdx.x >> 5);
  int q = threadIdx.x & 31;  // dims [q*4, q*4+4)
  int b = n >> 4, s = n & 15;
  bool ovr = (s == 0) && (t == KK - 1);
  int item = ovr ? self_loc[b] : topidx[n * KK + t];
  const int* xr = x + ((size_t)n * II + item) * 8;
  int toks[6];
#pragma unroll
  for (int jj = 0; jj < 6; ++jj) toks[jj] = xr[jj];
  float4 acc = {0.f, 0.f, 0.f, 0.f};
#pragma unroll
  for (int jj = 0; jj < 6; ++jj) {
    float4 v = *(const float4*)(emb + (size_t)toks[jj] * DD + q * 4);
    acc.x += v.x;
    acc.y += v.y;
    acc.z += v.z;
    acc.w += v.w;
  }
  bf16x4 ov = {(__bf16)acc.x, (__bf16)acc.y, (__bf16)acc.z, (__bf16)acc.w};
  *(bf16x4*)((__bf16*)em + ((size_t)t * 8192 + n) * DD + q * 4) = ov;
  if (ovr) {
    *(float4*)(xself + b * DD + q * 4) = acc;
    *(bf16x4*)(xself_bf + b * DD + q * 4) = ov;
  }
  if (q == 0) {
    float dtv = 0.f;
    if (t > 0) {
      int pitem = topidx[n * KK + t - 1];
      dtv = (float)xr[6] - (float)x[((size_t)n * II + pitem) * 8 + 6];
    }
    dtm[t * 8192 + n] = dtv;
  }
}

__global__ __launch_bounds__(128) void k_build_cont(const int* __restrict__ xc,
                                                    const float* __restrict__ emb,
                                                    __hip_bfloat16* __restrict__ ec,
                                                    float* __restrict__ dtc) {
  int p = blockIdx.x, t = blockIdx.y, d = threadIdx.x;
  const int* xr = xc + ((size_t)p * 128 + t) * 8;
  float acc = 0.f;
#pragma unroll
  for (int jj = 0; jj < 6; ++jj) acc += emb[(size_t)xr[jj] * DD + d];
  ec[((size_t)p * 128 + t) * DD + d] = __float2bfloat16(acc);
  if (d == 0) dtc[p * 128 + t] = (t > 0) ? ((float)xr[6] - (float)xr[-2]) : 0.f;
}

// ------------------------------------------------- weight fragment packing
__global__ __launch_bounds__(64) void k_pack(const float* __restrict__ B,
                                             __bf16* __restrict__ out) {
  int kt = blockIdx.x, tile = blockIdx.y, lane = threadIdx.x;
  const float* src = B + (size_t)(kt * 32 + (lane >> 4) * 8) * 768 + tile * 16 + (lane & 15);
  __bf16* o = out + (((size_t)(kt * 48 + tile) * 64 + lane) * 8);
#pragma unroll
  for (int i = 0; i < 8; ++i) o[i] = (__bf16)src[(size_t)i * 768];
}

// -------- cont-RNN g precompute: G2 (fragment-packed) = ec@Wc + b
// G2[rowflat*1024 + wvc*128 + lr*8 + gate*2 + nt], rowflat = p*128+t
__global__ __launch_bounds__(512) void k_gemm_g(const __hip_bfloat16* __restrict__ A,
                                                const __bf16* __restrict__ pB,
                                                const float* __restrict__ bias,
                                                __bf16* __restrict__ G2) {
  const int wv = threadIdx.x >> 6, lane = threadIdx.x & 63;
  const int lr = lane & 15, lg = lane >> 4;
  const int r0 = blockIdx.x * 32;
  f32x4 z4 = {0.f, 0.f, 0.f, 0.f};
  f32x4 acc[2][6];
#pragma unroll
  for (int mt = 0; mt < 2; ++mt)
#pragma unroll
    for (int n = 0; n < 6; ++n) acc[mt][n] = z4;
#pragma unroll
  for (int kt = 0; kt < 4; ++kt) {
    bf16x8 a[2];
#pragma unroll
    for (int mt = 0; mt < 2; ++mt)
      a[mt] = *(const bf16x8*)(A + (size_t)(r0 + mt * 16 + lr) * 128 + kt * 32 + lg * 8);
#pragma unroll
    for (int n = 0; n < 6; ++n) {
      bf16x8 b = *(const bf16x8*)(pB + (((size_t)kt * 48 + wv * 6 + n) * 64 + lane) * 8);
      acc[0][n] = MFMA16(a[0], b, acc[0][n], 0, 0, 0);
      acc[1][n] = MFMA16(a[1], b, acc[1][n], 0, 0, 0);
    }
  }
#pragma unroll
  for (int mt = 0; mt < 2; ++mt)
#pragma unroll
    for (int n = 0; n < 6; ++n) {
      int col = wv * 96 + n * 16 + lr;
      int gate = col >> 8, wvc = (col >> 5) & 7, nt = (col >> 4) & 1;
      float bc = bias[col];
#pragma unroll
      for (int r = 0; r < 4; ++r) {
        int row = r0 + mt * 16 + lg * 4 + r;
        G2[(size_t)row * 1024 + wvc * 128 + lr * 8 + gate * 2 + nt] = (__bf16)(acc[mt][n][r] + bc);
      }
    }
}

// ------------------------------------------------------------ main RNN MFMA
// 16 waves x 1024 threads; wave wv owns h-cols [wv*16, wv*16+16).
__global__ __launch_bounds__(1024) void k_rnn_main_mfma(
    const __hip_bfloat16* __restrict__ em, const float* __restrict__ dtm,
    const __bf16* __restrict__ xself_bf, const __bf16* __restrict__ pWs,
    const __bf16* __restrict__ pWe, const __bf16* __restrict__ pU,
    const float* __restrict__ bg, const float* __restrict__ wt,
    float* __restrict__ hmain) {
  const int wv = threadIdx.x >> 6, lane = threadIdx.x & 63;
  const int lr = lane & 15, lg = lane >> 4;
  const int n0 = blockIdx.x * 32;
  const int hc = wv * 16 + lr;  // this thread's h-column
  __shared__ __align__(16) __bf16 hbuf[2][32 * 256];  // 32 KB
  __shared__ float dl[KK * 32];                       // 1.9 KB
  f32x4 z4 = {0.f, 0.f, 0.f, 0.f};

  for (int idx = threadIdx.x; idx < KK * 32; idx += 1024)
    dl[idx] = dtm[(idx >> 5) * 8192 + n0 + (idx & 31)];

  const float bz = bg[hc], br = bg[hc + 256], bn = bg[hc + 512];
  const float wtv = wt[hc];

  // gs = xself @ W[0:128]  (constant over t; A rows broadcast per b)
  f32x4 gs[3][2];
#pragma unroll
  for (int g = 0; g < 3; ++g)
#pragma unroll
    for (int mt = 0; mt < 2; ++mt) gs[g][mt] = z4;
#pragma unroll
  for (int kt = 0; kt < 4; ++kt) {
    bf16x8 a[2];
#pragma unroll
    for (int mt = 0; mt < 2; ++mt)
      a[mt] = *(const bf16x8*)(xself_bf + (size_t)((n0 + mt * 16) >> 4) * 128 + kt * 32 + lg * 8);
#pragma unroll
    for (int g = 0; g < 3; ++g) {
      bf16x8 b = *(const bf16x8*)(pWs + (((size_t)kt * 48 + g * 16 + wv) * 64 + lane) * 8);
#pragma unroll
      for (int mt = 0; mt < 2; ++mt) gs[g][mt] = MFMA16(a[mt], b, gs[g][mt], 0, 0, 0);
    }
  }

  float h[2][4];
#pragma unroll
  for (int mt = 0; mt < 2; ++mt)
#pragma unroll
    for (int r = 0; r < 4; ++r) h[mt][r] = 0.f;
  __syncthreads();

  for (int t = 0; t < KK; ++t) {
    __bf16* hb = hbuf[t & 1];
    float hd[2][4];
#pragma unroll
    for (int mt = 0; mt < 2; ++mt)
#pragma unroll
      for (int r = 0; r < 4; ++r) {
        float dtv = dl[t * 32 + mt * 16 + lg * 4 + r];
        hd[mt][r] = h[mt][r] * __expf(-fmaxf(dtv * wtv, 0.f));
      }
#pragma unroll
    for (int mt = 0; mt < 2; ++mt)
#pragma unroll
      for (int r = 0; r < 4; ++r) {
        int row = mt * 16 + lg * 4 + r;
        hb[((row * 256) + hc) ^ ((row & 7) << 3)] = (__bf16)hd[mt][r];
      }
    __syncthreads();

    // acc: 0=z(g+u), 1=r(g+u), 2=g_n, 3=u_n
    f32x4 acc[4][2];
#pragma unroll
    for (int mt = 0; mt < 2; ++mt) {
      acc[0][mt] = gs[0][mt];
      acc[1][mt] = gs[1][mt];
      acc[2][mt] = gs[2][mt];
      acc[3][mt] = z4;
    }
    // first e-GEMM A-tile issued early; latency hides under the u-GEMM
    bf16x8 ac[2], an[2];
#pragma unroll
    for (int mt = 0; mt < 2; ++mt)
      ac[mt] = *(const bf16x8*)(em + ((size_t)t * 8192 + n0 + mt * 16 + lr) * 128 + lg * 8);
    // u-GEMM (K=256) from LDS hd
#pragma unroll
    for (int kt = 0; kt < 8; ++kt) {
      bf16x8 a[2];
#pragma unroll
      for (int mt = 0; mt < 2; ++mt) {
        int row = mt * 16 + lr;
        int s = ((row * 256) + (kt * 32 + lg * 8)) ^ ((row & 7) << 3);
        a[mt] = *(const bf16x8*)&hb[s];
      }
#pragma unroll
      for (int g = 0; g < 3; ++g) {
        const int ai = (g < 2) ? g : 3;
        bf16x8 b = *(const bf16x8*)(pU + (((size_t)kt * 48 + g * 16 + wv) * 64 + lane) * 8);
#pragma unroll
        for (int mt = 0; mt < 2; ++mt) acc[ai][mt] = MFMA16(a[mt], b, acc[ai][mt], 0, 0, 0);
      }
    }
    // e-GEMM (K=128), 1-kt-ahead A pipeline
#pragma unroll
    for (int kt = 0; kt < 4; ++kt) {
      if (kt < 3) {
#pragma unroll
        for (int mt = 0; mt < 2; ++mt)
          an[mt] = *(const bf16x8*)(em + ((size_t)t * 8192 + n0 + mt * 16 + lr) * 128 +
                                    (kt + 1) * 32 + lg * 8);
      }
#pragma unroll
      for (int g = 0; g < 3; ++g) {
        bf16x8 b = *(const bf16x8*)(pWe + (((size_t)kt * 48 + g * 16 + wv) * 64 + lane) * 8);
#pragma unroll
        for (int mt = 0; mt < 2; ++mt) acc[g][mt] = MFMA16(ac[mt], b, acc[g][mt], 0, 0, 0);
      }
#pragma unroll
      for (int mt = 0; mt < 2; ++mt) ac[mt] = an[mt];
    }
    // gates
#pragma unroll
    for (int mt = 0; mt < 2; ++mt)
#pragma unroll
      for (int r = 0; r < 4; ++r) {
        float zz = sigm(acc[0][mt][r] + bz);
        float rr = sigm(acc[1][mt][r] + br);
        float nn = tanh_fast(acc[2][mt][r] + bn + rr * acc[3][mt][r]);
        h[mt][r] = (1.f - zz) * hd[mt][r] + zz * nn;
      }
  }
  __syncthreads();
#pragma unroll
  for (int mt = 0; mt < 2; ++mt)
#pragma unroll
    for (int r = 0; r < 4; ++r)
      hmain[(size_t)(n0 + mt * 16 + lg * 4 + r) * 256 + hc] = h[mt][r];
}

// ------------------------------------------------------------ cont RNN MFMA
// U_c kt0-5 persistent in registers (144 VGPR); kt6-7 staged in LDS (96KB).
__global__ __attribute__((amdgpu_flat_work_group_size(512, 512)))
__attribute__((amdgpu_waves_per_eu(2, 2))) void k_rnn_cont_mfma(
    const __bf16* __restrict__ G2, const float* __restrict__ dtc,
    const __bf16* __restrict__ pUc, const float* __restrict__ wt,
    float* __restrict__ hcont) {
  const int wv = threadIdx.x >> 6, lane = threadIdx.x & 63;
  const int lr = lane & 15, lg = lane >> 4;
  const int p0 = blockIdx.x * 16;
  __shared__ __align__(16) __bf16 hbuf[2][16 * 256];   // 16 KB
  __shared__ __align__(16) __bf16 uLds[2 * 48 * 512];  // 96 KB: kt 6,7
  __shared__ float dl[16 * 128];                       // 8 KB
  for (int idx = threadIdx.x; idx < 2048; idx += 512)
    dl[idx] = dtc[(p0 + (idx >> 7)) * 128 + (idx & 127)];
  // stage U kt6-7 into LDS
  {
    const uint4* src = (const uint4*)(pUc + (size_t)6 * 48 * 512);
    uint4* dst = (uint4*)uLds;
    for (int idx = threadIdx.x; idx < 2 * 48 * 64; idx += 512) dst[idx] = src[idx];
  }
  float wtv[2];
#pragma unroll
  for (int nt = 0; nt < 2; ++nt) wtv[nt] = wt[wv * 32 + nt * 16 + lr];
  // persistent U_c fragments kt0-5: [gate][nt][kt] (144 VGPR)
  bf16x8 bfr[3][2][6];
#pragma unroll
  for (int g = 0; g < 3; ++g)
#pragma unroll
    for (int nt = 0; nt < 2; ++nt)
#pragma unroll
      for (int kt = 0; kt < 6; ++kt)
        bfr[g][nt][kt] =
            *(const bf16x8*)(pUc + (((size_t)kt * 48 + g * 16 + wv * 2 + nt) * 64 + lane) * 8);
  float h[2][4];
#pragma unroll
  for (int nt = 0; nt < 2; ++nt)
#pragma unroll
    for (int r = 0; r < 4; ++r) h[nt][r] = 0.f;

  const uint4* G2v = (const uint4*)G2;
  const size_t gb0 = (size_t)(p0 + lg * 4) * 16384 + wv * 16 + lr;
  __syncthreads();  // dl + uLds ready

  for (int t = 0; t < 128; ++t) {
    __bf16* hb = hbuf[t & 1];
    // issue this step's G loads early (consumed at gates, ~1k cyc later)
    uint4 Gv[4];
#pragma unroll
    for (int r = 0; r < 4; ++r) Gv[r] = G2v[gb0 + (size_t)r * 16384 + (size_t)t * 128];
    float hd[2][4];
#pragma unroll
    for (int r = 0; r < 4; ++r) {
      float dtv = dl[(lg * 4 + r) * 128 + t];
#pragma unroll
      for (int nt = 0; nt < 2; ++nt) hd[nt][r] = h[nt][r] * __expf(-fmaxf(dtv * wtv[nt], 0.f));
    }
#pragma unroll
    for (int nt = 0; nt < 2; ++nt)
#pragma unroll
      for (int r = 0; r < 4; ++r) {
        int row = lg * 4 + r;
        hb[((row * 256) + (wv * 32 + nt * 16 + lr)) ^ ((row & 7) << 3)] = (__bf16)hd[nt][r];
      }
    __syncthreads();
    f32x4 acc[3][2];
#pragma unroll
    for (int g = 0; g < 3; ++g)
#pragma unroll
      for (int nt = 0; nt < 2; ++nt) acc[g][nt] = f32x4{0.f, 0.f, 0.f, 0.f};
#pragma unroll
    for (int kt = 0; kt < 8; ++kt) {
      int s = ((lr * 256) + (kt * 32 + lg * 8)) ^ ((lr & 7) << 3);
      bf16x8 a = *(const bf16x8*)&hb[s];
      if (kt < 6) {
#pragma unroll
        for (int nt = 0; nt < 2; ++nt) {
          acc[0][nt] = MFMA16(a, bfr[0][nt][kt], acc[0][nt], 0, 0, 0);
          acc[1][nt] = MFMA16(a, bfr[1][nt][kt], acc[1][nt], 0, 0, 0);
          acc[2][nt] = MFMA16(a, bfr[2][nt][kt], acc[2][nt], 0, 0, 0);
        }
      } else {
#pragma unroll
        for (int g = 0; g < 3; ++g)
#pragma unroll
          for (int nt = 0; nt < 2; ++nt) {
            bf16x8 b = *(const bf16x8*)&uLds[(((kt - 6) * 48 + g * 16 + wv * 2 + nt) * 64 + lane) * 8];
            acc[g][nt] = MFMA16(a, b, acc[g][nt], 0, 0, 0);
          }
      }
    }
#pragma unroll
    for (int nt = 0; nt < 2; ++nt)
#pragma unroll
      for (int r = 0; r < 4; ++r) {
        unsigned uz = nt ? (Gv[r].x >> 16) : (Gv[r].x & 0xffffu);
        unsigned ur = nt ? (Gv[r].y >> 16) : (Gv[r].y & 0xffffu);
        unsigned un = nt ? (Gv[r].z >> 16) : (Gv[r].z & 0xffffu);
        float zz = sigm(bfu(uz) + acc[0][nt][r]);
        float rr = sigm(bfu(ur) + acc[1][nt][r]);
        float nn = tanh_fast(bfu(un) + rr * acc[2][nt][r]);
        float hnew = (1.f - zz) * hd[nt][r] + zz * nn;
        h[nt][r] = hnew;
        if (t >= 124)
          hcont[((size_t)(p0 + lg * 4 + r) * 4 + (t - 124)) * 256 + wv * 32 + nt * 16 + lr] = hnew;
      }
  }
}

// ------------------------------------------------------------------ tail
__global__ __launch_bounds__(256) void k_att(const float* __restrict__ hmain,
                                             const float* __restrict__ xself,
                                             const float* __restrict__ hc,
                                             const float* __restrict__ Wv,
                                             const float* __restrict__ bv,
                                             float* __restrict__ hh) {
  int b = blockIdx.x, tid = threadIdx.x;
  __shared__ float hl[16 * 256];
  __shared__ float aa[16 * 4];
  for (int idx = tid; idx < 4096; idx += 256) hl[idx] = hmain[(size_t)b * SS * HH + idx];
  __syncthreads();
  if (tid < 64) {
    int s = tid >> 2, m = tid & 3;
    float acc = bv[m];
    for (int j = 0; j < 256; ++j)
      acc += hl[s * 256 + j] * Wv[j * 4 + m] + hl[j] * Wv[(256 + j) * 4 + m];
    aa[s * 4 + m] = tanh_fast(acc);
  }
  __syncthreads();
  if (tid < 4) {
    int m = tid;
    float mx = -1e30f;
    for (int s = 0; s < 16; ++s) mx = fmaxf(mx, aa[s * 4 + m]);
    float sum = 0.f;
    for (int s = 0; s < 16; ++s) sum += __expf(aa[s * 4 + m] - mx);
    float inv = 1.f / sum;
    for (int s = 0; s < 16; ++s) aa[s * 4 + m] = __expf(aa[s * 4 + m] - mx) * inv;
  }
  __syncthreads();
  float a0 = 0.f, a1 = 0.f, a2 = 0.f, a3 = 0.f;
  for (int s = 0; s < 16; ++s) {
    float hv = hl[s * 256 + tid];
    a0 = fmaf(aa[s * 4 + 0], hv, a0);
    a1 = fmaf(aa[s * 4 + 1], hv, a1);
    a2 = fmaf(aa[s * 4 + 2], hv, a2);
    a3 = fmaf(aa[s * 4 + 3], hv, a3);
  }
  float* hb = hh + (size_t)b * 1664;
  hb[384 + 0 * 256 + tid] = a0;
  hb[384 + 1 * 256 + tid] = a1;
  hb[384 + 2 * 256 + tid] = a2;
  hb[384 + 3 * 256 + tid] = a3;
  if (tid < 128) hb[tid] = xself[b * DD + tid];
  hb[128 + tid] = hl[tid];
  hb[1408 + tid] = hc[(size_t)b * HH + tid];
}

__global__ __launch_bounds__(256) void k_mlp(const float* __restrict__ A,
                                             const float* __restrict__ W,
                                             const float* __restrict__ bias,
                                             float* __restrict__ C, int K, int N) {
  int tid = threadIdx.x;
  int j = blockIdx.x * 256 + tid;
  int rb = blockIdx.y * 16;
  __shared__ float al[16 * 512];
  float acc[16];
#pragma unroll
  for (int r = 0; r < 16; ++r) acc[r] = 0.f;
  for (int kc = 0; kc < K; kc += 512) {
    int ch = K - kc;
    if (ch > 512) ch = 512;
    __syncthreads();
#pragma unroll
    for (int r = 0; r < 16; ++r)
      for (int k = tid; k < ch; k += 256) al[r * 512 + k] = A[(size_t)(rb + r) * K + kc + k];
    __syncthreads();
    for (int k = 0; k < ch; ++k) {
      float w = W[(size_t)(kc + k) * N + j];
#pragma unroll
      for (int r = 0; r < 16; ++r) acc[r] = fmaf(al[r * 512 + k], w, acc[r]);
    }
  }
  float bj = bias[j];
#pragma unroll
  for (int r = 0; r < 16; ++r) {
    float v = acc[r] + bj;
    C[(size_t)(rb + r) * N + j] = v > 0.f ? v : 0.01f * v;
  }
}

__global__ __launch_bounds__(64) void k_head(const float* __restrict__ A,
                                             const float* __restrict__ Wp,
                                             const float* __restrict__ bp,
                                             float* __restrict__ out) {
  int row = blockIdx.x, l = threadIdx.x;
  float acc = 0.f;
  for (int j = l; j < 256; j += 64) acc = fmaf(A[(size_t)row * 256 + j], Wp[j], acc);
  for (int o = 32; o; o >>= 1) acc += __shfl_xor(acc, o);
  if (l == 0) out[row] = 1.f / (1.f + __expf(-(acc + bp[0])));
}

extern "C" void kernel_launch(void* const* d_in, const int* in_sizes, int n_in,
                              void* d_out, int out_size, void* d_ws, size_t ws_size,
                              hipStream_t stream) {
  const int* x = (const int*)d_in[0];
  const int* xc = (const int*)d_in[1];
  const int* self_loc = (const int*)d_in[2];
  const float* emb = (const float*)d_in[3];
  const float* W_rnn = (const float*)d_in[4];
  const float* U_rnn = (const float*)d_in[5];
  const float* b_rnn = (const float*)d_in[6];
  const float* wt_rnn = (const float*)d_in[7];
  const float* W_c = (const float*)d_in[8];
  const float* U_c = (const float*)d_in[9];
  const float* b_c = (const float*)d_in[10];
  const float* wt_c = (const float*)d_in[11];
  const float* Wv = (const float*)d_in[12];
  const float* bv = (const float*)d_in[13];
  const float* W0 = (const float*)d_in[14];
  const float* b0 = (const float*)d_in[15];
  const float* W1 = (const float*)d_in[16];
  const float* b1 = (const float*)d_in[17];
  const float* W2 = (const float*)d_in[18];
  const float* b2 = (const float*)d_in[19];
  const float* Wp = (const float*)d_in[20];
  const float* bp = (const float*)d_in[21];
  float* out = (float*)d_out;

  char* ws = (char*)d_ws;
  size_t cur = 0;
  auto alloc = [&](size_t bytes) {
    char* p = ws + cur;
    cur += (bytes + 255) & ~(size_t)255;
    return p;
  };
  float* es = (float*)alloc((size_t)BB * DD * 4);
  float* ns = (float*)alloc(BB * 4);
  unsigned* minu = (unsigned*)alloc(4);
  float* simw = (float*)alloc((size_t)BB * SS * II * 4);
  int* topidx = (int*)alloc((size_t)BB * SS * KK * 4);
  float* xself = (float*)alloc((size_t)BB * DD * 4);
  __bf16* xself_bf = (__bf16*)alloc((size_t)BB * DD * 2);
  float* dtm = (float*)alloc((size_t)KK * 8192 * 4);
  float* dtc = (float*)alloc((size_t)128 * 128 * 4);
  float* hcont = (float*)alloc((size_t)BB * HH * 4);
  float* hh = (float*)alloc((size_t)BB * 1664 * 4);
  float* z0 = (float*)alloc((size_t)BB * 1024 * 4);
  float* z1 = (float*)alloc((size_t)BB * 512 * 4);
  float* z2 = (float*)alloc((size_t)BB * 256 * 4);
  float* hmain = (float*)alloc((size_t)8192 * HH * 4);
  __hip_bfloat16* ec = (__hip_bfloat16*)alloc((size_t)16384 * DD * 2);
  __hip_bfloat16* em = (__hip_bfloat16*)alloc((size_t)KK * 8192 * DD * 2);
  __bf16* G2 = (__bf16*)alloc((size_t)16384 * 1024 * 2);
  __bf16* pWs = (__bf16*)alloc((size_t)4 * 48 * 64 * 8 * 2);
  __bf16* pWe = (__bf16*)alloc((size_t)4 * 48 * 64 * 8 * 2);
  __bf16* pU = (__bf16*)alloc((size_t)8 * 48 * 64 * 8 * 2);
  __bf16* pWc = (__bf16*)alloc((size_t)4 * 48 * 64 * 8 * 2);
  __bf16* pUc = (__bf16*)alloc((size_t)8 * 48 * 64 * 8 * 2);
  (void)ws_size;

  hipLaunchKernelGGL(k_init, dim3(1), dim3(1), 0, stream, minu);
  hipLaunchKernelGGL(k_eself, dim3(BB), dim3(128), 0, stream, x, self_loc, emb, es, ns);
  hipLaunchKernelGGL(k_cos, dim3(BB * SS), dim3(256), 0, stream, x, emb, es, ns, simw, minu);
  hipLaunchKernelGGL(k_topk, dim3(BB * SS), dim3(64), 0, stream, x, simw, minu, topidx);
  hipLaunchKernelGGL(k_build_main, dim3(1024, KK), dim3(256), 0, stream, x, self_loc, emb,
                     topidx, em, dtm, xself, xself_bf);
  hipLaunchKernelGGL(k_build_cont, dim3(128, 128), dim3(128), 0, stream, xc, emb, ec, dtc);
  hipLaunchKernelGGL(k_pack, dim3(4, 48), dim3(64), 0, stream, W_rnn, pWs);
  hipLaunchKernelGGL(k_pack, dim3(4, 48), dim3(64), 0, stream, W_rnn + 128 * 768, pWe);
  hipLaunchKernelGGL(k_pack, dim3(8, 48), dim3(64), 0, stream, U_rnn, pU);
  hipLaunchKernelGGL(k_pack, dim3(4, 48), dim3(64), 0, stream, W_c, pWc);
  hipLaunchKernelGGL(k_pack, dim3(8, 48), dim3(64), 0, stream, U_c, pUc);
  hipLaunchKernelGGL(k_gemm_g, dim3(512), dim3(512), 0, stream, ec, pWc, b_c, G2);
  hipLaunchKernelGGL(k_rnn_main_mfma, dim3(256), dim3(1024), 0, stream, em, dtm, xself_bf,
                     pWs, pWe, pU, b_rnn, wt_rnn, hmain);
  hipLaunchKernelGGL(k_rnn_cont_mfma, dim3(8), dim3(512), 0, stream, G2, dtc, pUc, wt_c,
                     hcont);
  hipLaunchKernelGGL(k_att, dim3(BB), dim3(256), 0, stream, hmain, xself, hcont, Wv, bv, hh);
  hipLaunchKernelGGL(k_mlp, dim3(4, 32), dim3(256), 0, stream, hh, W0, b0, z0, 1664, 1024);
  hipLaunchKernelGGL(k_mlp, dim3(2, 32), dim3(256), 0, stream, z0, W1, b1, z1, 1024, 512);
  hipLaunchKernelGGL(k_mlp, dim3(1, 32), dim3(256), 0, stream, z1, W2, b2, z2, 512, 256);
  hipLaunchKernelGGL(k_head, dim3(BB), dim3(64), 0, stream, z2, Wp, bp, out);
}

// Round 7
// 1739.212 us; speedup vs baseline: 2.8406x; 1.0031x over previous
//
#include <hip/hip_runtime.h>
#include <hip/hip_bf16.h>

// SearchPredictModel round 7: explicit occupancy tier via __launch_bounds__
// second arg (min BLOCKS per CU, CUDA semantics):
//   main: (1024,1) -> 4 waves/SIMD -> 128-VGPR budget >= ~116 demand.
//   cont: (512,1)  -> 2 waves/SIMD -> 256-VGPR budget >= ~220 demand.
// Everything else unchanged from round 6.

#define PAD_TOK 200000
#define DD 128
#define HH 256
#define KK 15
#define BB 512
#define SS 16
#define II 64

typedef __bf16 bf16x8 __attribute__((ext_vector_type(8)));
typedef __bf16 bf16x4 __attribute__((ext_vector_type(4)));
typedef float f32x4 __attribute__((ext_vector_type(4)));
#define MFMA16 __builtin_amdgcn_mfma_f32_16x16x32_bf16

__device__ __forceinline__ float sigm(float x) { return 1.f / (1.f + __expf(-x)); }
__device__ __forceinline__ float tanh_fast(float x) {
  x = fminf(fmaxf(x, -15.f), 15.f);
  float e2 = __expf(2.f * x);
  return (e2 - 1.f) / (e2 + 1.f);
}
__device__ __forceinline__ float bfu(unsigned u16) { return __uint_as_float(u16 << 16); }

// ---------------------------------------------------------------- front end
__global__ __launch_bounds__(128) void k_eself(const int* __restrict__ x,
                                               const int* __restrict__ self_loc,
                                               const float* __restrict__ emb,
                                               float* __restrict__ es,
                                               float* __restrict__ ns) {
  int b = blockIdx.x, d = threadIdx.x;
  int tok = x[((size_t)(b * SS + 0) * II + self_loc[b]) * 8 + 5];
  float v = emb[(size_t)tok * DD + d];
  es[b * DD + d] = v;
  __shared__ float red[128];
  red[d] = v * v;
  __syncthreads();
  for (int o = 64; o > 0; o >>= 1) {
    if (d < o) red[d] += red[d + o];
    __syncthreads();
  }
  if (d == 0) ns[b] = fmaxf(sqrtf(red[0]), 1e-8f);
}

__global__ void k_init(unsigned* minu) { *minu = 0xFFFFFFFFu; }

// one block per row (b,s); 64 items x 4 lanes each
__global__ __launch_bounds__(256) void k_cos(const int* __restrict__ x,
                                             const float* __restrict__ emb,
                                             const float* __restrict__ es,
                                             const float* __restrict__ ns,
                                             float* __restrict__ simw,
                                             unsigned* __restrict__ minu) {
  int row = blockIdx.x;
  int b = row >> 4;
  int tid = threadIdx.x;
  int i = tid >> 2;  // item
  int q = tid & 3;   // dim quarter (32 dims)
  __shared__ float esl[128];
  __shared__ unsigned smin[64];
  if (tid < 128) esl[tid] = es[b * DD + tid];
  __syncthreads();
  const int* xr = x + ((size_t)row * II + i) * 8;
  int tok = xr[5];
  int first = xr[0];
  const float4* ep = (const float4*)(emb + (size_t)tok * DD + q * 32);
  const float4* sp = (const float4*)(esl + q * 32);
  float dot = 0.f, ss = 0.f;
#pragma unroll
  for (int j = 0; j < 8; ++j) {
    float4 a = ep[j];
    float4 e = sp[j];
    dot += a.x * e.x + a.y * e.y + a.z * e.z + a.w * e.w;
    ss += a.x * a.x + a.y * a.y + a.z * a.z + a.w * a.w;
  }
  dot += __shfl_xor(dot, 1);
  ss += __shfl_xor(ss, 1);
  dot += __shfl_xor(dot, 2);
  ss += __shfl_xor(ss, 2);
  if (q == 0) {
    float cosv = dot / (fmaxf(sqrtf(ss), 1e-8f) * ns[b]);
    simw[(size_t)row * II + i] = cosv;
    unsigned key = 0xFFFFFFFFu;
    if (first != PAD_TOK) {
      unsigned u = __float_as_uint(cosv);
      key = (cosv < 0.f) ? ~u : (u | 0x80000000u);
    }
    smin[i] = key;
  }
  __syncthreads();
  if (tid < 64) {
    unsigned m = smin[tid];
    for (int o = 32; o; o >>= 1) m = min(m, __shfl_xor(m, o));
    if (tid == 0 && m != 0xFFFFFFFFu) atomicMin(minu, m);
  }
}

__global__ __launch_bounds__(64) void k_topk(const int* __restrict__ x,
                                             const float* __restrict__ simw,
                                             const unsigned* __restrict__ minu,
                                             int* __restrict__ topidx) {
  int row = blockIdx.x, i = threadIdx.x;
  unsigned mk = *minu;
  float neg = ((mk & 0x80000000u) ? __uint_as_float(mk ^ 0x80000000u) : __uint_as_float(~mk)) - 1.0f;
  float c = simw[(size_t)row * II + i];
  bool real = x[((size_t)row * II + i) * 8] != PAD_TOK;
  float s = real ? c : neg;
  __shared__ float sv[64];
  sv[i] = s;
  __syncthreads();
  int rank = 0;
  for (int j = 0; j < 64; ++j) {
    float o = sv[j];
    rank += (o > s) || (o == s && j < i);
  }
  bool sel = rank < KK;
  unsigned long long mask = __ballot(sel);
  if (sel) {
    int pos = __popcll(mask & ((1ull << i) - 1ull));
    topidx[row * KK + pos] = i;
  }
}

// 8 items/block x 32 lanes (float4 per lane)
__global__ __launch_bounds__(256) void k_build_main(const int* __restrict__ x,
                                                    const int* __restrict__ self_loc,
                                                    const float* __restrict__ emb,
                                                    const int* __restrict__ topidx,
                                                    __hip_bfloat16* __restrict__ em,
                                                    float* __restrict__ dtm,
                                                    float* __restrict__ xself,
                                                    __bf16* __restrict__ xself_bf) {
  int t = blockIdx.y;
  int n = blockIdx.x * 8 + (threadIdx.x >> 5);
  int q = threadIdx.x & 31;  // dims [q*4, q*4+4)
  int b = n >> 4, s = n & 15;
  bool ovr = (s == 0) && (t == KK - 1);
  int item = ovr ? self_loc[b] : topidx[n * KK + t];
  const int* xr = x + ((size_t)n * II + item) * 8;
  int toks[6];
#pragma unroll
  for (int jj = 0; jj < 6; ++jj) toks[jj] = xr[jj];
  float4 acc = {0.f, 0.f, 0.f, 0.f};
#pragma unroll
  for (int jj = 0; jj < 6; ++jj) {
    float4 v = *(const float4*)(emb + (size_t)toks[jj] * DD + q * 4);
    acc.x += v.x;
    acc.y += v.y;
    acc.z += v.z;
    acc.w += v.w;
  }
  bf16x4 ov = {(__bf16)acc.x, (__bf16)acc.y, (__bf16)acc.z, (__bf16)acc.w};
  *(bf16x4*)((__bf16*)em + ((size_t)t * 8192 + n) * DD + q * 4) = ov;
  if (ovr) {
    *(float4*)(xself + b * DD + q * 4) = acc;
    *(bf16x4*)(xself_bf + b * DD + q * 4) = ov;
  }
  if (q == 0) {
    float dtv = 0.f;
    if (t > 0) {
      int pitem = topidx[n * KK + t - 1];
      dtv = (float)xr[6] - (float)x[((size_t)n * II + pitem) * 8 + 6];
    }
    dtm[t * 8192 + n] = dtv;
  }
}

__global__ __launch_bounds__(128) void k_build_cont(const int* __restrict__ xc,
                                                    const float* __restrict__ emb,
                                                    __hip_bfloat16* __restrict__ ec,
                                                    float* __restrict__ dtc) {
  int p = blockIdx.x, t = blockIdx.y, d = threadIdx.x;
  const int* xr = xc + ((size_t)p * 128 + t) * 8;
  float acc = 0.f;
#pragma unroll
  for (int jj = 0; jj < 6; ++jj) acc += emb[(size_t)xr[jj] * DD + d];
  ec[((size_t)p * 128 + t) * DD + d] = __float2bfloat16(acc);
  if (d == 0) dtc[p * 128 + t] = (t > 0) ? ((float)xr[6] - (float)xr[-2]) : 0.f;
}

// ------------------------------------------------- weight fragment packing
__global__ __launch_bounds__(64) void k_pack(const float* __restrict__ B,
                                             __bf16* __restrict__ out) {
  int kt = blockIdx.x, tile = blockIdx.y, lane = threadIdx.x;
  const float* src = B + (size_t)(kt * 32 + (lane >> 4) * 8) * 768 + tile * 16 + (lane & 15);
  __bf16* o = out + (((size_t)(kt * 48 + tile) * 64 + lane) * 8);
#pragma unroll
  for (int i = 0; i < 8; ++i) o[i] = (__bf16)src[(size_t)i * 768];
}

// -------- cont-RNN g precompute: G2 (fragment-packed) = ec@Wc + b
// G2[rowflat*1024 + wvc*128 + lr*8 + gate*2 + nt], rowflat = p*128+t
__global__ __launch_bounds__(512) void k_gemm_g(const __hip_bfloat16* __restrict__ A,
                                                const __bf16* __restrict__ pB,
                                                const float* __restrict__ bias,
                                                __bf16* __restrict__ G2) {
  const int wv = threadIdx.x >> 6, lane = threadIdx.x & 63;
  const int lr = lane & 15, lg = lane >> 4;
  const int r0 = blockIdx.x * 32;
  f32x4 z4 = {0.f, 0.f, 0.f, 0.f};
  f32x4 acc[2][6];
#pragma unroll
  for (int mt = 0; mt < 2; ++mt)
#pragma unroll
    for (int n = 0; n < 6; ++n) acc[mt][n] = z4;
#pragma unroll
  for (int kt = 0; kt < 4; ++kt) {
    bf16x8 a[2];
#pragma unroll
    for (int mt = 0; mt < 2; ++mt)
      a[mt] = *(const bf16x8*)(A + (size_t)(r0 + mt * 16 + lr) * 128 + kt * 32 + lg * 8);
#pragma unroll
    for (int n = 0; n < 6; ++n) {
      bf16x8 b = *(const bf16x8*)(pB + (((size_t)kt * 48 + wv * 6 + n) * 64 + lane) * 8);
      acc[0][n] = MFMA16(a[0], b, acc[0][n], 0, 0, 0);
      acc[1][n] = MFMA16(a[1], b, acc[1][n], 0, 0, 0);
    }
  }
#pragma unroll
  for (int mt = 0; mt < 2; ++mt)
#pragma unroll
    for (int n = 0; n < 6; ++n) {
      int col = wv * 96 + n * 16 + lr;
      int gate = col >> 8, wvc = (col >> 5) & 7, nt = (col >> 4) & 1;
      float bc = bias[col];
#pragma unroll
      for (int r = 0; r < 4; ++r) {
        int row = r0 + mt * 16 + lg * 4 + r;
        G2[(size_t)row * 1024 + wvc * 128 + lr * 8 + gate * 2 + nt] = (__bf16)(acc[mt][n][r] + bc);
      }
    }
}

// ------------------------------------------------------------ main RNN MFMA
// 16 waves x 1024 threads; wave wv owns h-cols [wv*16, wv*16+16).
// (1024,1): 1 block/CU -> 4 waves/SIMD -> 128-VGPR budget (demand ~116).
__global__ __launch_bounds__(1024, 1) void k_rnn_main_mfma(
    const __hip_bfloat16* __restrict__ em, const float* __restrict__ dtm,
    const __bf16* __restrict__ xself_bf, const __bf16* __restrict__ pWs,
    const __bf16* __restrict__ pWe, const __bf16* __restrict__ pU,
    const float* __restrict__ bg, const float* __restrict__ wt,
    float* __restrict__ hmain) {
  const int wv = threadIdx.x >> 6, lane = threadIdx.x & 63;
  const int lr = lane & 15, lg = lane >> 4;
  const int n0 = blockIdx.x * 32;
  const int hc = wv * 16 + lr;  // this thread's h-column
  __shared__ __align__(16) __bf16 hbuf[2][32 * 256];  // 32 KB
  __shared__ float dl[KK * 32];                       // 1.9 KB
  f32x4 z4 = {0.f, 0.f, 0.f, 0.f};

  for (int idx = threadIdx.x; idx < KK * 32; idx += 1024)
    dl[idx] = dtm[(idx >> 5) * 8192 + n0 + (idx & 31)];

  const float bz = bg[hc], br = bg[hc + 256], bn = bg[hc + 512];
  const float wtv = wt[hc];

  // gs = xself @ W[0:128]  (constant over t; A rows broadcast per b)
  f32x4 gs[3][2];
#pragma unroll
  for (int g = 0; g < 3; ++g)
#pragma unroll
    for (int mt = 0; mt < 2; ++mt) gs[g][mt] = z4;
#pragma unroll
  for (int kt = 0; kt < 4; ++kt) {
    bf16x8 a[2];
#pragma unroll
    for (int mt = 0; mt < 2; ++mt)
      a[mt] = *(const bf16x8*)(xself_bf + (size_t)((n0 + mt * 16) >> 4) * 128 + kt * 32 + lg * 8);
#pragma unroll
    for (int g = 0; g < 3; ++g) {
      bf16x8 b = *(const bf16x8*)(pWs + (((size_t)kt * 48 + g * 16 + wv) * 64 + lane) * 8);
#pragma unroll
      for (int mt = 0; mt < 2; ++mt) gs[g][mt] = MFMA16(a[mt], b, gs[g][mt], 0, 0, 0);
    }
  }

  float h[2][4];
#pragma unroll
  for (int mt = 0; mt < 2; ++mt)
#pragma unroll
    for (int r = 0; r < 4; ++r) h[mt][r] = 0.f;
  __syncthreads();

  for (int t = 0; t < KK; ++t) {
    __bf16* hb = hbuf[t & 1];
    float hd[2][4];
#pragma unroll
    for (int mt = 0; mt < 2; ++mt)
#pragma unroll
      for (int r = 0; r < 4; ++r) {
        float dtv = dl[t * 32 + mt * 16 + lg * 4 + r];
        hd[mt][r] = h[mt][r] * __expf(-fmaxf(dtv * wtv, 0.f));
      }
#pragma unroll
    for (int mt = 0; mt < 2; ++mt)
#pragma unroll
      for (int r = 0; r < 4; ++r) {
        int row = mt * 16 + lg * 4 + r;
        hb[((row * 256) + hc) ^ ((row & 7) << 3)] = (__bf16)hd[mt][r];
      }
    __syncthreads();

    // acc: 0=z(g+u), 1=r(g+u), 2=g_n, 3=u_n
    f32x4 acc[4][2];
#pragma unroll
    for (int mt = 0; mt < 2; ++mt) {
      acc[0][mt] = gs[0][mt];
      acc[1][mt] = gs[1][mt];
      acc[2][mt] = gs[2][mt];
      acc[3][mt] = z4;
    }
    // first e-GEMM A-tile issued early; latency hides under the u-GEMM
    bf16x8 ac[2], an[2];
#pragma unroll
    for (int mt = 0; mt < 2; ++mt)
      ac[mt] = *(const bf16x8*)(em + ((size_t)t * 8192 + n0 + mt * 16 + lr) * 128 + lg * 8);
    // u-GEMM (K=256) from LDS hd
#pragma unroll
    for (int kt = 0; kt < 8; ++kt) {
      bf16x8 a[2];
#pragma unroll
      for (int mt = 0; mt < 2; ++mt) {
        int row = mt * 16 + lr;
        int s = ((row * 256) + (kt * 32 + lg * 8)) ^ ((row & 7) << 3);
        a[mt] = *(const bf16x8*)&hb[s];
      }
#pragma unroll
      for (int g = 0; g < 3; ++g) {
        const int ai = (g < 2) ? g : 3;
        bf16x8 b = *(const bf16x8*)(pU + (((size_t)kt * 48 + g * 16 + wv) * 64 + lane) * 8);
#pragma unroll
        for (int mt = 0; mt < 2; ++mt) acc[ai][mt] = MFMA16(a[mt], b, acc[ai][mt], 0, 0, 0);
      }
    }
    // e-GEMM (K=128), 1-kt-ahead A pipeline
#pragma unroll
    for (int kt = 0; kt < 4; ++kt) {
      if (kt < 3) {
#pragma unroll
        for (int mt = 0; mt < 2; ++mt)
          an[mt] = *(const bf16x8*)(em + ((size_t)t * 8192 + n0 + mt * 16 + lr) * 128 +
                                    (kt + 1) * 32 + lg * 8);
      }
#pragma unroll
      for (int g = 0; g < 3; ++g) {
        bf16x8 b = *(const bf16x8*)(pWe + (((size_t)kt * 48 + g * 16 + wv) * 64 + lane) * 8);
#pragma unroll
        for (int mt = 0; mt < 2; ++mt) acc[g][mt] = MFMA16(ac[mt], b, acc[g][mt], 0, 0, 0);
      }
#pragma unroll
      for (int mt = 0; mt < 2; ++mt) ac[mt] = an[mt];
    }
    // gates
#pragma unroll
    for (int mt = 0; mt < 2; ++mt)
#pragma unroll
      for (int r = 0; r < 4; ++r) {
        float zz = sigm(acc[0][mt][r] + bz);
        float rr = sigm(acc[1][mt][r] + br);
        float nn = tanh_fast(acc[2][mt][r] + bn + rr * acc[3][mt][r]);
        h[mt][r] = (1.f - zz) * hd[mt][r] + zz * nn;
      }
  }
  __syncthreads();
#pragma unroll
  for (int mt = 0; mt < 2; ++mt)
#pragma unroll
    for (int r = 0; r < 4; ++r)
      hmain[(size_t)(n0 + mt * 16 + lg * 4 + r) * 256 + hc] = h[mt][r];
}

// ------------------------------------------------------------ cont RNN MFMA
// U_c kt0-5 persistent in registers (144 VGPR); kt6-7 staged in LDS (96KB).
// (512,1): 1 block/CU -> 2 waves/SIMD -> 256-VGPR budget (demand ~220).
__global__ __launch_bounds__(512, 1) void k_rnn_cont_mfma(
    const __bf16* __restrict__ G2, const float* __restrict__ dtc,
    const __bf16* __restrict__ pUc, const float* __restrict__ wt,
    float* __restrict__ hcont) {
  const int wv = threadIdx.x >> 6, lane = threadIdx.x & 63;
  const int lr = lane & 15, lg = lane >> 4;
  const int p0 = blockIdx.x * 16;
  __shared__ __align__(16) __bf16 hbuf[2][16 * 256];   // 16 KB
  __shared__ __align__(16) __bf16 uLds[2 * 48 * 512];  // 96 KB: kt 6,7
  __shared__ float dl[16 * 128];                       // 8 KB
  for (int idx = threadIdx.x; idx < 2048; idx += 512)
    dl[idx] = dtc[(p0 + (idx >> 7)) * 128 + (idx & 127)];
  // stage U kt6-7 into LDS
  {
    const uint4* src = (const uint4*)(pUc + (size_t)6 * 48 * 512);
    uint4* dst = (uint4*)uLds;
    for (int idx = threadIdx.x; idx < 2 * 48 * 64; idx += 512) dst[idx] = src[idx];
  }
  float wtv[2];
#pragma unroll
  for (int nt = 0; nt < 2; ++nt) wtv[nt] = wt[wv * 32 + nt * 16 + lr];
  // persistent U_c fragments kt0-5: [gate][nt][kt] (144 VGPR)
  bf16x8 bfr[3][2][6];
#pragma unroll
  for (int g = 0; g < 3; ++g)
#pragma unroll
    for (int nt = 0; nt < 2; ++nt)
#pragma unroll
      for (int kt = 0; kt < 6; ++kt)
        bfr[g][nt][kt] =
            *(const bf16x8*)(pUc + (((size_t)kt * 48 + g * 16 + wv * 2 + nt) * 64 + lane) * 8);
  float h[2][4];
#pragma unroll
  for (int nt = 0; nt < 2; ++nt)
#pragma unroll
    for (int r = 0; r < 4; ++r) h[nt][r] = 0.f;

  const uint4* G2v = (const uint4*)G2;
  const size_t gb0 = (size_t)(p0 + lg * 4) * 16384 + wv * 16 + lr;
  __syncthreads();  // dl + uLds ready

  for (int t = 0; t < 128; ++t) {
    __bf16* hb = hbuf[t & 1];
    // issue this step's G loads early (consumed at gates, ~1k cyc later)
    uint4 Gv[4];
#pragma unroll
    for (int r = 0; r < 4; ++r) Gv[r] = G2v[gb0 + (size_t)r * 16384 + (size_t)t * 128];
    float hd[2][4];
#pragma unroll
    for (int r = 0; r < 4; ++r) {
      float dtv = dl[(lg * 4 + r) * 128 + t];
#pragma unroll
      for (int nt = 0; nt < 2; ++nt) hd[nt][r] = h[nt][r] * __expf(-fmaxf(dtv * wtv[nt], 0.f));
    }
#pragma unroll
    for (int nt = 0; nt < 2; ++nt)
#pragma unroll
      for (int r = 0; r < 4; ++r) {
        int row = lg * 4 + r;
        hb[((row * 256) + (wv * 32 + nt * 16 + lr)) ^ ((row & 7) << 3)] = (__bf16)hd[nt][r];
      }
    __syncthreads();
    f32x4 acc[3][2];
#pragma unroll
    for (int g = 0; g < 3; ++g)
#pragma unroll
      for (int nt = 0; nt < 2; ++nt) acc[g][nt] = f32x4{0.f, 0.f, 0.f, 0.f};
#pragma unroll
    for (int kt = 0; kt < 8; ++kt) {
      int s = ((lr * 256) + (kt * 32 + lg * 8)) ^ ((lr & 7) << 3);
      bf16x8 a = *(const bf16x8*)&hb[s];
      if (kt < 6) {
#pragma unroll
        for (int nt = 0; nt < 2; ++nt) {
          acc[0][nt] = MFMA16(a, bfr[0][nt][kt], acc[0][nt], 0, 0, 0);
          acc[1][nt] = MFMA16(a, bfr[1][nt][kt], acc[1][nt], 0, 0, 0);
          acc[2][nt] = MFMA16(a, bfr[2][nt][kt], acc[2][nt], 0, 0, 0);
        }
      } else {
#pragma unroll
        for (int g = 0; g < 3; ++g)
#pragma unroll
          for (int nt = 0; nt < 2; ++nt) {
            bf16x8 b = *(const bf16x8*)&uLds[(((kt - 6) * 48 + g * 16 + wv * 2 + nt) * 64 + lane) * 8];
            acc[g][nt] = MFMA16(a, b, acc[g][nt], 0, 0, 0);
          }
      }
    }
#pragma unroll
    for (int nt = 0; nt < 2; ++nt)
#pragma unroll
      for (int r = 0; r < 4; ++r) {
        unsigned uz = nt ? (Gv[r].x >> 16) : (Gv[r].x & 0xffffu);
        unsigned ur = nt ? (Gv[r].y >> 16) : (Gv[r].y & 0xffffu);
        unsigned un = nt ? (Gv[r].z >> 16) : (Gv[r].z & 0xffffu);
        float zz = sigm(bfu(uz) + acc[0][nt][r]);
        float rr = sigm(bfu(ur) + acc[1][nt][r]);
        float nn = tanh_fast(bfu(un) + rr * acc[2][nt][r]);
        float hnew = (1.f - zz) * hd[nt][r] + zz * nn;
        h[nt][r] = hnew;
        if (t >= 124)
          hcont[((size_t)(p0 + lg * 4 + r) * 4 + (t - 124)) * 256 + wv * 32 + nt * 16 + lr] = hnew;
      }
  }
}

// ------------------------------------------------------------------ tail
__global__ __launch_bounds__(256) void k_att(const float* __restrict__ hmain,
                                             const float* __restrict__ xself,
                                             const float* __restrict__ hc,
                                             const float* __restrict__ Wv,
                                             const float* __restrict__ bv,
                                             float* __restrict__ hh) {
  int b = blockIdx.x, tid = threadIdx.x;
  __shared__ float hl[16 * 256];
  __shared__ float aa[16 * 4];
  for (int idx = tid; idx < 4096; idx += 256) hl[idx] = hmain[(size_t)b * SS * HH + idx];
  __syncthreads();
  if (tid < 64) {
    int s = tid >> 2, m = tid & 3;
    float acc = bv[m];
    for (int j = 0; j < 256; ++j)
      acc += hl[s * 256 + j] * Wv[j * 4 + m] + hl[j] * Wv[(256 + j) * 4 + m];
    aa[s * 4 + m] = tanh_fast(acc);
  }
  __syncthreads();
  if (tid < 4) {
    int m = tid;
    float mx = -1e30f;
    for (int s = 0; s < 16; ++s) mx = fmaxf(mx, aa[s * 4 + m]);
    float sum = 0.f;
    for (int s = 0; s < 16; ++s) sum += __expf(aa[s * 4 + m] - mx);
    float inv = 1.f / sum;
    for (int s = 0; s < 16; ++s) aa[s * 4 + m] = __expf(aa[s * 4 + m] - mx) * inv;
  }
  __syncthreads();
  float a0 = 0.f, a1 = 0.f, a2 = 0.f, a3 = 0.f;
  for (int s = 0; s < 16; ++s) {
    float hv = hl[s * 256 + tid];
    a0 = fmaf(aa[s * 4 + 0], hv, a0);
    a1 = fmaf(aa[s * 4 + 1], hv, a1);
    a2 = fmaf(aa[s * 4 + 2], hv, a2);
    a3 = fmaf(aa[s * 4 + 3], hv, a3);
  }
  float* hb = hh + (size_t)b * 1664;
  hb[384 + 0 * 256 + tid] = a0;
  hb[384 + 1 * 256 + tid] = a1;
  hb[384 + 2 * 256 + tid] = a2;
  hb[384 + 3 * 256 + tid] = a3;
  if (tid < 128) hb[tid] = xself[b * DD + tid];
  hb[128 + tid] = hl[tid];
  hb[1408 + tid] = hc[(size_t)b * HH + tid];
}

__global__ __launch_bounds__(256) void k_mlp(const float* __restrict__ A,
                                             const float* __restrict__ W,
                                             const float* __restrict__ bias,
                                             float* __restrict__ C, int K, int N) {
  int tid = threadIdx.x;
  int j = blockIdx.x * 256 + tid;
  int rb = blockIdx.y * 16;
  __shared__ float al[16 * 512];
  float acc[16];
#pragma unroll
  for (int r = 0; r < 16; ++r) acc[r] = 0.f;
  for (int kc = 0; kc < K; kc += 512) {
    int ch = K - kc;
    if (ch > 512) ch = 512;
    __syncthreads();
#pragma unroll
    for (int r = 0; r < 16; ++r)
      for (int k = tid; k < ch; k += 256) al[r * 512 + k] = A[(size_t)(rb + r) * K + kc + k];
    __syncthreads();
    for (int k = 0; k < ch; ++k) {
      float w = W[(size_t)(kc + k) * N + j];
#pragma unroll
      for (int r = 0; r < 16; ++r) acc[r] = fmaf(al[r * 512 + k], w, acc[r]);
    }
  }
  float bj = bias[j];
#pragma unroll
  for (int r = 0; r < 16; ++r) {
    float v = acc[r] + bj;
    C[(size_t)(rb + r) * N + j] = v > 0.f ? v : 0.01f * v;
  }
}

__global__ __launch_bounds__(64) void k_head(const float* __restrict__ A,
                                             const float* __restrict__ Wp,
                                             const float* __restrict__ bp,
                                             float* __restrict__ out) {
  int row = blockIdx.x, l = threadIdx.x;
  float acc = 0.f;
  for (int j = l; j < 256; j += 64) acc = fmaf(A[(size_t)row * 256 + j], Wp[j], acc);
  for (int o = 32; o; o >>= 1) acc += __shfl_xor(acc, o);
  if (l == 0) out[row] = 1.f / (1.f + __expf(-(acc + bp[0])));
}

extern "C" void kernel_launch(void* const* d_in, const int* in_sizes, int n_in,
                              void* d_out, int out_size, void* d_ws, size_t ws_size,
                              hipStream_t stream) {
  const int* x = (const int*)d_in[0];
  const int* xc = (const int*)d_in[1];
  const int* self_loc = (const int*)d_in[2];
  const float* emb = (const float*)d_in[3];
  const float* W_rnn = (const float*)d_in[4];
  const float* U_rnn = (const float*)d_in[5];
  const float* b_rnn = (const float*)d_in[6];
  const float* wt_rnn = (const float*)d_in[7];
  const float* W_c = (const float*)d_in[8];
  const float* U_c = (const float*)d_in[9];
  const float* b_c = (const float*)d_in[10];
  const float* wt_c = (const float*)d_in[11];
  const float* Wv = (const float*)d_in[12];
  const float* bv = (const float*)d_in[13];
  const float* W0 = (const float*)d_in[14];
  const float* b0 = (const float*)d_in[15];
  const float* W1 = (const float*)d_in[16];
  const float* b1 = (const float*)d_in[17];
  const float* W2 = (const float*)d_in[18];
  const float* b2 = (const float*)d_in[19];
  const float* Wp = (const float*)d_in[20];
  const float* bp = (const float*)d_in[21];
  float* out = (float*)d_out;

  char* ws = (char*)d_ws;
  size_t cur = 0;
  auto alloc = [&](size_t bytes) {
    char* p = ws + cur;
    cur += (bytes + 255) & ~(size_t)255;
    return p;
  };
  float* es = (float*)alloc((size_t)BB * DD * 4);
  float* ns = (float*)alloc(BB * 4);
  unsigned* minu = (unsigned*)alloc(4);
  float* simw = (float*)alloc((size_t)BB * SS * II * 4);
  int* topidx = (int*)alloc((size_t)BB * SS * KK * 4);
  float* xself = (float*)alloc((size_t)BB * DD * 4);
  __bf16* xself_bf = (__bf16*)alloc((size_t)BB * DD * 2);
  float* dtm = (float*)alloc((size_t)KK * 8192 * 4);
  float* dtc = (float*)alloc((size_t)128 * 128 * 4);
  float* hcont = (float*)alloc((size_t)BB * HH * 4);
  float* hh = (float*)alloc((size_t)BB * 1664 * 4);
  float* z0 = (float*)alloc((size_t)BB * 1024 * 4);
  float* z1 = (float*)alloc((size_t)BB * 512 * 4);
  float* z2 = (float*)alloc((size_t)BB * 256 * 4);
  float* hmain = (float*)alloc((size_t)8192 * HH * 4);
  __hip_bfloat16* ec = (__hip_bfloat16*)alloc((size_t)16384 * DD * 2);
  __hip_bfloat16* em = (__hip_bfloat16*)alloc((size_t)KK * 8192 * DD * 2);
  __bf16* G2 = (__bf16*)alloc((size_t)16384 * 1024 * 2);
  __bf16* pWs = (__bf16*)alloc((size_t)4 * 48 * 64 * 8 * 2);
  __bf16* pWe = (__bf16*)alloc((size_t)4 * 48 * 64 * 8 * 2);
  __bf16* pU = (__bf16*)alloc((size_t)8 * 48 * 64 * 8 * 2);
  __bf16* pWc = (__bf16*)alloc((size_t)4 * 48 * 64 * 8 * 2);
  __bf16* pUc = (__bf16*)alloc((size_t)8 * 48 * 64 * 8 * 2);
  (void)ws_size;

  hipLaunchKernelGGL(k_init, dim3(1), dim3(1), 0, stream, minu);
  hipLaunchKernelGGL(k_eself, dim3(BB), dim3(128), 0, stream, x, self_loc, emb, es, ns);
  hipLaunchKernelGGL(k_cos, dim3(BB * SS), dim3(256), 0, stream, x, emb, es, ns, simw, minu);
  hipLaunchKernelGGL(k_topk, dim3(BB * SS), dim3(64), 0, stream, x, simw, minu, topidx);
  hipLaunchKernelGGL(k_build_main, dim3(1024, KK), dim3(256), 0, stream, x, self_loc, emb,
                     topidx, em, dtm, xself, xself_bf);
  hipLaunchKernelGGL(k_build_cont, dim3(128, 128), dim3(128), 0, stream, xc, emb, ec, dtc);
  hipLaunchKernelGGL(k_pack, dim3(4, 48), dim3(64), 0, stream, W_rnn, pWs);
  hipLaunchKernelGGL(k_pack, dim3(4, 48), dim3(64), 0, stream, W_rnn + 128 * 768, pWe);
  hipLaunchKernelGGL(k_pack, dim3(8, 48), dim3(64), 0, stream, U_rnn, pU);
  hipLaunchKernelGGL(k_pack, dim3(4, 48), dim3(64), 0, stream, W_c, pWc);
  hipLaunchKernelGGL(k_pack, dim3(8, 48), dim3(64), 0, stream, U_c, pUc);
  hipLaunchKernelGGL(k_gemm_g, dim3(512), dim3(512), 0, stream, ec, pWc, b_c, G2);
  hipLaunchKernelGGL(k_rnn_main_mfma, dim3(256), dim3(1024), 0, stream, em, dtm, xself_bf,
                     pWs, pWe, pU, b_rnn, wt_rnn, hmain);
  hipLaunchKernelGGL(k_rnn_cont_mfma, dim3(8), dim3(512), 0, stream, G2, dtc, pUc, wt_c,
                     hcont);
  hipLaunchKernelGGL(k_att, dim3(BB), dim3(256), 0, stream, hmain, xself, hcont, Wv, bv, hh);
  hipLaunchKernelGGL(k_mlp, dim3(4, 32), dim3(256), 0, stream, hh, W0, b0, z0, 1664, 1024);
  hipLaunchKernelGGL(k_mlp, dim3(2, 32), dim3(256), 0, stream, z0, W1, b1, z1, 1024, 512);
  hipLaunchKernelGGL(k_mlp, dim3(1, 32), dim3(256), 0, stream, z1, W2, b2, z2, 512, 256);
  hipLaunchKernelGGL(k_head, dim3(BB), dim3(64), 0, stream, z2, Wp, bp, out);
}